// Round 1
// baseline (3854.630 us; speedup 1.0000x reference)
//
#include <hip/hip_runtime.h>
#include <stdint.h>

#define T_STEPS 8
#define FIN 3
#define HID 32
#define NEG_SLOPE 0.2f

__device__ __forceinline__ float lrelu(float x) { return x > 0.f ? x : NEG_SLOPE * x; }
__device__ __forceinline__ float sigmoidf(float x) { return 1.f / (1.f + __expf(-x)); }

// ---------------- edge dtype detection (int64 vs int32) ----------------
// If the buffer holds int64 values < 2^31, every odd int32 slot is 0.
__global__ void detect_kernel(const int* ei32, int nElems, int* flag) {
    __shared__ int any_nonzero;
    if (threadIdx.x == 0) any_nonzero = 0;
    __syncthreads();
    int idx = 1 + 2 * (int)threadIdx.x;  // odd int32 slots
    if (idx < nElems && ei32[idx] != 0) any_nonzero = 1;  // benign race
    __syncthreads();
    if (threadIdx.x == 0) *flag = (any_nonzero ? 0 : 1);  // 1 => int64
}

__device__ __forceinline__ int get_edge(const void* ei, int is64, long long idx) {
    if (is64) return (int)((const long long*)ei)[idx];
    return ((const int*)ei)[idx];
}

// ---------------- CSR build ----------------
__global__ void init_kernel(int* cnt, int N) {
    int i = blockIdx.x * 256 + threadIdx.x;
    if (i < N) cnt[i] = 1;  // self-loop pre-counted
}

__global__ void count_kernel(const void* ei, const int* flag, int E, int N, int* cnt) {
    int e = blockIdx.x * 256 + threadIdx.x;
    if (e >= E) return;
    int is64 = *flag;
    int d = get_edge(ei, is64, (long long)E + e);
    if ((unsigned)d < (unsigned)N) atomicAdd(&cnt[d], 1);
}

__global__ __launch_bounds__(1024) void scan_kernel(const int* cnt, int* rowptr, int n) {
    __shared__ int sm[1024];
    __shared__ int carry;
    int tid = threadIdx.x;
    if (tid == 0) { carry = 0; rowptr[0] = 0; }
    __syncthreads();
    for (int base = 0; base < n; base += 1024) {
        int i = base + tid;
        int v = (i < n) ? cnt[i] : 0;
        sm[tid] = v;
        __syncthreads();
        for (int off = 1; off < 1024; off <<= 1) {
            int t = (tid >= off) ? sm[tid - off] : 0;
            __syncthreads();
            sm[tid] += t;
            __syncthreads();
        }
        int inc = sm[tid] + carry;
        if (i < n) rowptr[i + 1] = inc;
        __syncthreads();
        if (tid == 1023) carry = inc;
        __syncthreads();
    }
}

__global__ void selffill_kernel(const int* rowptr, int* csr, int* fill, int N) {
    int n = blockIdx.x * 256 + threadIdx.x;
    if (n >= N) return;
    int rp = rowptr[n];
    csr[rp] = n;        // self-loop occupies slot 0 of each row
    fill[n] = rp + 1;
}

__global__ void scatter_kernel(const void* ei, const int* flag, int E, int N, int* fill, int* csr) {
    int e = blockIdx.x * 256 + threadIdx.x;
    if (e >= E) return;
    int is64 = *flag;
    int s = get_edge(ei, is64, e);
    int d = get_edge(ei, is64, (long long)E + e);
    if ((unsigned)d >= (unsigned)N) return;
    if ((unsigned)s >= (unsigned)N) s = 0;  // safety clamp (never hit when detection is right)
    int p = atomicAdd(&fill[d], 1);
    csr[p] = s;
}

// ---------------- GAT layer 1 featurize: h1 = x @ W1^T, per-node att scores ----------------
// one wave (64 lanes) per node; lane = head*32+chan
__global__ __launch_bounds__(256) void feat1_kernel(
        const float* __restrict__ x, const float* __restrict__ W1,
        const float* __restrict__ a1s, const float* __restrict__ a1d,
        float* __restrict__ h1, float* __restrict__ ss1, float* __restrict__ sd1, int N) {
    int tid = blockIdx.x * 256 + threadIdx.x;
    int node = tid >> 6;
    int lane = threadIdx.x & 63;
    if (node >= N) return;
    const float* xp = x + (size_t)node * FIN;
    float x0 = xp[0], x1 = xp[1], x2 = xp[2];
    float h = W1[lane * 3 + 0] * x0 + W1[lane * 3 + 1] * x1 + W1[lane * 3 + 2] * x2;
    h1[(size_t)node * 64 + lane] = h;
    float ps = h * a1s[lane], pd = h * a1d[lane];
    for (int m = 16; m >= 1; m >>= 1) {
        ps += __shfl_xor(ps, m, 64);
        pd += __shfl_xor(pd, m, 64);
    }
    if ((lane & 31) == 0) {
        int head = lane >> 5;
        ss1[node * 2 + head] = ps;
        sd1[node * 2 + head] = pd;
    }
}

// ---------------- GAT1 aggregate (+bias,+mean-heads,+relu) fused with GAT2 featurize ----------------
// one wave per destination, grid-stride over destinations
__global__ __launch_bounds__(256) void agg1feat2_kernel(
        const int* __restrict__ rowptr, const int* __restrict__ csr,
        const float* __restrict__ h1, const float* __restrict__ ss1, const float* __restrict__ sd1,
        const float* __restrict__ b1, const float* __restrict__ W2,
        const float* __restrict__ a2s, const float* __restrict__ a2d,
        float* __restrict__ h2, float* __restrict__ ss2, float* __restrict__ sd2, int N) {
    __shared__ float w2T[32 * 64];  // w2T[k*64+c] = W2[c*32+k]
    for (int i = threadIdx.x; i < 2048; i += 256) {
        int k = i >> 6, c = i & 63;
        w2T[i] = W2[c * 32 + k];
    }
    __syncthreads();
    int lane = threadIdx.x & 63;
    int head = lane >> 5;
    int gw = blockIdx.x * 4 + (threadIdx.x >> 6);
    int nw = gridDim.x * 4;
    for (int dst = gw; dst < N; dst += nw) {
        int rs = rowptr[dst], re = rowptr[dst + 1];
        float sd = sd1[dst * 2 + head];
        float mx = -1e30f;
        for (int e = rs; e < re; e++) {
            int s = csr[e];
            float sc = lrelu(ss1[s * 2 + head] + sd);
            mx = fmaxf(mx, sc);
        }
        float denom = 0.f, acc = 0.f;
        for (int e = rs; e < re; e++) {
            int s = csr[e];
            float sc = lrelu(ss1[s * 2 + head] + sd);
            float w = __expf(sc - mx);
            denom += w;
            acc += w * h1[(size_t)s * 64 + lane];
        }
        float r = acc / (denom + 1e-16f);
        float other = __shfl(r, lane ^ 32, 64);
        float g = 0.5f * (r + other) + b1[lane & 31];
        g = fmaxf(g, 0.f);  // relu; identical value in both wave halves
        // GAT2 featurize for this node: h2[c] = sum_k W2[c,k] * g[k]
        float hv = 0.f;
#pragma unroll
        for (int k = 0; k < 32; k++) hv += w2T[k * 64 + lane] * __shfl(g, k, 64);
        h2[(size_t)dst * 64 + lane] = hv;
        float ps = hv * a2s[lane], pd = hv * a2d[lane];
        for (int m = 16; m >= 1; m >>= 1) {
            ps += __shfl_xor(ps, m, 64);
            pd += __shfl_xor(pd, m, 64);
        }
        if ((lane & 31) == 0) {
            ss2[dst * 2 + head] = ps;
            sd2[dst * 2 + head] = pd;
        }
    }
}

// ---------------- GAT2 aggregate fused with GRU cell ----------------
// lanes 0-31 compute input-gate dots, lanes 32-63 hidden-gate dots
__global__ __launch_bounds__(256) void agg2gru_kernel(
        const int* __restrict__ rowptr, const int* __restrict__ csr,
        const float* __restrict__ h2, const float* __restrict__ ss2, const float* __restrict__ sd2,
        const float* __restrict__ b2,
        const float* __restrict__ w_ih, const float* __restrict__ w_hh,
        const float* __restrict__ b_ih, const float* __restrict__ b_hh,
        float* __restrict__ hstate, int N, int first) {
    __shared__ float wih[32 * 96];  // wih[k*96+r] = w_ih[r*32+k]
    __shared__ float whh[32 * 96];
    for (int i = threadIdx.x; i < 3072; i += 256) {
        int r = i >> 5, k = i & 31;
        wih[k * 96 + r] = w_ih[i];
        whh[k * 96 + r] = w_hh[i];
    }
    __syncthreads();
    int lane = threadIdx.x & 63;
    int head = lane >> 5;
    int c = lane & 31;
    bool hi = lane >= 32;
    int gw = blockIdx.x * 4 + (threadIdx.x >> 6);
    int nw = gridDim.x * 4;
    for (int dst = gw; dst < N; dst += nw) {
        int rs = rowptr[dst], re = rowptr[dst + 1];
        float sdv = sd2[dst * 2 + head];
        float mx = -1e30f;
        for (int e = rs; e < re; e++) {
            int s = csr[e];
            float sc = lrelu(ss2[s * 2 + head] + sdv);
            mx = fmaxf(mx, sc);
        }
        float denom = 0.f, acc = 0.f;
        for (int e = rs; e < re; e++) {
            int s = csr[e];
            float sc = lrelu(ss2[s * 2 + head] + sdv);
            float w = __expf(sc - mx);
            denom += w;
            acc += w * h2[(size_t)s * 64 + lane];
        }
        float r = acc / (denom + 1e-16f);
        float other = __shfl(r, lane ^ 32, 64);
        float g = 0.5f * (r + other) + b2[c];
        g = fmaxf(g, 0.f);  // GAT2 output channel c (both halves hold it)
        // GRU cell
        float hold = first ? 0.f : hstate[(size_t)dst * 32 + c];
        float a0, a1v, a2v;
        if (!hi) { a0 = b_ih[c]; a1v = b_ih[32 + c]; a2v = b_ih[64 + c]; }
        else     { a0 = b_hh[c]; a1v = b_hh[32 + c]; a2v = b_hh[64 + c]; }
        const float* wt = hi ? whh : wih;
        float bc = hi ? hold : g;   // lane k / lane 32+k broadcast channel k
        int base = hi ? 32 : 0;
#pragma unroll
        for (int k = 0; k < 32; k++) {
            float v = __shfl(bc, base + k, 64);
            a0  += wt[k * 96 + c]      * v;
            a1v += wt[k * 96 + 32 + c] * v;
            a2v += wt[k * 96 + 64 + c] * v;
        }
        float hr = __shfl(a0, c + 32, 64);
        float hz = __shfl(a1v, c + 32, 64);
        float hn = __shfl(a2v, c + 32, 64);
        if (!hi) {
            float rr = sigmoidf(a0 + hr);
            float zz = sigmoidf(a1v + hz);
            float cand = tanhf(a2v + rr * hn);
            float hnew = (1.f - zz) * cand + zz * hold;
            hstate[(size_t)dst * 32 + c] = hnew;
        }
    }
}

// ---------------- final Linear(hid,1) ----------------
__global__ __launch_bounds__(256) void final_kernel(
        const float* __restrict__ hstate, const float* __restrict__ fc_w,
        const float* __restrict__ fc_b, float* __restrict__ out, int N) {
    int tid = blockIdx.x * 256 + threadIdx.x;
    int node = tid >> 5;
    int c = tid & 31;
    if (node >= N) return;
    float v = hstate[(size_t)node * 32 + c] * fc_w[c];
    for (int m = 16; m >= 1; m >>= 1) v += __shfl_xor(v, m, 64);
    if (c == 0) out[node] = v + fc_b[0];
}

extern "C" void kernel_launch(void* const* d_in, const int* in_sizes, int n_in,
                              void* d_out, int out_size, void* d_ws, size_t ws_size,
                              hipStream_t stream) {
    const float* x_seq = (const float*)d_in[0];
    const float* W1  = (const float*)d_in[1];
    const float* a1s = (const float*)d_in[2];
    const float* a1d = (const float*)d_in[3];
    const float* b1  = (const float*)d_in[4];
    const float* W2  = (const float*)d_in[5];
    const float* a2s = (const float*)d_in[6];
    const float* a2d = (const float*)d_in[7];
    const float* b2  = (const float*)d_in[8];
    const float* w_ih = (const float*)d_in[9];
    const float* w_hh = (const float*)d_in[10];
    const float* b_ih = (const float*)d_in[11];
    const float* b_hh = (const float*)d_in[12];
    const float* fc_w = (const float*)d_in[13];
    const float* fc_b = (const float*)d_in[14];
    const void*  ei   = d_in[15];

    const int N = in_sizes[0] / (T_STEPS * FIN);  // 50000
    const int E = in_sizes[15] / 2;               // 800000
    const int NE = E + N;

    char* ws = (char*)d_ws;
    size_t off = 0;
    auto alloc = [&](size_t bytes) -> void* {
        void* p = ws + off;
        off += (bytes + 255) & ~(size_t)255;
        return p;
    };
    int*   flag   = (int*)alloc(4);
    int*   rowptr = (int*)alloc((size_t)(N + 1) * 4);
    int*   cnt    = (int*)alloc((size_t)N * 4);        // reused as fill cursor
    int*   csr    = (int*)alloc((size_t)NE * 4);
    float* h1     = (float*)alloc((size_t)N * 64 * 4);
    float* h2     = (float*)alloc((size_t)N * 64 * 4);
    float* ss1    = (float*)alloc((size_t)N * 2 * 4);
    float* sd1    = (float*)alloc((size_t)N * 2 * 4);
    float* ss2    = (float*)alloc((size_t)N * 2 * 4);
    float* sd2    = (float*)alloc((size_t)N * 2 * 4);
    float* hst    = (float*)alloc((size_t)N * 32 * 4);
    if (off > ws_size) return;  // workspace too small — cannot proceed safely

    const int AGG_BLOCKS = 2048;

    // ---- preprocessing: CSR by destination (reused for 16 aggregations) ----
    detect_kernel<<<1, 128, 0, stream>>>((const int*)ei, in_sizes[15], flag);
    init_kernel<<<(N + 255) / 256, 256, 0, stream>>>(cnt, N);
    count_kernel<<<(E + 255) / 256, 256, 0, stream>>>(ei, flag, E, N, cnt);
    scan_kernel<<<1, 1024, 0, stream>>>(cnt, rowptr, N);
    selffill_kernel<<<(N + 255) / 256, 256, 0, stream>>>(rowptr, csr, cnt, N);
    scatter_kernel<<<(E + 255) / 256, 256, 0, stream>>>(ei, flag, E, N, cnt, csr);

    // ---- T timesteps ----
    for (int t = 0; t < T_STEPS; t++) {
        const float* xt = x_seq + (size_t)t * N * FIN;
        feat1_kernel<<<(N * 64 + 255) / 256, 256, 0, stream>>>(xt, W1, a1s, a1d, h1, ss1, sd1, N);
        agg1feat2_kernel<<<AGG_BLOCKS, 256, 0, stream>>>(rowptr, csr, h1, ss1, sd1, b1, W2,
                                                         a2s, a2d, h2, ss2, sd2, N);
        agg2gru_kernel<<<AGG_BLOCKS, 256, 0, stream>>>(rowptr, csr, h2, ss2, sd2, b2,
                                                       w_ih, w_hh, b_ih, b_hh, hst, N,
                                                       t == 0 ? 1 : 0);
    }
    final_kernel<<<(N * 32 + 255) / 256, 256, 0, stream>>>(hst, fc_w, fc_b, (float*)d_out, N);
}

// Round 2
// 2937.274 us; speedup vs baseline: 1.3123x; 1.3123x over previous
//
#include <hip/hip_runtime.h>
#include <stdint.h>

#define T_STEPS 8
#define FIN 3
#define HID 32
#define NEG_SLOPE 0.2f

__device__ __forceinline__ float lrelu(float x) { return x > 0.f ? x : NEG_SLOPE * x; }
__device__ __forceinline__ float sigmoidf(float x) { return 1.f / (1.f + __expf(-x)); }

// ---------------- edge dtype detection (int64 vs int32) ----------------
__global__ void detect_kernel(const int* ei32, int nElems, int* flag) {
    __shared__ int any_nonzero;
    if (threadIdx.x == 0) any_nonzero = 0;
    __syncthreads();
    int idx = 1 + 2 * (int)threadIdx.x;  // odd int32 slots
    if (idx < nElems && ei32[idx] != 0) any_nonzero = 1;  // benign race
    __syncthreads();
    if (threadIdx.x == 0) *flag = (any_nonzero ? 0 : 1);  // 1 => int64
}

__device__ __forceinline__ int get_edge(const void* ei, int is64, long long idx) {
    if (is64) return (int)((const long long*)ei)[idx];
    return ((const int*)ei)[idx];
}

// ---------------- CSR build ----------------
__global__ void init_kernel(int* cnt, int N) {
    int i = blockIdx.x * 256 + threadIdx.x;
    if (i < N) cnt[i] = 1;  // self-loop pre-counted
}

__global__ void count_kernel(const void* ei, const int* flag, int E, int N, int* cnt) {
    int e = blockIdx.x * 256 + threadIdx.x;
    if (e >= E) return;
    int is64 = *flag;
    int d = get_edge(ei, is64, (long long)E + e);
    if ((unsigned)d < (unsigned)N) atomicAdd(&cnt[d], 1);
}

__global__ __launch_bounds__(1024) void scan_kernel(const int* cnt, int* rowptr, int n) {
    __shared__ int sm[1024];
    __shared__ int carry;
    int tid = threadIdx.x;
    if (tid == 0) { carry = 0; rowptr[0] = 0; }
    __syncthreads();
    for (int base = 0; base < n; base += 1024) {
        int i = base + tid;
        int v = (i < n) ? cnt[i] : 0;
        sm[tid] = v;
        __syncthreads();
        for (int off = 1; off < 1024; off <<= 1) {
            int t = (tid >= off) ? sm[tid - off] : 0;
            __syncthreads();
            sm[tid] += t;
            __syncthreads();
        }
        int inc = sm[tid] + carry;
        if (i < n) rowptr[i + 1] = inc;
        __syncthreads();
        if (tid == 1023) carry = inc;
        __syncthreads();
    }
}

__global__ void selffill_kernel(const int* rowptr, int* csr, int* fill, int N) {
    int n = blockIdx.x * 256 + threadIdx.x;
    if (n >= N) return;
    int rp = rowptr[n];
    csr[rp] = n;        // self-loop occupies slot 0 of each row
    fill[n] = rp + 1;
}

__global__ void scatter_kernel(const void* ei, const int* flag, int E, int N, int* fill, int* csr) {
    int e = blockIdx.x * 256 + threadIdx.x;
    if (e >= E) return;
    int is64 = *flag;
    int s = get_edge(ei, is64, e);
    int d = get_edge(ei, is64, (long long)E + e);
    if ((unsigned)d >= (unsigned)N) return;
    if ((unsigned)s >= (unsigned)N) s = 0;  // safety clamp
    int p = atomicAdd(&fill[d], 1);
    csr[p] = s;
}

// ---------------- precompute u = W2^T a2 per head (for layer-2 scores) ----------------
// u_s[h*32+k] = sum_c a2s[h*32+c] * W2[(h*32+c)*32 + k]
__global__ __launch_bounds__(64) void prep_u_kernel(
        const float* __restrict__ W2, const float* __restrict__ a2s,
        const float* __restrict__ a2d, float* __restrict__ u_s, float* __restrict__ u_d) {
    int l = threadIdx.x;  // 0..63
    int h = l >> 5, k = l & 31;
    float us = 0.f, ud = 0.f;
    for (int c = 0; c < 32; c++) {
        float w = W2[(h * 32 + c) * 32 + k];
        us += a2s[h * 32 + c] * w;
        ud += a2d[h * 32 + c] * w;
    }
    u_s[l] = us;
    u_d[l] = ud;
}

// ---------------- layer-1 per-node attention scores (no h1 materialization) ----------------
__global__ __launch_bounds__(256) void score1_kernel(
        const float* __restrict__ x, const float* __restrict__ W1,
        const float* __restrict__ a1s, const float* __restrict__ a1d,
        float* __restrict__ ss1, float* __restrict__ sd1, int N) {
    int tid = blockIdx.x * 256 + threadIdx.x;
    int node = tid >> 6;
    int lane = threadIdx.x & 63;
    if (node >= N) return;
    const float* xp = x + (size_t)node * FIN;
    float h = W1[lane * 3] * xp[0] + W1[lane * 3 + 1] * xp[1] + W1[lane * 3 + 2] * xp[2];
    float ps = h * a1s[lane], pd = h * a1d[lane];
    for (int m = 16; m >= 1; m >>= 1) {
        ps += __shfl_xor(ps, m, 64);
        pd += __shfl_xor(pd, m, 64);
    }
    if ((lane & 31) == 0) {
        int head = lane >> 5;
        ss1[node * 2 + head] = ps;
        sd1[node * 2 + head] = pd;
    }
}

// ---------------- GAT1 aggregate via commuted linear map (gather x: 12B/edge) ----------------
// + GAT2 featurize scores (u·g1). One wave per dst; lane = head*32+chan.
__global__ __launch_bounds__(256) void aggA_kernel(
        const int* __restrict__ rowptr, const int* __restrict__ csr,
        const float* __restrict__ x,
        const float* __restrict__ ss1, const float* __restrict__ sd1,
        const float* __restrict__ W1, const float* __restrict__ b1,
        const float* __restrict__ u_s, const float* __restrict__ u_d,
        float* __restrict__ g1, float* __restrict__ ss2, float* __restrict__ sd2, int N) {
    int lane = threadIdx.x & 63;
    int head = lane >> 5;
    int c = lane & 31;
    float w10 = W1[lane * 3], w11 = W1[lane * 3 + 1], w12 = W1[lane * 3 + 2];
    float b1v = b1[c];
    float usv = u_s[lane], udv = u_d[lane];
    const float* ssp = ss1 + head;
    int gw = blockIdx.x * 4 + (threadIdx.x >> 6);
    int nw = gridDim.x * 4;
    for (int dst = gw; dst < N; dst += nw) {
        int rs = rowptr[dst], re = rowptr[dst + 1];
        float sdv = sd1[dst * 2 + head];
        float ax0 = 0.f, ax1 = 0.f, ax2 = 0.f, den = 0.f;
#pragma unroll 4
        for (int e = rs; e < re; e++) {
            int s = __builtin_amdgcn_readfirstlane(csr[e]);
            float w = __expf(lrelu(ssp[2 * s] + sdv));  // bounded scores: max-shift-free softmax
            const float* xp = x + 3 * (size_t)s;
            ax0 += w * xp[0];
            ax1 += w * xp[1];
            ax2 += w * xp[2];
            den += w;
        }
        float inv = 1.f / (den + 1e-16f);
        float v = (w10 * ax0 + w11 * ax1 + w12 * ax2) * inv;  // = Σ alpha·(W1 x[src]) at this lane
        float other = __shfl(v, lane ^ 32, 64);
        float g = fmaxf(0.5f * (v + other) + b1v, 0.f);        // mean heads + bias + relu
        if (lane < 32) g1[(size_t)dst * 32 + c] = g;
        // layer-2 scores: ss2[h] = u_s[h]·g1, sd2[h] = u_d[h]·g1
        float ps = g * usv, pd = g * udv;
        for (int m = 16; m >= 1; m >>= 1) {
            ps += __shfl_xor(ps, m, 64);
            pd += __shfl_xor(pd, m, 64);
        }
        if (c == 0) {
            ss2[dst * 2 + head] = ps;
            sd2[dst * 2 + head] = pd;
        }
    }
}

// ---------------- GAT2 aggregate (gather g1: 128B/edge) + W2 epilogue + GRU cell ----------------
__global__ __launch_bounds__(256) void aggB_kernel(
        const int* __restrict__ rowptr, const int* __restrict__ csr,
        const float* __restrict__ g1,
        const float* __restrict__ ss2, const float* __restrict__ sd2,
        const float* __restrict__ W2, const float* __restrict__ b2,
        const float* __restrict__ w_ih, const float* __restrict__ w_hh,
        const float* __restrict__ b_ih, const float* __restrict__ b_hh,
        float* __restrict__ hstate, int N, int first) {
    __shared__ float w2T[32 * 64];   // w2T[k*64+l] = W2[l*32+k]
    __shared__ float wih[32 * 96];   // wih[k*96+r] = w_ih[r*32+k]
    __shared__ float whh[32 * 96];
    for (int i = threadIdx.x; i < 2048; i += 256) {
        int k = i >> 6, l = i & 63;
        w2T[i] = W2[l * 32 + k];     // consecutive threads -> consecutive LDS: conflict-free
    }
    for (int i = threadIdx.x; i < 3072; i += 256) {
        int k = i / 96, r = i % 96;  // consecutive threads -> consecutive LDS: conflict-free
        wih[i] = w_ih[r * 32 + k];
        whh[i] = w_hh[r * 32 + k];
    }
    __syncthreads();
    int lane = threadIdx.x & 63;
    int head = lane >> 5;
    int c = lane & 31;
    bool hi = lane >= 32;
    const float* ssp = ss2 + head;
    float b2v = b2[c];
    int gw = blockIdx.x * 4 + (threadIdx.x >> 6);
    int nw = gridDim.x * 4;
    for (int dst = gw; dst < N; dst += nw) {
        int rs = rowptr[dst], re = rowptr[dst + 1];
        float sdv = sd2[dst * 2 + head];
        float acc = 0.f, den = 0.f;
#pragma unroll 4
        for (int e = rs; e < re; e++) {
            int s = __builtin_amdgcn_readfirstlane(csr[e]);
            float w = __expf(lrelu(ssp[2 * s] + sdv));
            float gv = g1[(size_t)s * 32 + c];  // both halves read same 128B line
            acc += w * gv;
            den += w;
        }
        float r = acc / (den + 1e-16f);  // agg_head[c] at lane head*32+c
        // h2agg[lane] = Σ_k W2[lane,k] · agg_head[k]
        float hv = 0.f;
#pragma unroll
        for (int k = 0; k < 32; k++) hv += w2T[k * 64 + lane] * __shfl(r, (lane & 32) | k, 64);
        float other = __shfl(hv, lane ^ 32, 64);
        float g = fmaxf(0.5f * (hv + other) + b2v, 0.f);  // GAT2 output channel c (both halves)
        // ---- GRU cell: lanes 0-31 input gates, 32-63 hidden gates ----
        float hold = first ? 0.f : hstate[(size_t)dst * 32 + c];
        float a0, a1v, a2v;
        if (!hi) { a0 = b_ih[c]; a1v = b_ih[32 + c]; a2v = b_ih[64 + c]; }
        else     { a0 = b_hh[c]; a1v = b_hh[32 + c]; a2v = b_hh[64 + c]; }
        const float* wt = hi ? whh : wih;
        float bc = hi ? hold : g;
        int base = hi ? 32 : 0;
#pragma unroll
        for (int k = 0; k < 32; k++) {
            float v = __shfl(bc, base + k, 64);
            a0  += wt[k * 96 + c]      * v;
            a1v += wt[k * 96 + 32 + c] * v;
            a2v += wt[k * 96 + 64 + c] * v;
        }
        float hr = __shfl(a0, c + 32, 64);
        float hz = __shfl(a1v, c + 32, 64);
        float hn = __shfl(a2v, c + 32, 64);
        if (!hi) {
            float rr = sigmoidf(a0 + hr);
            float zz = sigmoidf(a1v + hz);
            float cand = tanhf(a2v + rr * hn);
            float hnew = (1.f - zz) * cand + zz * hold;
            hstate[(size_t)dst * 32 + c] = hnew;
        }
    }
}

// ---------------- final Linear(hid,1) ----------------
__global__ __launch_bounds__(256) void final_kernel(
        const float* __restrict__ hstate, const float* __restrict__ fc_w,
        const float* __restrict__ fc_b, float* __restrict__ out, int N) {
    int tid = blockIdx.x * 256 + threadIdx.x;
    int node = tid >> 5;
    int c = tid & 31;
    if (node >= N) return;
    float v = hstate[(size_t)node * 32 + c] * fc_w[c];
    for (int m = 16; m >= 1; m >>= 1) v += __shfl_xor(v, m, 64);
    if (c == 0) out[node] = v + fc_b[0];
}

extern "C" void kernel_launch(void* const* d_in, const int* in_sizes, int n_in,
                              void* d_out, int out_size, void* d_ws, size_t ws_size,
                              hipStream_t stream) {
    const float* x_seq = (const float*)d_in[0];
    const float* W1  = (const float*)d_in[1];
    const float* a1s = (const float*)d_in[2];
    const float* a1d = (const float*)d_in[3];
    const float* b1  = (const float*)d_in[4];
    const float* W2  = (const float*)d_in[5];
    const float* a2s = (const float*)d_in[6];
    const float* a2d = (const float*)d_in[7];
    const float* b2  = (const float*)d_in[8];
    const float* w_ih = (const float*)d_in[9];
    const float* w_hh = (const float*)d_in[10];
    const float* b_ih = (const float*)d_in[11];
    const float* b_hh = (const float*)d_in[12];
    const float* fc_w = (const float*)d_in[13];
    const float* fc_b = (const float*)d_in[14];
    const void*  ei   = d_in[15];

    const int N = in_sizes[0] / (T_STEPS * FIN);  // 50000
    const int E = in_sizes[15] / 2;               // 800000
    const int NE = E + N;

    char* ws = (char*)d_ws;
    size_t off = 0;
    auto alloc = [&](size_t bytes) -> void* {
        void* p = ws + off;
        off += (bytes + 255) & ~(size_t)255;
        return p;
    };
    int*   flag   = (int*)alloc(4);
    int*   rowptr = (int*)alloc((size_t)(N + 1) * 4);
    int*   cnt    = (int*)alloc((size_t)N * 4);        // reused as fill cursor
    int*   csr    = (int*)alloc((size_t)NE * 4);
    float* ss1    = (float*)alloc((size_t)N * 2 * 4);
    float* sd1    = (float*)alloc((size_t)N * 2 * 4);
    float* ss2    = (float*)alloc((size_t)N * 2 * 4);
    float* sd2    = (float*)alloc((size_t)N * 2 * 4);
    float* g1     = (float*)alloc((size_t)N * 32 * 4);
    float* hst    = (float*)alloc((size_t)N * 32 * 4);
    float* u_s    = (float*)alloc(64 * 4);
    float* u_d    = (float*)alloc(64 * 4);
    if (off > ws_size) return;  // workspace too small — cannot proceed safely

    const int AGG_BLOCKS = 2048;

    // ---- preprocessing: CSR by destination (reused for all 16 aggregations) ----
    detect_kernel<<<1, 128, 0, stream>>>((const int*)ei, in_sizes[15], flag);
    init_kernel<<<(N + 255) / 256, 256, 0, stream>>>(cnt, N);
    count_kernel<<<(E + 255) / 256, 256, 0, stream>>>(ei, flag, E, N, cnt);
    scan_kernel<<<1, 1024, 0, stream>>>(cnt, rowptr, N);
    selffill_kernel<<<(N + 255) / 256, 256, 0, stream>>>(rowptr, csr, cnt, N);
    scatter_kernel<<<(E + 255) / 256, 256, 0, stream>>>(ei, flag, E, N, cnt, csr);
    prep_u_kernel<<<1, 64, 0, stream>>>(W2, a2s, a2d, u_s, u_d);

    // ---- T timesteps ----
    for (int t = 0; t < T_STEPS; t++) {
        const float* xt = x_seq + (size_t)t * N * FIN;
        score1_kernel<<<(N * 64 + 255) / 256, 256, 0, stream>>>(xt, W1, a1s, a1d, ss1, sd1, N);
        aggA_kernel<<<AGG_BLOCKS, 256, 0, stream>>>(rowptr, csr, xt, ss1, sd1, W1, b1,
                                                    u_s, u_d, g1, ss2, sd2, N);
        aggB_kernel<<<AGG_BLOCKS, 256, 0, stream>>>(rowptr, csr, g1, ss2, sd2, W2, b2,
                                                    w_ih, w_hh, b_ih, b_hh, hst, N,
                                                    t == 0 ? 1 : 0);
    }
    final_kernel<<<(N * 32 + 255) / 256, 256, 0, stream>>>(hst, fc_w, fc_b, (float*)d_out, N);
}

// Round 3
// 1657.822 us; speedup vs baseline: 2.3251x; 1.7718x over previous
//
#include <hip/hip_runtime.h>
#include <stdint.h>

#define T_STEPS 8
#define FIN 3
#define HID 32
#define NEG_SLOPE 0.2f

__device__ __forceinline__ float lrelu(float x) { return x > 0.f ? x : NEG_SLOPE * x; }
__device__ __forceinline__ float sigmoidf(float x) { return 1.f / (1.f + __expf(-x)); }

// ---------------- edge dtype detection (int64 vs int32) ----------------
__global__ void detect_kernel(const int* ei32, int nElems, int* flag) {
    __shared__ int any_nonzero;
    if (threadIdx.x == 0) any_nonzero = 0;
    __syncthreads();
    int idx = 1 + 2 * (int)threadIdx.x;  // odd int32 slots
    if (idx < nElems && ei32[idx] != 0) any_nonzero = 1;  // benign race
    __syncthreads();
    if (threadIdx.x == 0) *flag = (any_nonzero ? 0 : 1);  // 1 => int64
}

__device__ __forceinline__ int get_edge(const void* ei, int is64, long long idx) {
    if (is64) return (int)((const long long*)ei)[idx];
    return ((const int*)ei)[idx];
}

// ---------------- CSR build ----------------
__global__ void init_kernel(int* cnt, int N) {
    int i = blockIdx.x * 256 + threadIdx.x;
    if (i < N) cnt[i] = 1;  // self-loop pre-counted
}

__global__ void count_kernel(const void* ei, const int* flag, int E, int N, int* cnt) {
    int e = blockIdx.x * 256 + threadIdx.x;
    if (e >= E) return;
    int is64 = *flag;
    int d = get_edge(ei, is64, (long long)E + e);
    if ((unsigned)d < (unsigned)N) atomicAdd(&cnt[d], 1);
}

__global__ __launch_bounds__(1024) void scan_kernel(const int* cnt, int* rowptr, int n) {
    __shared__ int sm[1024];
    __shared__ int carry;
    int tid = threadIdx.x;
    if (tid == 0) { carry = 0; rowptr[0] = 0; }
    __syncthreads();
    for (int base = 0; base < n; base += 1024) {
        int i = base + tid;
        int v = (i < n) ? cnt[i] : 0;
        sm[tid] = v;
        __syncthreads();
        for (int off = 1; off < 1024; off <<= 1) {
            int t = (tid >= off) ? sm[tid - off] : 0;
            __syncthreads();
            sm[tid] += t;
            __syncthreads();
        }
        int inc = sm[tid] + carry;
        if (i < n) rowptr[i + 1] = inc;
        __syncthreads();
        if (tid == 1023) carry = inc;
        __syncthreads();
    }
}

__global__ void selffill_kernel(const int* rowptr, int* csr, int* fill, int N) {
    int n = blockIdx.x * 256 + threadIdx.x;
    if (n >= N) return;
    int rp = rowptr[n];
    csr[rp] = n;        // self-loop occupies slot 0 of each row
    fill[n] = rp + 1;
}

__global__ void scatter_kernel(const void* ei, const int* flag, int E, int N, int* fill, int* csr) {
    int e = blockIdx.x * 256 + threadIdx.x;
    if (e >= E) return;
    int is64 = *flag;
    int s = get_edge(ei, is64, e);
    int d = get_edge(ei, is64, (long long)E + e);
    if ((unsigned)d >= (unsigned)N) return;
    if ((unsigned)s >= (unsigned)N) s = 0;  // safety clamp
    int p = atomicAdd(&fill[d], 1);
    csr[p] = s;
}

// ---------------- precompute u = W2^T a2 per head (for layer-2 scores) ----------------
__global__ __launch_bounds__(64) void prep_u_kernel(
        const float* __restrict__ W2, const float* __restrict__ a2s,
        const float* __restrict__ a2d, float* __restrict__ u_s, float* __restrict__ u_d) {
    int l = threadIdx.x;  // 0..63
    int h = l >> 5, k = l & 31;
    float us = 0.f, ud = 0.f;
    for (int c = 0; c < 32; c++) {
        float w = W2[(h * 32 + c) * 32 + k];
        us += a2s[h * 32 + c] * w;
        ud += a2d[h * 32 + c] * w;
    }
    u_s[l] = us;
    u_d[l] = ud;
}

// ---------------- layer-1 per-node attention scores ----------------
__global__ __launch_bounds__(256) void score1_kernel(
        const float* __restrict__ x, const float* __restrict__ W1,
        const float* __restrict__ a1s, const float* __restrict__ a1d,
        float* __restrict__ ss1, float* __restrict__ sd1, int N) {
    int tid = blockIdx.x * 256 + threadIdx.x;
    int node = tid >> 6;
    int lane = threadIdx.x & 63;
    if (node >= N) return;
    const float* xp = x + (size_t)node * FIN;
    float h = W1[lane * 3] * xp[0] + W1[lane * 3 + 1] * xp[1] + W1[lane * 3 + 2] * xp[2];
    float ps = h * a1s[lane], pd = h * a1d[lane];
    for (int m = 16; m >= 1; m >>= 1) {
        ps += __shfl_xor(ps, m, 64);
        pd += __shfl_xor(pd, m, 64);
    }
    if ((lane & 31) == 0) {
        int head = lane >> 5;
        ss1[node * 2 + head] = ps;
        sd1[node * 2 + head] = pd;
    }
}

// ---------------- GAT1 aggregate: lane-parallel edges, wave-reduce products ----------------
// one wave per dst. Phase1: lane e loads edge e's (src, scores, x). Then 8 butterfly
// reductions give per-head {sum w, sum w*x0, sum w*x1, sum w*x2}. No serial edge chain.
__global__ __launch_bounds__(256) void aggA_kernel(
        const int* __restrict__ rowptr, const int* __restrict__ csr,
        const float* __restrict__ x,
        const float* __restrict__ ss1, const float* __restrict__ sd1,
        const float* __restrict__ W1, const float* __restrict__ b1,
        const float* __restrict__ u_s, const float* __restrict__ u_d,
        float* __restrict__ g1, float* __restrict__ ss2, float* __restrict__ sd2, int N) {
    int lane = threadIdx.x & 63;
    int head = lane >> 5;
    int c = lane & 31;
    float w10 = W1[lane * 3], w11 = W1[lane * 3 + 1], w12 = W1[lane * 3 + 2];
    float b1v = b1[c];
    float usv = u_s[lane], udv = u_d[lane];
    int gw = blockIdx.x * 4 + (threadIdx.x >> 6);
    int nw = gridDim.x * 4;
    for (int dst = gw; dst < N; dst += nw) {
        int rs = rowptr[dst], re = rowptr[dst + 1];
        int deg = re - rs;
        float sd0 = sd1[dst * 2], sd1v = sd1[dst * 2 + 1];
        float q0 = 0.f, q0x0 = 0.f, q0x1 = 0.f, q0x2 = 0.f;
        float q1 = 0.f, q1x0 = 0.f, q1x1 = 0.f, q1x2 = 0.f;
        for (int base = 0; base < deg; base += 64) {
            int idx = base + lane;
            bool valid = idx < deg;
            int s = valid ? csr[rs + idx] : 0;
            float2 sc = ((const float2*)ss1)[s];
            float w0 = valid ? __expf(lrelu(sc.x + sd0)) : 0.f;   // bounded scores
            float w1 = valid ? __expf(lrelu(sc.y + sd1v)) : 0.f;  // -> shift-free softmax
            const float* xp = x + 3 * (size_t)s;
            float x0 = xp[0], x1 = xp[1], x2 = xp[2];
            q0 += w0; q0x0 += w0 * x0; q0x1 += w0 * x1; q0x2 += w0 * x2;
            q1 += w1; q1x0 += w1 * x0; q1x1 += w1 * x1; q1x2 += w1 * x2;
        }
        for (int m = 32; m >= 1; m >>= 1) {
            q0   += __shfl_xor(q0, m, 64);   q0x0 += __shfl_xor(q0x0, m, 64);
            q0x1 += __shfl_xor(q0x1, m, 64); q0x2 += __shfl_xor(q0x2, m, 64);
            q1   += __shfl_xor(q1, m, 64);   q1x0 += __shfl_xor(q1x0, m, 64);
            q1x1 += __shfl_xor(q1x1, m, 64); q1x2 += __shfl_xor(q1x2, m, 64);
        }
        float den = head ? q1 : q0;
        float AX0 = head ? q1x0 : q0x0;
        float AX1 = head ? q1x1 : q0x1;
        float AX2 = head ? q1x2 : q0x2;
        float v = (w10 * AX0 + w11 * AX1 + w12 * AX2) / (den + 1e-16f);
        float other = __shfl(v, lane ^ 32, 64);
        float g = fmaxf(0.5f * (v + other) + b1v, 0.f);  // mean heads + bias + relu
        if (lane < 32) g1[(size_t)dst * 32 + c] = g;
        float ps = g * usv, pd = g * udv;
        for (int m = 16; m >= 1; m >>= 1) {
            ps += __shfl_xor(ps, m, 64);
            pd += __shfl_xor(pd, m, 64);
        }
        if (c == 0) {
            ss2[dst * 2 + head] = ps;
            sd2[dst * 2 + head] = pd;
        }
    }
}

// ---------------- GAT2 aggregate + W2 epilogue + GRU cell ----------------
// Phase1: lane e loads edge e's (src, both head weights) — coalesced/gathered 64-wide.
// Phase2: 4 groups x 16 lanes; group g takes edges 4i+g, each lane a float2 of g1[s]
// (full 128B line per group) -> 4 independent cache lines per load instruction.
__global__ __launch_bounds__(256) void aggB_kernel(
        const int* __restrict__ rowptr, const int* __restrict__ csr,
        const float* __restrict__ g1,
        const float* __restrict__ ss2, const float* __restrict__ sd2,
        const float* __restrict__ W2, const float* __restrict__ b2,
        const float* __restrict__ w_ih, const float* __restrict__ w_hh,
        const float* __restrict__ b_ih, const float* __restrict__ b_hh,
        float* __restrict__ hstate, int N, int first) {
    __shared__ float w2T[32 * 64];   // w2T[k*64+l] = W2[l*32+k]
    __shared__ float wih[32 * 96];   // wih[k*96+r] = w_ih[r*32+k]
    __shared__ float whh[32 * 96];
    for (int i = threadIdx.x; i < 2048; i += 256) {
        int k = i >> 6, l = i & 63;
        w2T[i] = W2[l * 32 + k];
    }
    for (int i = threadIdx.x; i < 3072; i += 256) {
        int k = i / 96, r = i % 96;
        wih[i] = w_ih[r * 32 + k];
        whh[i] = w_hh[r * 32 + k];
    }
    __syncthreads();
    int lane = threadIdx.x & 63;
    int c = lane & 31;
    bool hi = lane >= 32;
    int grp = lane >> 4;   // 0..3: which edge of each 4-pack
    int t = lane & 15;     // channel-pair index: channels 2t, 2t+1
    float b2v = b2[c];
    int gw = blockIdx.x * 4 + (threadIdx.x >> 6);
    int nw = gridDim.x * 4;
    for (int dst = gw; dst < N; dst += nw) {
        int rs = rowptr[dst], re = rowptr[dst + 1];
        int deg = re - rs;
        float sd0 = sd2[dst * 2], sd1v = sd2[dst * 2 + 1];
        float den0 = 0.f, den1 = 0.f;
        float a00 = 0.f, a01 = 0.f, a10 = 0.f, a11 = 0.f;
        for (int base = 0; base < deg; base += 64) {
            int idx = base + lane;
            bool valid = idx < deg;
            int s_l = valid ? csr[rs + idx] : 0;
            float2 sc = ((const float2*)ss2)[s_l];
            float w0 = valid ? __expf(lrelu(sc.x + sd0)) : 0.f;
            float w1 = valid ? __expf(lrelu(sc.y + sd1v)) : 0.f;
            den0 += w0; den1 += w1;
            int cnt = min(deg - base, 64);
            int iters = (cnt + 3) >> 2;
#pragma unroll 4
            for (int i = 0; i < iters; i++) {
                int e = (i << 2) + grp;          // e <= 63 always
                int s = __shfl(s_l, e, 64);      // invalid edges: s=0, w=0 (branch-free tail)
                float w0e = __shfl(w0, e, 64);
                float w1e = __shfl(w1, e, 64);
                const float2 gv = *(const float2*)(g1 + (size_t)s * 32 + (t << 1));
                a00 += w0e * gv.x; a01 += w0e * gv.y;
                a10 += w1e * gv.x; a11 += w1e * gv.y;
            }
        }
        for (int m = 32; m >= 1; m >>= 1) {
            den0 += __shfl_xor(den0, m, 64);
            den1 += __shfl_xor(den1, m, 64);
        }
        // sum the 4 groups (lanes sharing t)
        for (int m = 32; m >= 16; m >>= 1) {
            a00 += __shfl_xor(a00, m, 64);
            a01 += __shfl_xor(a01, m, 64);
            a10 += __shfl_xor(a10, m, 64);
            a11 += __shfl_xor(a11, m, 64);
        }
        // redistribute: lane (head hi, channel c) <- component (c&1) of pair t=c>>1
        int srcl = c >> 1;
        float r00 = __shfl(a00, srcl, 64);
        float r01 = __shfl(a01, srcl, 64);
        float r10 = __shfl(a10, srcl, 64);
        float r11 = __shfl(a11, srcl, 64);
        float num = hi ? ((c & 1) ? r11 : r10) : ((c & 1) ? r01 : r00);
        float den = hi ? den1 : den0;
        float r = num / (den + 1e-16f);  // agg_head[c] at lane head*32+c
        // h2agg[lane] = sum_k W2[lane,k] * agg_head[k]
        float hv = 0.f;
#pragma unroll
        for (int k = 0; k < 32; k++) hv += w2T[k * 64 + lane] * __shfl(r, (lane & 32) | k, 64);
        float otherh = __shfl(hv, lane ^ 32, 64);
        float g = fmaxf(0.5f * (hv + otherh) + b2v, 0.f);  // GAT2 output channel c
        // ---- GRU cell: lanes 0-31 input gates, 32-63 hidden gates ----
        float hold = first ? 0.f : hstate[(size_t)dst * 32 + c];
        float a0, a1v, a2v;
        if (!hi) { a0 = b_ih[c]; a1v = b_ih[32 + c]; a2v = b_ih[64 + c]; }
        else     { a0 = b_hh[c]; a1v = b_hh[32 + c]; a2v = b_hh[64 + c]; }
        const float* wt = hi ? whh : wih;
        float bc = hi ? hold : g;
        int base = hi ? 32 : 0;
#pragma unroll
        for (int k = 0; k < 32; k++) {
            float v = __shfl(bc, base + k, 64);
            a0  += wt[k * 96 + c]      * v;
            a1v += wt[k * 96 + 32 + c] * v;
            a2v += wt[k * 96 + 64 + c] * v;
        }
        float hr = __shfl(a0, c + 32, 64);
        float hz = __shfl(a1v, c + 32, 64);
        float hn = __shfl(a2v, c + 32, 64);
        if (!hi) {
            float rr = sigmoidf(a0 + hr);
            float zz = sigmoidf(a1v + hz);
            float cand = tanhf(a2v + rr * hn);
            float hnew = (1.f - zz) * cand + zz * hold;
            hstate[(size_t)dst * 32 + c] = hnew;
        }
    }
}

// ---------------- final Linear(hid,1) ----------------
__global__ __launch_bounds__(256) void final_kernel(
        const float* __restrict__ hstate, const float* __restrict__ fc_w,
        const float* __restrict__ fc_b, float* __restrict__ out, int N) {
    int tid = blockIdx.x * 256 + threadIdx.x;
    int node = tid >> 5;
    int c = tid & 31;
    if (node >= N) return;
    float v = hstate[(size_t)node * 32 + c] * fc_w[c];
    for (int m = 16; m >= 1; m >>= 1) v += __shfl_xor(v, m, 64);
    if (c == 0) out[node] = v + fc_b[0];
}

extern "C" void kernel_launch(void* const* d_in, const int* in_sizes, int n_in,
                              void* d_out, int out_size, void* d_ws, size_t ws_size,
                              hipStream_t stream) {
    const float* x_seq = (const float*)d_in[0];
    const float* W1  = (const float*)d_in[1];
    const float* a1s = (const float*)d_in[2];
    const float* a1d = (const float*)d_in[3];
    const float* b1  = (const float*)d_in[4];
    const float* W2  = (const float*)d_in[5];
    const float* a2s = (const float*)d_in[6];
    const float* a2d = (const float*)d_in[7];
    const float* b2  = (const float*)d_in[8];
    const float* w_ih = (const float*)d_in[9];
    const float* w_hh = (const float*)d_in[10];
    const float* b_ih = (const float*)d_in[11];
    const float* b_hh = (const float*)d_in[12];
    const float* fc_w = (const float*)d_in[13];
    const float* fc_b = (const float*)d_in[14];
    const void*  ei   = d_in[15];

    const int N = in_sizes[0] / (T_STEPS * FIN);  // 50000
    const int E = in_sizes[15] / 2;               // 800000
    const int NE = E + N;

    char* ws = (char*)d_ws;
    size_t off = 0;
    auto alloc = [&](size_t bytes) -> void* {
        void* p = ws + off;
        off += (bytes + 255) & ~(size_t)255;
        return p;
    };
    int*   flag   = (int*)alloc(4);
    int*   rowptr = (int*)alloc((size_t)(N + 1) * 4);
    int*   cnt    = (int*)alloc((size_t)N * 4);        // reused as fill cursor
    int*   csr    = (int*)alloc((size_t)NE * 4);
    float* ss1    = (float*)alloc((size_t)N * 2 * 4);
    float* sd1    = (float*)alloc((size_t)N * 2 * 4);
    float* ss2    = (float*)alloc((size_t)N * 2 * 4);
    float* sd2    = (float*)alloc((size_t)N * 2 * 4);
    float* g1     = (float*)alloc((size_t)N * 32 * 4);
    float* hst    = (float*)alloc((size_t)N * 32 * 4);
    float* u_s    = (float*)alloc(64 * 4);
    float* u_d    = (float*)alloc(64 * 4);
    if (off > ws_size) return;  // workspace too small — cannot proceed safely

    const int AGG_BLOCKS = 2048;

    // ---- preprocessing: CSR by destination (reused for all 16 aggregations) ----
    detect_kernel<<<1, 128, 0, stream>>>((const int*)ei, in_sizes[15], flag);
    init_kernel<<<(N + 255) / 256, 256, 0, stream>>>(cnt, N);
    count_kernel<<<(E + 255) / 256, 256, 0, stream>>>(ei, flag, E, N, cnt);
    scan_kernel<<<1, 1024, 0, stream>>>(cnt, rowptr, N);
    selffill_kernel<<<(N + 255) / 256, 256, 0, stream>>>(rowptr, csr, cnt, N);
    scatter_kernel<<<(E + 255) / 256, 256, 0, stream>>>(ei, flag, E, N, cnt, csr);
    prep_u_kernel<<<1, 64, 0, stream>>>(W2, a2s, a2d, u_s, u_d);

    // ---- T timesteps ----
    for (int t = 0; t < T_STEPS; t++) {
        const float* xt = x_seq + (size_t)t * N * FIN;
        score1_kernel<<<(N * 64 + 255) / 256, 256, 0, stream>>>(xt, W1, a1s, a1d, ss1, sd1, N);
        aggA_kernel<<<AGG_BLOCKS, 256, 0, stream>>>(rowptr, csr, xt, ss1, sd1, W1, b1,
                                                    u_s, u_d, g1, ss2, sd2, N);
        aggB_kernel<<<AGG_BLOCKS, 256, 0, stream>>>(rowptr, csr, g1, ss2, sd2, W2, b2,
                                                    w_ih, w_hh, b_ih, b_hh, hst, N,
                                                    t == 0 ? 1 : 0);
    }
    final_kernel<<<(N * 32 + 255) / 256, 256, 0, stream>>>(hst, fc_w, fc_b, (float*)d_out, N);
}

// Round 4
// 1403.720 us; speedup vs baseline: 2.7460x; 1.1810x over previous
//
#include <hip/hip_runtime.h>
#include <hip/hip_fp16.h>
#include <stdint.h>

#define T_STEPS 8
#define FIN 3
#define HID 32
#define NEG_SLOPE 0.2f

__device__ __forceinline__ float lrelu(float x) { return x > 0.f ? x : NEG_SLOPE * x; }
__device__ __forceinline__ float sigmoidf(float x) { return 1.f / (1.f + __expf(-x)); }

// ---------------- edge dtype detection (int64 vs int32) ----------------
__global__ void detect_kernel(const int* ei32, int nElems, int* flag) {
    __shared__ int any_nonzero;
    if (threadIdx.x == 0) any_nonzero = 0;
    __syncthreads();
    int idx = 1 + 2 * (int)threadIdx.x;  // odd int32 slots
    if (idx < nElems && ei32[idx] != 0) any_nonzero = 1;  // benign race
    __syncthreads();
    if (threadIdx.x == 0) *flag = (any_nonzero ? 0 : 1);  // 1 => int64
}

__device__ __forceinline__ int get_edge(const void* ei, int is64, long long idx) {
    if (is64) return (int)((const long long*)ei)[idx];
    return ((const int*)ei)[idx];
}

// ---------------- CSR build ----------------
__global__ void init_kernel(int* cnt, int N) {
    int i = blockIdx.x * 256 + threadIdx.x;
    if (i < N) cnt[i] = 1;  // self-loop pre-counted
}

__global__ void count_kernel(const void* ei, const int* flag, int E, int N, int* cnt) {
    int e = blockIdx.x * 256 + threadIdx.x;
    if (e >= E) return;
    int is64 = *flag;
    int d = get_edge(ei, is64, (long long)E + e);
    if ((unsigned)d < (unsigned)N) atomicAdd(&cnt[d], 1);
}

__global__ __launch_bounds__(1024) void scan_kernel(const int* cnt, int* rowptr, int n) {
    __shared__ int sm[1024];
    __shared__ int carry;
    int tid = threadIdx.x;
    if (tid == 0) { carry = 0; rowptr[0] = 0; }
    __syncthreads();
    for (int base = 0; base < n; base += 1024) {
        int i = base + tid;
        int v = (i < n) ? cnt[i] : 0;
        sm[tid] = v;
        __syncthreads();
        for (int off = 1; off < 1024; off <<= 1) {
            int t = (tid >= off) ? sm[tid - off] : 0;
            __syncthreads();
            sm[tid] += t;
            __syncthreads();
        }
        int inc = sm[tid] + carry;
        if (i < n) rowptr[i + 1] = inc;
        __syncthreads();
        if (tid == 1023) carry = inc;
        __syncthreads();
    }
}

__global__ void selffill_kernel(const int* rowptr, int* csr, int* fill, int N) {
    int n = blockIdx.x * 256 + threadIdx.x;
    if (n >= N) return;
    int rp = rowptr[n];
    csr[rp] = n;        // self-loop occupies slot 0 of each row
    fill[n] = rp + 1;
}

__global__ void scatter_kernel(const void* ei, const int* flag, int E, int N, int* fill, int* csr) {
    int e = blockIdx.x * 256 + threadIdx.x;
    if (e >= E) return;
    int is64 = *flag;
    int s = get_edge(ei, is64, e);
    int d = get_edge(ei, is64, (long long)E + e);
    if ((unsigned)d >= (unsigned)N) return;
    if ((unsigned)s >= (unsigned)N) s = 0;  // safety clamp
    int p = atomicAdd(&fill[d], 1);
    csr[p] = s;
}

// ---------------- precompute u = W2^T a2 per head (for layer-2 scores) ----------------
__global__ __launch_bounds__(64) void prep_u_kernel(
        const float* __restrict__ W2, const float* __restrict__ a2s,
        const float* __restrict__ a2d, float* __restrict__ u_s, float* __restrict__ u_d) {
    int l = threadIdx.x;  // 0..63
    int h = l >> 5, k = l & 31;
    float us = 0.f, ud = 0.f;
    for (int c = 0; c < 32; c++) {
        float w = W2[(h * 32 + c) * 32 + k];
        us += a2s[h * 32 + c] * w;
        ud += a2d[h * 32 + c] * w;
    }
    u_s[l] = us;
    u_d[l] = ud;
}

// ---------------- layer-1 scores + packed node record {x0,x1,x2,ss1_0,ss1_1} (32B stride) ----------------
__global__ __launch_bounds__(256) void score1_kernel(
        const float* __restrict__ x, const float* __restrict__ W1,
        const float* __restrict__ a1s, const float* __restrict__ a1d,
        float* __restrict__ nrec, float* __restrict__ sd1, int N) {
    int tid = blockIdx.x * 256 + threadIdx.x;
    int node = tid >> 6;
    int lane = threadIdx.x & 63;
    if (node >= N) return;
    const float* xp = x + (size_t)node * FIN;
    float x0 = xp[0], x1 = xp[1], x2 = xp[2];
    float h = W1[lane * 3] * x0 + W1[lane * 3 + 1] * x1 + W1[lane * 3 + 2] * x2;
    float ps = h * a1s[lane], pd = h * a1d[lane];
    for (int m = 16; m >= 1; m >>= 1) {
        ps += __shfl_xor(ps, m, 64);
        pd += __shfl_xor(pd, m, 64);
    }
    if (lane == 0) {
        float4 r; r.x = x0; r.y = x1; r.z = x2; r.w = ps;
        ((float4*)nrec)[node * 2] = r;
        sd1[node * 2] = pd;
    } else if (lane == 32) {
        nrec[node * 8 + 4] = ps;
        sd1[node * 2 + 1] = pd;
    }
}

// ---------------- GAT1 aggregate (packed 1-line gathers) + GAT2 scores + g1->fp16 ----------------
__global__ __launch_bounds__(256) void aggA_kernel(
        const int* __restrict__ rowptr, const int* __restrict__ csr,
        const float* __restrict__ nrec, const float* __restrict__ sd1,
        const float* __restrict__ W1, const float* __restrict__ b1,
        const float* __restrict__ u_s, const float* __restrict__ u_d,
        __half2* __restrict__ g1h, float* __restrict__ ssd2, float* __restrict__ sd2, int N) {
    int lane = threadIdx.x & 63;
    int head = lane >> 5;
    int c = lane & 31;
    float w10 = W1[lane * 3], w11 = W1[lane * 3 + 1], w12 = W1[lane * 3 + 2];
    float b1v = b1[c];
    float usv = u_s[lane], udv = u_d[lane];
    // contiguous dst chunk per wave: adjacent csr ranges -> L2-local phase-1 loads
    int wid = blockIdx.x * 4 + (threadIdx.x >> 6);
    int nwv = gridDim.x * 4;
    int K = (N + nwv - 1) / nwv;
    int d0 = wid * K, d1 = min(d0 + K, N);
    for (int dst = d0; dst < d1; dst++) {
        int rs = rowptr[dst], re = rowptr[dst + 1];
        int deg = re - rs;
        float sd0 = sd1[dst * 2], sd1v = sd1[dst * 2 + 1];
        float q0 = 0.f, q0x0 = 0.f, q0x1 = 0.f, q0x2 = 0.f;
        float q1 = 0.f, q1x0 = 0.f, q1x1 = 0.f, q1x2 = 0.f;
        for (int base = 0; base < deg; base += 64) {
            int idx = base + lane;
            bool valid = idx < deg;
            int s = valid ? csr[rs + idx] : 0;
            float4 r0 = ((const float4*)nrec)[(size_t)s * 2];
            float s5 = nrec[(size_t)s * 8 + 4];
            float w0 = valid ? __expf(lrelu(r0.w + sd0)) : 0.f;   // bounded scores
            float w1 = valid ? __expf(lrelu(s5 + sd1v)) : 0.f;    // -> shift-free softmax
            q0 += w0; q0x0 += w0 * r0.x; q0x1 += w0 * r0.y; q0x2 += w0 * r0.z;
            q1 += w1; q1x0 += w1 * r0.x; q1x1 += w1 * r0.y; q1x2 += w1 * r0.z;
        }
        for (int m = 32; m >= 1; m >>= 1) {
            q0   += __shfl_xor(q0, m, 64);   q0x0 += __shfl_xor(q0x0, m, 64);
            q0x1 += __shfl_xor(q0x1, m, 64); q0x2 += __shfl_xor(q0x2, m, 64);
            q1   += __shfl_xor(q1, m, 64);   q1x0 += __shfl_xor(q1x0, m, 64);
            q1x1 += __shfl_xor(q1x1, m, 64); q1x2 += __shfl_xor(q1x2, m, 64);
        }
        float den = head ? q1 : q0;
        float AX0 = head ? q1x0 : q0x0;
        float AX1 = head ? q1x1 : q0x1;
        float AX2 = head ? q1x2 : q0x2;
        float v = (w10 * AX0 + w11 * AX1 + w12 * AX2) / (den + 1e-16f);
        float other = __shfl(v, lane ^ 32, 64);
        float g = fmaxf(0.5f * (v + other) + b1v, 0.f);  // mean heads + bias + relu
        // pack g1 as half2: slot t holds channels {2t, 2t+1}
        float e0 = __shfl(g, (lane & 15) * 2, 64);
        float e1 = __shfl(g, (lane & 15) * 2 + 1, 64);
        if (lane < 16) g1h[(size_t)dst * 16 + lane] = __floats2half2_rn(e0, e1);
        float ps = g * usv, pd = g * udv;
        for (int m = 16; m >= 1; m >>= 1) {
            ps += __shfl_xor(ps, m, 64);
            pd += __shfl_xor(pd, m, 64);
        }
        if (c == 0) {
            ssd2[dst * 2 + head] = ps;
            sd2[dst * 2 + head] = pd;
        }
    }
}

// ---------------- GAT2 aggregate only (lean: no LDS, <=64 VGPR, 8 waves/SIMD) ----------------
// Phase2: 4 groups x 16 lanes; group g takes edges 4i+g, lane t reads half2 {2t,2t+1}
// of g1h[s] -> one 64B line per edge. Writes agg[dst*64+lane] = num/den per head/channel.
__global__ __launch_bounds__(256, 8) void aggB_gather(
        const int* __restrict__ rowptr, const int* __restrict__ csr,
        const __half2* __restrict__ g1h,
        const float* __restrict__ ssd2, const float* __restrict__ sd2,
        float* __restrict__ agg, int N) {
    int lane = threadIdx.x & 63;
    int c = lane & 31;
    bool hi = lane >= 32;
    int grp = lane >> 4;   // 0..3: which edge of each 4-pack
    int t = lane & 15;     // channel-pair index
    int wid = blockIdx.x * 4 + (threadIdx.x >> 6);
    int nwv = gridDim.x * 4;
    int K = (N + nwv - 1) / nwv;
    int dlo = wid * K, dhi = min(dlo + K, N);
    for (int dst = dlo; dst < dhi; dst++) {
        int rs = rowptr[dst], re = rowptr[dst + 1];
        int deg = re - rs;
        float sd0 = sd2[dst * 2], sd1v = sd2[dst * 2 + 1];
        float den0 = 0.f, den1 = 0.f;
        float a00 = 0.f, a01 = 0.f, a10 = 0.f, a11 = 0.f;
        for (int base = 0; base < deg; base += 64) {
            int idx = base + lane;
            bool valid = idx < deg;
            int s_l = valid ? csr[rs + idx] : 0;
            float2 sc = ((const float2*)ssd2)[s_l];
            float w0 = valid ? __expf(lrelu(sc.x + sd0)) : 0.f;
            float w1 = valid ? __expf(lrelu(sc.y + sd1v)) : 0.f;
            den0 += w0; den1 += w1;
            int cnt = min(deg - base, 64);
            int iters = (cnt + 3) >> 2;
#pragma unroll 4
            for (int i = 0; i < iters; i++) {
                int e = (i << 2) + grp;          // e <= 63 always
                int s = __shfl(s_l, e, 64);      // invalid edges: s=0, w=0 (branch-free tail)
                float w0e = __shfl(w0, e, 64);
                float w1e = __shfl(w1, e, 64);
                float2 gv = __half22float2(g1h[(size_t)s * 16 + t]);
                a00 += w0e * gv.x; a01 += w0e * gv.y;
                a10 += w1e * gv.x; a11 += w1e * gv.y;
            }
        }
        for (int m = 32; m >= 1; m >>= 1) {
            den0 += __shfl_xor(den0, m, 64);
            den1 += __shfl_xor(den1, m, 64);
        }
        for (int m = 32; m >= 16; m >>= 1) {
            a00 += __shfl_xor(a00, m, 64);
            a01 += __shfl_xor(a01, m, 64);
            a10 += __shfl_xor(a10, m, 64);
            a11 += __shfl_xor(a11, m, 64);
        }
        // lane (head hi, channel c) <- component (c&1) of pair t=c>>1
        int srcl = c >> 1;
        float r00 = __shfl(a00, srcl, 64);
        float r01 = __shfl(a01, srcl, 64);
        float r10 = __shfl(a10, srcl, 64);
        float r11 = __shfl(a11, srcl, 64);
        float num = hi ? ((c & 1) ? r11 : r10) : ((c & 1) ? r01 : r00);
        float den = hi ? den1 : den0;
        agg[(size_t)dst * 64 + lane] = num / (den + 1e-16f);
    }
}

// ---------------- dense epilogue: W2 + mean-heads + relu + GRU cell (streaming) ----------------
__global__ __launch_bounds__(256) void gru_kernel(
        const float* __restrict__ agg,
        const float* __restrict__ W2, const float* __restrict__ b2,
        const float* __restrict__ w_ih, const float* __restrict__ w_hh,
        const float* __restrict__ b_ih, const float* __restrict__ b_hh,
        float* __restrict__ hstate, int N, int first) {
    __shared__ float w2T[32 * 64];   // w2T[k*64+l] = W2[l*32+k]
    __shared__ float wih[32 * 96];   // wih[k*96+r] = w_ih[r*32+k]
    __shared__ float whh[32 * 96];
    for (int i = threadIdx.x; i < 2048; i += 256) {
        int k = i >> 6, l = i & 63;
        w2T[i] = W2[l * 32 + k];
    }
    for (int i = threadIdx.x; i < 3072; i += 256) {
        int k = i / 96, r = i % 96;
        wih[i] = w_ih[r * 32 + k];
        whh[i] = w_hh[r * 32 + k];
    }
    __syncthreads();
    int lane = threadIdx.x & 63;
    int c = lane & 31;
    bool hi = lane >= 32;
    float b2v = b2[c];
    int gw = blockIdx.x * 4 + (threadIdx.x >> 6);
    int nw = gridDim.x * 4;
    for (int dst = gw; dst < N; dst += nw) {
        float r = agg[(size_t)dst * 64 + lane];  // agg_head[c] at lane head*32+c
        float hv = 0.f;
#pragma unroll
        for (int k = 0; k < 32; k++) hv += w2T[k * 64 + lane] * __shfl(r, (lane & 32) | k, 64);
        float otherh = __shfl(hv, lane ^ 32, 64);
        float g = fmaxf(0.5f * (hv + otherh) + b2v, 0.f);  // GAT2 output channel c
        float hold = first ? 0.f : hstate[(size_t)dst * 32 + c];
        float a0, a1v, a2v;
        if (!hi) { a0 = b_ih[c]; a1v = b_ih[32 + c]; a2v = b_ih[64 + c]; }
        else     { a0 = b_hh[c]; a1v = b_hh[32 + c]; a2v = b_hh[64 + c]; }
        const float* wt = hi ? whh : wih;
        float bc = hi ? hold : g;
        int base = hi ? 32 : 0;
#pragma unroll
        for (int k = 0; k < 32; k++) {
            float v = __shfl(bc, base + k, 64);
            a0  += wt[k * 96 + c]      * v;
            a1v += wt[k * 96 + 32 + c] * v;
            a2v += wt[k * 96 + 64 + c] * v;
        }
        float hr = __shfl(a0, c + 32, 64);
        float hz = __shfl(a1v, c + 32, 64);
        float hn = __shfl(a2v, c + 32, 64);
        if (!hi) {
            float rr = sigmoidf(a0 + hr);
            float zz = sigmoidf(a1v + hz);
            float cand = tanhf(a2v + rr * hn);
            float hnew = (1.f - zz) * cand + zz * hold;
            hstate[(size_t)dst * 32 + c] = hnew;
        }
    }
}

// ---------------- final Linear(hid,1) ----------------
__global__ __launch_bounds__(256) void final_kernel(
        const float* __restrict__ hstate, const float* __restrict__ fc_w,
        const float* __restrict__ fc_b, float* __restrict__ out, int N) {
    int tid = blockIdx.x * 256 + threadIdx.x;
    int node = tid >> 5;
    int c = tid & 31;
    if (node >= N) return;
    float v = hstate[(size_t)node * 32 + c] * fc_w[c];
    for (int m = 16; m >= 1; m >>= 1) v += __shfl_xor(v, m, 64);
    if (c == 0) out[node] = v + fc_b[0];
}

extern "C" void kernel_launch(void* const* d_in, const int* in_sizes, int n_in,
                              void* d_out, int out_size, void* d_ws, size_t ws_size,
                              hipStream_t stream) {
    const float* x_seq = (const float*)d_in[0];
    const float* W1  = (const float*)d_in[1];
    const float* a1s = (const float*)d_in[2];
    const float* a1d = (const float*)d_in[3];
    const float* b1  = (const float*)d_in[4];
    const float* W2  = (const float*)d_in[5];
    const float* a2s = (const float*)d_in[6];
    const float* a2d = (const float*)d_in[7];
    const float* b2  = (const float*)d_in[8];
    const float* w_ih = (const float*)d_in[9];
    const float* w_hh = (const float*)d_in[10];
    const float* b_ih = (const float*)d_in[11];
    const float* b_hh = (const float*)d_in[12];
    const float* fc_w = (const float*)d_in[13];
    const float* fc_b = (const float*)d_in[14];
    const void*  ei   = d_in[15];

    const int N = in_sizes[0] / (T_STEPS * FIN);  // 50000
    const int E = in_sizes[15] / 2;               // 800000
    const int NE = E + N;

    char* ws = (char*)d_ws;
    size_t off = 0;
    auto alloc = [&](size_t bytes) -> void* {
        void* p = ws + off;
        off += (bytes + 255) & ~(size_t)255;
        return p;
    };
    int*     flag   = (int*)alloc(4);
    int*     rowptr = (int*)alloc((size_t)(N + 1) * 4);
    int*     cnt    = (int*)alloc((size_t)N * 4);        // reused as fill cursor
    int*     csr    = (int*)alloc((size_t)NE * 4);
    float*   nrec   = (float*)alloc((size_t)N * 8 * 4);  // packed {x0,x1,x2,ss1_0,ss1_1}, 32B stride
    float*   sd1    = (float*)alloc((size_t)N * 2 * 4);
    float*   ssd2   = (float*)alloc((size_t)N * 2 * 4);
    float*   sd2    = (float*)alloc((size_t)N * 2 * 4);
    __half2* g1h    = (__half2*)alloc((size_t)N * 16 * 4);  // fp16 g1: 64B/node, L2-resident
    float*   agg    = (float*)alloc((size_t)N * 64 * 4);
    float*   hst    = (float*)alloc((size_t)N * 32 * 4);
    float*   u_s    = (float*)alloc(64 * 4);
    float*   u_d    = (float*)alloc(64 * 4);
    if (off > ws_size) return;  // workspace too small — cannot proceed safely

    const int AGG_BLOCKS = 2048;

    // ---- preprocessing: CSR by destination (reused for all 16 aggregations) ----
    detect_kernel<<<1, 128, 0, stream>>>((const int*)ei, in_sizes[15], flag);
    init_kernel<<<(N + 255) / 256, 256, 0, stream>>>(cnt, N);
    count_kernel<<<(E + 255) / 256, 256, 0, stream>>>(ei, flag, E, N, cnt);
    scan_kernel<<<1, 1024, 0, stream>>>(cnt, rowptr, N);
    selffill_kernel<<<(N + 255) / 256, 256, 0, stream>>>(rowptr, csr, cnt, N);
    scatter_kernel<<<(E + 255) / 256, 256, 0, stream>>>(ei, flag, E, N, cnt, csr);
    prep_u_kernel<<<1, 64, 0, stream>>>(W2, a2s, a2d, u_s, u_d);

    // ---- T timesteps ----
    for (int t = 0; t < T_STEPS; t++) {
        const float* xt = x_seq + (size_t)t * N * FIN;
        score1_kernel<<<(N * 64 + 255) / 256, 256, 0, stream>>>(xt, W1, a1s, a1d, nrec, sd1, N);
        aggA_kernel<<<AGG_BLOCKS, 256, 0, stream>>>(rowptr, csr, nrec, sd1, W1, b1,
                                                    u_s, u_d, g1h, ssd2, sd2, N);
        aggB_gather<<<AGG_BLOCKS, 256, 0, stream>>>(rowptr, csr, g1h, ssd2, sd2, agg, N);
        gru_kernel<<<AGG_BLOCKS, 256, 0, stream>>>(agg, W2, b2, w_ih, w_hh, b_ih, b_hh,
                                                   hst, N, t == 0 ? 1 : 0);
    }
    final_kernel<<<(N * 32 + 255) / 256, 256, 0, stream>>>(hst, fc_w, fc_b, (float*)d_out, N);
}

// Round 5
// 1380.660 us; speedup vs baseline: 2.7919x; 1.0167x over previous
//
#include <hip/hip_runtime.h>
#include <hip/hip_fp16.h>
#include <stdint.h>

#define T_STEPS 8
#define FIN 3
#define HID 32
#define NEG_SLOPE 0.2f

__device__ __forceinline__ float lrelu(float x) { return x > 0.f ? x : NEG_SLOPE * x; }
__device__ __forceinline__ float sigmoidf(float x) { return 1.f / (1.f + __expf(-x)); }

// ---------------- edge dtype detection (int64 vs int32) ----------------
__global__ void detect_kernel(const int* ei32, int nElems, int* flag) {
    __shared__ int any_nonzero;
    if (threadIdx.x == 0) any_nonzero = 0;
    __syncthreads();
    int idx = 1 + 2 * (int)threadIdx.x;  // odd int32 slots
    if (idx < nElems && ei32[idx] != 0) any_nonzero = 1;  // benign race
    __syncthreads();
    if (threadIdx.x == 0) *flag = (any_nonzero ? 0 : 1);  // 1 => int64
}

__device__ __forceinline__ int get_edge(const void* ei, int is64, long long idx) {
    if (is64) return (int)((const long long*)ei)[idx];
    return ((const int*)ei)[idx];
}

// ---------------- CSR build ----------------
__global__ void init_kernel(int* cnt, int N) {
    int i = blockIdx.x * 256 + threadIdx.x;
    if (i < N) cnt[i] = 1;  // self-loop pre-counted
}

__global__ void count_kernel(const void* ei, const int* flag, int E, int N, int* cnt) {
    int e = blockIdx.x * 256 + threadIdx.x;
    if (e >= E) return;
    int is64 = *flag;
    int d = get_edge(ei, is64, (long long)E + e);
    if ((unsigned)d < (unsigned)N) atomicAdd(&cnt[d], 1);
}

// hierarchical scan: scan1 (per-block inclusive) -> scan2 (block sums) -> scan3 (add offsets)
__global__ __launch_bounds__(256) void scan1_kernel(const int* cnt, int* rowptr, int* bsum, int n) {
    __shared__ int sm[256];
    int i = blockIdx.x * 256 + threadIdx.x;
    int v = (i < n) ? cnt[i] : 0;
    sm[threadIdx.x] = v;
    __syncthreads();
    for (int off = 1; off < 256; off <<= 1) {
        int t = (threadIdx.x >= off) ? sm[threadIdx.x - off] : 0;
        __syncthreads();
        sm[threadIdx.x] += t;
        __syncthreads();
    }
    if (i < n) rowptr[i + 1] = sm[threadIdx.x];
    if (threadIdx.x == 255) bsum[blockIdx.x] = sm[255];
}

__global__ __launch_bounds__(256) void scan2_kernel(int* bsum, int nb) {
    __shared__ int sm[256];
    int v = (threadIdx.x < nb) ? bsum[threadIdx.x] : 0;
    sm[threadIdx.x] = v;
    __syncthreads();
    for (int off = 1; off < 256; off <<= 1) {
        int t = (threadIdx.x >= off) ? sm[threadIdx.x - off] : 0;
        __syncthreads();
        sm[threadIdx.x] += t;
        __syncthreads();
    }
    if (threadIdx.x < nb) bsum[threadIdx.x] = sm[threadIdx.x];
}

__global__ __launch_bounds__(256) void scan3_kernel(int* rowptr, const int* bsum, int n) {
    int i = blockIdx.x * 256 + threadIdx.x;
    if (i < n && blockIdx.x > 0) rowptr[i + 1] += bsum[blockIdx.x - 1];
    if (i == 0) rowptr[0] = 0;
}

__global__ void selffill_kernel(const int* rowptr, int* csr, int* fill, int N) {
    int n = blockIdx.x * 256 + threadIdx.x;
    if (n >= N) return;
    int rp = rowptr[n];
    csr[rp] = n;        // self-loop occupies slot 0 of each row
    fill[n] = rp + 1;
}

__global__ void scatter_kernel(const void* ei, const int* flag, int E, int N, int* fill, int* csr) {
    int e = blockIdx.x * 256 + threadIdx.x;
    if (e >= E) return;
    int is64 = *flag;
    int s = get_edge(ei, is64, e);
    int d = get_edge(ei, is64, (long long)E + e);
    if ((unsigned)d >= (unsigned)N) return;
    if ((unsigned)s >= (unsigned)N) s = 0;  // safety clamp
    int p = atomicAdd(&fill[d], 1);
    csr[p] = s;
}

// ---------------- precompute u = W2^T a2 per head (for layer-2 scores) ----------------
__global__ __launch_bounds__(64) void prep_u_kernel(
        const float* __restrict__ W2, const float* __restrict__ a2s,
        const float* __restrict__ a2d, float* __restrict__ u_s, float* __restrict__ u_d) {
    int l = threadIdx.x;  // 0..63
    int h = l >> 5, k = l & 31;
    float us = 0.f, ud = 0.f;
    for (int c = 0; c < 32; c++) {
        float w = W2[(h * 32 + c) * 32 + k];
        us += a2s[h * 32 + c] * w;
        ud += a2d[h * 32 + c] * w;
    }
    u_s[l] = us;
    u_d[l] = ud;
}

// ---------------- layer-1 scores + packed 16B node record {x0,x1,x2,half2(ss0,ss1)} ----------------
__global__ __launch_bounds__(256) void score1_kernel(
        const float* __restrict__ x, const float* __restrict__ W1,
        const float* __restrict__ a1s, const float* __restrict__ a1d,
        float4* __restrict__ nrec4, float2* __restrict__ sd1, int N) {
    int tid = blockIdx.x * 256 + threadIdx.x;
    int node = tid >> 6;
    int lane = threadIdx.x & 63;
    if (node >= N) return;
    const float* xp = x + (size_t)node * FIN;
    float x0 = xp[0], x1 = xp[1], x2 = xp[2];
    float h = W1[lane * 3] * x0 + W1[lane * 3 + 1] * x1 + W1[lane * 3 + 2] * x2;
    float ps = h * a1s[lane], pd = h * a1d[lane];
    for (int m = 16; m >= 1; m >>= 1) {
        ps += __shfl_xor(ps, m, 64);
        pd += __shfl_xor(pd, m, 64);
    }
    float ps1 = __shfl(ps, 32, 64);
    float pd1 = __shfl(pd, 32, 64);
    if (lane == 0) {
        unsigned u = (unsigned)__half_as_ushort(__float2half_rn(ps)) |
                     ((unsigned)__half_as_ushort(__float2half_rn(ps1)) << 16);
        float4 r;
        r.x = x0; r.y = x1; r.z = x2; r.w = __uint_as_float(u);
        nrec4[node] = r;
        sd1[node] = make_float2(pd, pd1);
    }
}

__device__ __forceinline__ void unpack_scores(float wslot, float& s0, float& s1) {
    unsigned u = __float_as_uint(wslot);
    s0 = __half2float(__ushort_as_half((unsigned short)(u & 0xffffu)));
    s1 = __half2float(__ushort_as_half((unsigned short)(u >> 16)));
}

// ---------------- GAT1 aggregate: 2-row interleave, one 16B gather/edge ----------------
__global__ __launch_bounds__(256, 6) void aggA_kernel(
        const int* __restrict__ rowptr, const int* __restrict__ csr,
        const float4* __restrict__ nrec4, const float2* __restrict__ sd1,
        const float* __restrict__ W1, const float* __restrict__ b1,
        const float* __restrict__ u_s, const float* __restrict__ u_d,
        __half2* __restrict__ g1h, float2* __restrict__ ssd2, float2* __restrict__ sd2, int N) {
    int lane = threadIdx.x & 63;
    int head = lane >> 5;
    int c = lane & 31;
    float w10 = W1[lane * 3], w11 = W1[lane * 3 + 1], w12 = W1[lane * 3 + 2];
    float b1v = b1[c];
    float usv = u_s[lane], udv = u_d[lane];
    int wid = blockIdx.x * 4 + (threadIdx.x >> 6);
    int nwv = gridDim.x * 4;
    int K = (N + nwv - 1) / nwv;
    int dlo = wid * K, dhi = min(dlo + K, N);
    for (int dst = dlo; dst < dhi; dst += 2) {
        bool two = (dst + 1) < dhi;
        int rsA = rowptr[dst], reA = rowptr[dst + 1];
        int reB = two ? rowptr[dst + 2] : reA;
        int degA = reA - rsA, rsB = reA, degB = reB - reA;
        float2 sdA = sd1[dst];
        float2 sdB = two ? sd1[dst + 1] : make_float2(0.f, 0.f);
        float qA0 = 0, qA1 = 0, qA2 = 0, qA3 = 0, qA4 = 0, qA5 = 0, qA6 = 0, qA7 = 0;
        float qB0 = 0, qB1 = 0, qB2 = 0, qB3 = 0, qB4 = 0, qB5 = 0, qB6 = 0, qB7 = 0;
        int degM = max(degA, degB);
        for (int base = 0; base < degM; base += 64) {
            int idx = base + lane;
            bool vA = idx < degA, vB = idx < degB;
            int sA = vA ? csr[rsA + idx] : 0;
            int sB = vB ? csr[rsB + idx] : 0;
            float4 rA = nrec4[sA];
            float4 rB = nrec4[sB];
            float sA0, sA1, sB0, sB1;
            unpack_scores(rA.w, sA0, sA1);
            unpack_scores(rB.w, sB0, sB1);
            float w0A = vA ? __expf(lrelu(sA0 + sdA.x)) : 0.f;
            float w1A = vA ? __expf(lrelu(sA1 + sdA.y)) : 0.f;
            float w0B = vB ? __expf(lrelu(sB0 + sdB.x)) : 0.f;
            float w1B = vB ? __expf(lrelu(sB1 + sdB.y)) : 0.f;
            qA0 += w0A; qA1 += w0A * rA.x; qA2 += w0A * rA.y; qA3 += w0A * rA.z;
            qA4 += w1A; qA5 += w1A * rA.x; qA6 += w1A * rA.y; qA7 += w1A * rA.z;
            qB0 += w0B; qB1 += w0B * rB.x; qB2 += w0B * rB.y; qB3 += w0B * rB.z;
            qB4 += w1B; qB5 += w1B * rB.x; qB6 += w1B * rB.y; qB7 += w1B * rB.z;
        }
        for (int m = 32; m >= 1; m >>= 1) {
            qA0 += __shfl_xor(qA0, m, 64); qA1 += __shfl_xor(qA1, m, 64);
            qA2 += __shfl_xor(qA2, m, 64); qA3 += __shfl_xor(qA3, m, 64);
            qA4 += __shfl_xor(qA4, m, 64); qA5 += __shfl_xor(qA5, m, 64);
            qA6 += __shfl_xor(qA6, m, 64); qA7 += __shfl_xor(qA7, m, 64);
            qB0 += __shfl_xor(qB0, m, 64); qB1 += __shfl_xor(qB1, m, 64);
            qB2 += __shfl_xor(qB2, m, 64); qB3 += __shfl_xor(qB3, m, 64);
            qB4 += __shfl_xor(qB4, m, 64); qB5 += __shfl_xor(qB5, m, 64);
            qB6 += __shfl_xor(qB6, m, 64); qB7 += __shfl_xor(qB7, m, 64);
        }
        {   // row A epilogue
            float den = head ? qA4 : qA0;
            float AX0 = head ? qA5 : qA1;
            float AX1 = head ? qA6 : qA2;
            float AX2 = head ? qA7 : qA3;
            float v = (w10 * AX0 + w11 * AX1 + w12 * AX2) / (den + 1e-16f);
            float other = __shfl(v, lane ^ 32, 64);
            float g = fmaxf(0.5f * (v + other) + b1v, 0.f);
            float e0 = __shfl(g, (lane & 15) * 2, 64);
            float e1 = __shfl(g, (lane & 15) * 2 + 1, 64);
            if (lane < 16) g1h[(size_t)dst * 16 + lane] = __floats2half2_rn(e0, e1);
            float ps = g * usv, pd = g * udv;
            for (int m = 16; m >= 1; m >>= 1) {
                ps += __shfl_xor(ps, m, 64);
                pd += __shfl_xor(pd, m, 64);
            }
            float ps1 = __shfl(ps, 32, 64);
            float pd1 = __shfl(pd, 32, 64);
            if (lane == 0) {
                ssd2[dst] = make_float2(ps, ps1);
                sd2[dst] = make_float2(pd, pd1);
            }
        }
        if (two) {  // row B epilogue
            float den = head ? qB4 : qB0;
            float AX0 = head ? qB5 : qB1;
            float AX1 = head ? qB6 : qB2;
            float AX2 = head ? qB7 : qB3;
            float v = (w10 * AX0 + w11 * AX1 + w12 * AX2) / (den + 1e-16f);
            float other = __shfl(v, lane ^ 32, 64);
            float g = fmaxf(0.5f * (v + other) + b1v, 0.f);
            float e0 = __shfl(g, (lane & 15) * 2, 64);
            float e1 = __shfl(g, (lane & 15) * 2 + 1, 64);
            if (lane < 16) g1h[(size_t)(dst + 1) * 16 + lane] = __floats2half2_rn(e0, e1);
            float ps = g * usv, pd = g * udv;
            for (int m = 16; m >= 1; m >>= 1) {
                ps += __shfl_xor(ps, m, 64);
                pd += __shfl_xor(pd, m, 64);
            }
            float ps1 = __shfl(ps, 32, 64);
            float pd1 = __shfl(pd, 32, 64);
            if (lane == 0) {
                ssd2[dst + 1] = make_float2(ps, ps1);
                sd2[dst + 1] = make_float2(pd, pd1);
            }
        }
    }
}

// ---------------- GAT2 aggregate: 2-row interleave, lean (no LDS) ----------------
__global__ __launch_bounds__(256, 6) void aggB_gather(
        const int* __restrict__ rowptr, const int* __restrict__ csr,
        const __half2* __restrict__ g1h,
        const float2* __restrict__ ssd2, const float2* __restrict__ sd2,
        float* __restrict__ agg, int N) {
    int lane = threadIdx.x & 63;
    int c = lane & 31;
    bool hi = lane >= 32;
    int grp = lane >> 4;   // 0..3: which edge of each 4-pack
    int t = lane & 15;     // channel-pair index
    int wid = blockIdx.x * 4 + (threadIdx.x >> 6);
    int nwv = gridDim.x * 4;
    int K = (N + nwv - 1) / nwv;
    int dlo = wid * K, dhi = min(dlo + K, N);
    for (int dst = dlo; dst < dhi; dst += 2) {
        bool two = (dst + 1) < dhi;
        int rsA = rowptr[dst], reA = rowptr[dst + 1];
        int reB = two ? rowptr[dst + 2] : reA;
        int degA = reA - rsA, rsB = reA, degB = reB - reA;
        float2 sdA = sd2[dst];
        float2 sdB = two ? sd2[dst + 1] : make_float2(0.f, 0.f);
        float denA0 = 0, denA1 = 0, denB0 = 0, denB1 = 0;
        float aA00 = 0, aA01 = 0, aA10 = 0, aA11 = 0;
        float aB00 = 0, aB01 = 0, aB10 = 0, aB11 = 0;
        int degM = max(degA, degB);
        for (int base = 0; base < degM; base += 64) {
            int idx = base + lane;
            bool vA = idx < degA, vB = idx < degB;
            int sAl = vA ? csr[rsA + idx] : 0;
            int sBl = vB ? csr[rsB + idx] : 0;
            float2 scA = ssd2[sAl];
            float2 scB = ssd2[sBl];
            float w0A = vA ? __expf(lrelu(scA.x + sdA.x)) : 0.f;
            float w1A = vA ? __expf(lrelu(scA.y + sdA.y)) : 0.f;
            float w0B = vB ? __expf(lrelu(scB.x + sdB.x)) : 0.f;
            float w1B = vB ? __expf(lrelu(scB.y + sdB.y)) : 0.f;
            denA0 += w0A; denA1 += w1A; denB0 += w0B; denB1 += w1B;
            int cntM = min(degM - base, 64);
            int iters = (cntM + 3) >> 2;
#pragma unroll 4
            for (int i = 0; i < iters; i++) {
                int e = (i << 2) + grp;  // <= 63; out-of-row edges carry w=0, s=0
                int sA = __shfl(sAl, e, 64);
                float w0Ae = __shfl(w0A, e, 64);
                float w1Ae = __shfl(w1A, e, 64);
                float2 gvA = __half22float2(g1h[(size_t)sA * 16 + t]);
                aA00 += w0Ae * gvA.x; aA01 += w0Ae * gvA.y;
                aA10 += w1Ae * gvA.x; aA11 += w1Ae * gvA.y;
                int sB = __shfl(sBl, e, 64);
                float w0Be = __shfl(w0B, e, 64);
                float w1Be = __shfl(w1B, e, 64);
                float2 gvB = __half22float2(g1h[(size_t)sB * 16 + t]);
                aB00 += w0Be * gvB.x; aB01 += w0Be * gvB.y;
                aB10 += w1Be * gvB.x; aB11 += w1Be * gvB.y;
            }
        }
        for (int m = 32; m >= 1; m >>= 1) {
            denA0 += __shfl_xor(denA0, m, 64); denA1 += __shfl_xor(denA1, m, 64);
            denB0 += __shfl_xor(denB0, m, 64); denB1 += __shfl_xor(denB1, m, 64);
        }
        for (int m = 32; m >= 16; m >>= 1) {
            aA00 += __shfl_xor(aA00, m, 64); aA01 += __shfl_xor(aA01, m, 64);
            aA10 += __shfl_xor(aA10, m, 64); aA11 += __shfl_xor(aA11, m, 64);
            aB00 += __shfl_xor(aB00, m, 64); aB01 += __shfl_xor(aB01, m, 64);
            aB10 += __shfl_xor(aB10, m, 64); aB11 += __shfl_xor(aB11, m, 64);
        }
        int srcl = c >> 1;
        {
            float r00 = __shfl(aA00, srcl, 64), r01 = __shfl(aA01, srcl, 64);
            float r10 = __shfl(aA10, srcl, 64), r11 = __shfl(aA11, srcl, 64);
            float num = hi ? ((c & 1) ? r11 : r10) : ((c & 1) ? r01 : r00);
            float den = hi ? denA1 : denA0;
            agg[(size_t)dst * 64 + lane] = num / (den + 1e-16f);
        }
        if (two) {
            float r00 = __shfl(aB00, srcl, 64), r01 = __shfl(aB01, srcl, 64);
            float r10 = __shfl(aB10, srcl, 64), r11 = __shfl(aB11, srcl, 64);
            float num = hi ? ((c & 1) ? r11 : r10) : ((c & 1) ? r01 : r00);
            float den = hi ? denB1 : denB0;
            agg[(size_t)(dst + 1) * 64 + lane] = num / (den + 1e-16f);
        }
    }
}

// ---------------- dense epilogue: W2 + mean-heads + relu + GRU cell (streaming) ----------------
__global__ __launch_bounds__(256) void gru_kernel(
        const float* __restrict__ agg,
        const float* __restrict__ W2, const float* __restrict__ b2,
        const float* __restrict__ w_ih, const float* __restrict__ w_hh,
        const float* __restrict__ b_ih, const float* __restrict__ b_hh,
        float* __restrict__ hstate, int N, int first) {
    __shared__ float w2T[32 * 64];   // w2T[k*64+l] = W2[l*32+k]
    __shared__ float wih[32 * 96];   // wih[k*96+r] = w_ih[r*32+k]
    __shared__ float whh[32 * 96];
    for (int i = threadIdx.x; i < 2048; i += 256) {
        int k = i >> 6, l = i & 63;
        w2T[i] = W2[l * 32 + k];
    }
    for (int i = threadIdx.x; i < 3072; i += 256) {
        int k = i / 96, r = i % 96;
        wih[i] = w_ih[r * 32 + k];
        whh[i] = w_hh[r * 32 + k];
    }
    __syncthreads();
    int lane = threadIdx.x & 63;
    int c = lane & 31;
    bool hi = lane >= 32;
    float b2v = b2[c];
    int gw = blockIdx.x * 4 + (threadIdx.x >> 6);
    int nw = gridDim.x * 4;
    for (int dst = gw; dst < N; dst += nw) {
        float r = agg[(size_t)dst * 64 + lane];  // agg_head[c] at lane head*32+c
        float hv = 0.f;
#pragma unroll
        for (int k = 0; k < 32; k++) hv += w2T[k * 64 + lane] * __shfl(r, (lane & 32) | k, 64);
        float otherh = __shfl(hv, lane ^ 32, 64);
        float g = fmaxf(0.5f * (hv + otherh) + b2v, 0.f);  // GAT2 output channel c
        float hold = first ? 0.f : hstate[(size_t)dst * 32 + c];
        float a0, a1v, a2v;
        if (!hi) { a0 = b_ih[c]; a1v = b_ih[32 + c]; a2v = b_ih[64 + c]; }
        else     { a0 = b_hh[c]; a1v = b_hh[32 + c]; a2v = b_hh[64 + c]; }
        const float* wt = hi ? whh : wih;
        float bc = hi ? hold : g;
        int base = hi ? 32 : 0;
#pragma unroll
        for (int k = 0; k < 32; k++) {
            float v = __shfl(bc, base + k, 64);
            a0  += wt[k * 96 + c]      * v;
            a1v += wt[k * 96 + 32 + c] * v;
            a2v += wt[k * 96 + 64 + c] * v;
        }
        float hr = __shfl(a0, c + 32, 64);
        float hz = __shfl(a1v, c + 32, 64);
        float hn = __shfl(a2v, c + 32, 64);
        if (!hi) {
            float rr = sigmoidf(a0 + hr);
            float zz = sigmoidf(a1v + hz);
            float cand = tanhf(a2v + rr * hn);
            float hnew = (1.f - zz) * cand + zz * hold;
            hstate[(size_t)dst * 32 + c] = hnew;
        }
    }
}

// ---------------- final Linear(hid,1) ----------------
__global__ __launch_bounds__(256) void final_kernel(
        const float* __restrict__ hstate, const float* __restrict__ fc_w,
        const float* __restrict__ fc_b, float* __restrict__ out, int N) {
    int tid = blockIdx.x * 256 + threadIdx.x;
    int node = tid >> 5;
    int c = tid & 31;
    if (node >= N) return;
    float v = hstate[(size_t)node * 32 + c] * fc_w[c];
    for (int m = 16; m >= 1; m >>= 1) v += __shfl_xor(v, m, 64);
    if (c == 0) out[node] = v + fc_b[0];
}

extern "C" void kernel_launch(void* const* d_in, const int* in_sizes, int n_in,
                              void* d_out, int out_size, void* d_ws, size_t ws_size,
                              hipStream_t stream) {
    const float* x_seq = (const float*)d_in[0];
    const float* W1  = (const float*)d_in[1];
    const float* a1s = (const float*)d_in[2];
    const float* a1d = (const float*)d_in[3];
    const float* b1  = (const float*)d_in[4];
    const float* W2  = (const float*)d_in[5];
    const float* a2s = (const float*)d_in[6];
    const float* a2d = (const float*)d_in[7];
    const float* b2  = (const float*)d_in[8];
    const float* w_ih = (const float*)d_in[9];
    const float* w_hh = (const float*)d_in[10];
    const float* b_ih = (const float*)d_in[11];
    const float* b_hh = (const float*)d_in[12];
    const float* fc_w = (const float*)d_in[13];
    const float* fc_b = (const float*)d_in[14];
    const void*  ei   = d_in[15];

    const int N = in_sizes[0] / (T_STEPS * FIN);  // 50000
    const int E = in_sizes[15] / 2;               // 800000
    const int NE = E + N;
    const int NB = (N + 255) / 256;               // scan blocks (196)

    char* ws = (char*)d_ws;
    size_t off = 0;
    auto alloc = [&](size_t bytes) -> void* {
        void* p = ws + off;
        off += (bytes + 255) & ~(size_t)255;
        return p;
    };
    int*     flag   = (int*)alloc(4);
    int*     rowptr = (int*)alloc((size_t)(N + 1) * 4);
    int*     cnt    = (int*)alloc((size_t)N * 4);        // reused as fill cursor
    int*     bsum   = (int*)alloc(256 * 4);
    int*     csr    = (int*)alloc((size_t)NE * 4);
    float4*  nrec4  = (float4*)alloc((size_t)N * 16);    // {x0,x1,x2,half2(ss0,ss1)}
    float2*  sd1    = (float2*)alloc((size_t)N * 8);
    float2*  ssd2   = (float2*)alloc((size_t)N * 8);
    float2*  sd2    = (float2*)alloc((size_t)N * 8);
    __half2* g1h    = (__half2*)alloc((size_t)N * 16 * 4);  // fp16 g1: 64B/node, L2-resident
    float*   agg    = (float*)alloc((size_t)N * 64 * 4);
    float*   hst    = (float*)alloc((size_t)N * 32 * 4);
    float*   u_s    = (float*)alloc(64 * 4);
    float*   u_d    = (float*)alloc(64 * 4);
    if (off > ws_size) return;  // workspace too small — cannot proceed safely

    const int AGG_BLOCKS = 2048;

    // ---- preprocessing: CSR by destination (reused for all 16 aggregations) ----
    detect_kernel<<<1, 128, 0, stream>>>((const int*)ei, in_sizes[15], flag);
    init_kernel<<<NB, 256, 0, stream>>>(cnt, N);
    count_kernel<<<(E + 255) / 256, 256, 0, stream>>>(ei, flag, E, N, cnt);
    scan1_kernel<<<NB, 256, 0, stream>>>(cnt, rowptr, bsum, N);
    scan2_kernel<<<1, 256, 0, stream>>>(bsum, NB);
    scan3_kernel<<<NB, 256, 0, stream>>>(rowptr, bsum, N);
    selffill_kernel<<<NB, 256, 0, stream>>>(rowptr, csr, cnt, N);
    scatter_kernel<<<(E + 255) / 256, 256, 0, stream>>>(ei, flag, E, N, cnt, csr);
    prep_u_kernel<<<1, 64, 0, stream>>>(W2, a2s, a2d, u_s, u_d);

    // ---- T timesteps ----
    for (int t = 0; t < T_STEPS; t++) {
        const float* xt = x_seq + (size_t)t * N * FIN;
        score1_kernel<<<(N * 64 + 255) / 256, 256, 0, stream>>>(xt, W1, a1s, a1d, nrec4, sd1, N);
        aggA_kernel<<<AGG_BLOCKS, 256, 0, stream>>>(rowptr, csr, nrec4, sd1, W1, b1,
                                                    u_s, u_d, g1h, ssd2, sd2, N);
        aggB_gather<<<AGG_BLOCKS, 256, 0, stream>>>(rowptr, csr, g1h, ssd2, sd2, agg, N);
        gru_kernel<<<AGG_BLOCKS, 256, 0, stream>>>(agg, W2, b2, w_ih, w_hh, b_ih, b_hh,
                                                   hst, N, t == 0 ? 1 : 0);
    }
    final_kernel<<<(N * 32 + 255) / 256, 256, 0, stream>>>(hst, fc_w, fc_b, (float*)d_out, N);
}

// Round 6
// 1340.913 us; speedup vs baseline: 2.8746x; 1.0296x over previous
//
#include <hip/hip_runtime.h>
#include <hip/hip_fp16.h>
#include <stdint.h>

#define T_STEPS 8
#define FIN 3
#define HID 32
#define NEG_SLOPE 0.2f

__device__ __forceinline__ float lrelu(float x) { return x > 0.f ? x : NEG_SLOPE * x; }
__device__ __forceinline__ float sigmoidf(float x) { return 1.f / (1.f + __expf(-x)); }

// ---------------- edge dtype detection (int64 vs int32) ----------------
__global__ void detect_kernel(const int* ei32, int nElems, int* flag) {
    __shared__ int any_nonzero;
    if (threadIdx.x == 0) any_nonzero = 0;
    __syncthreads();
    int idx = 1 + 2 * (int)threadIdx.x;  // odd int32 slots
    if (idx < nElems && ei32[idx] != 0) any_nonzero = 1;  // benign race
    __syncthreads();
    if (threadIdx.x == 0) *flag = (any_nonzero ? 0 : 1);  // 1 => int64
}

__device__ __forceinline__ int get_edge(const void* ei, int is64, long long idx) {
    if (is64) return (int)((const long long*)ei)[idx];
    return ((const int*)ei)[idx];
}

// ---------------- CSR build ----------------
__global__ void init_kernel(int* cnt, int N) {
    int i = blockIdx.x * 256 + threadIdx.x;
    if (i < N) cnt[i] = 1;  // self-loop pre-counted
}

__global__ void count_kernel(const void* ei, const int* flag, int E, int N, int* cnt) {
    int e = blockIdx.x * 256 + threadIdx.x;
    if (e >= E) return;
    int is64 = *flag;
    int d = get_edge(ei, is64, (long long)E + e);
    if ((unsigned)d < (unsigned)N) atomicAdd(&cnt[d], 1);
}

// hierarchical scan: scan1 (per-block inclusive) -> scan2 (block sums) -> scan3 (add offsets)
__global__ __launch_bounds__(256) void scan1_kernel(const int* cnt, int* rowptr, int* bsum, int n) {
    __shared__ int sm[256];
    int i = blockIdx.x * 256 + threadIdx.x;
    int v = (i < n) ? cnt[i] : 0;
    sm[threadIdx.x] = v;
    __syncthreads();
    for (int off = 1; off < 256; off <<= 1) {
        int t = (threadIdx.x >= off) ? sm[threadIdx.x - off] : 0;
        __syncthreads();
        sm[threadIdx.x] += t;
        __syncthreads();
    }
    if (i < n) rowptr[i + 1] = sm[threadIdx.x];
    if (threadIdx.x == 255) bsum[blockIdx.x] = sm[255];
}

__global__ __launch_bounds__(256) void scan2_kernel(int* bsum, int nb) {
    __shared__ int sm[256];
    int v = (threadIdx.x < nb) ? bsum[threadIdx.x] : 0;
    sm[threadIdx.x] = v;
    __syncthreads();
    for (int off = 1; off < 256; off <<= 1) {
        int t = (threadIdx.x >= off) ? sm[threadIdx.x - off] : 0;
        __syncthreads();
        sm[threadIdx.x] += t;
        __syncthreads();
    }
    if (threadIdx.x < nb) bsum[threadIdx.x] = sm[threadIdx.x];
}

__global__ __launch_bounds__(256) void scan3_kernel(int* rowptr, const int* bsum, int n) {
    int i = blockIdx.x * 256 + threadIdx.x;
    if (i < n && blockIdx.x > 0) rowptr[i + 1] += bsum[blockIdx.x - 1];
    if (i == 0) rowptr[0] = 0;
}

__global__ void selffill_kernel(const int* rowptr, int* csr, int* fill, int N) {
    int n = blockIdx.x * 256 + threadIdx.x;
    if (n >= N) return;
    int rp = rowptr[n];
    csr[rp] = n;        // self-loop occupies slot 0 of each row
    fill[n] = rp + 1;
}

__global__ void scatter_kernel(const void* ei, const int* flag, int E, int N, int* fill, int* csr) {
    int e = blockIdx.x * 256 + threadIdx.x;
    if (e >= E) return;
    int is64 = *flag;
    int s = get_edge(ei, is64, e);
    int d = get_edge(ei, is64, (long long)E + e);
    if ((unsigned)d >= (unsigned)N) return;
    if ((unsigned)s >= (unsigned)N) s = 0;  // safety clamp
    int p = atomicAdd(&fill[d], 1);
    csr[p] = s;
}

// ---------------- precompute u = W2^T a2 per head (for layer-2 scores) ----------------
__global__ __launch_bounds__(64) void prep_u_kernel(
        const float* __restrict__ W2, const float* __restrict__ a2s,
        const float* __restrict__ a2d, float* __restrict__ u_s, float* __restrict__ u_d) {
    int l = threadIdx.x;  // 0..63
    int h = l >> 5, k = l & 31;
    float us = 0.f, ud = 0.f;
    for (int c = 0; c < 32; c++) {
        float w = W2[(h * 32 + c) * 32 + k];
        us += a2s[h * 32 + c] * w;
        ud += a2d[h * 32 + c] * w;
    }
    u_s[l] = us;
    u_d[l] = ud;
}

// ---------------- layer-1 scores + packed 16B node record {x0,x1,x2,half2(ss0,ss1)} ----------------
__global__ __launch_bounds__(256) void score1_kernel(
        const float* __restrict__ x, const float* __restrict__ W1,
        const float* __restrict__ a1s, const float* __restrict__ a1d,
        float4* __restrict__ nrec4, float2* __restrict__ sd1, int N) {
    int tid = blockIdx.x * 256 + threadIdx.x;
    int node = tid >> 6;
    int lane = threadIdx.x & 63;
    if (node >= N) return;
    const float* xp = x + (size_t)node * FIN;
    float x0 = xp[0], x1 = xp[1], x2 = xp[2];
    float h = W1[lane * 3] * x0 + W1[lane * 3 + 1] * x1 + W1[lane * 3 + 2] * x2;
    float ps = h * a1s[lane], pd = h * a1d[lane];
    for (int m = 16; m >= 1; m >>= 1) {
        ps += __shfl_xor(ps, m, 64);
        pd += __shfl_xor(pd, m, 64);
    }
    float ps1 = __shfl(ps, 32, 64);
    float pd1 = __shfl(pd, 32, 64);
    if (lane == 0) {
        unsigned u = (unsigned)__half_as_ushort(__float2half_rn(ps)) |
                     ((unsigned)__half_as_ushort(__float2half_rn(ps1)) << 16);
        float4 r;
        r.x = x0; r.y = x1; r.z = x2; r.w = __uint_as_float(u);
        nrec4[node] = r;
        sd1[node] = make_float2(pd, pd1);
    }
}

__device__ __forceinline__ void unpack_scores(float wslot, float& s0, float& s1) {
    unsigned u = __float_as_uint(wslot);
    s0 = __half2float(__ushort_as_half((unsigned short)(u & 0xffffu)));
    s1 = __half2float(__ushort_as_half((unsigned short)(u >> 16)));
}

// ---------------- GAT1 aggregate: 2-row interleave, one 16B gather/edge ----------------
__global__ __launch_bounds__(256, 6) void aggA_kernel(
        const int* __restrict__ rowptr, const int* __restrict__ csr,
        const float4* __restrict__ nrec4, const float2* __restrict__ sd1,
        const float* __restrict__ W1, const float* __restrict__ b1,
        const float* __restrict__ u_s, const float* __restrict__ u_d,
        __half2* __restrict__ g1h, float2* __restrict__ ssd2, float2* __restrict__ sd2, int N) {
    int lane = threadIdx.x & 63;
    int head = lane >> 5;
    int c = lane & 31;
    float w10 = W1[lane * 3], w11 = W1[lane * 3 + 1], w12 = W1[lane * 3 + 2];
    float b1v = b1[c];
    float usv = u_s[lane], udv = u_d[lane];
    int wid = blockIdx.x * 4 + (threadIdx.x >> 6);
    int nwv = gridDim.x * 4;
    int K = (N + nwv - 1) / nwv;
    int dlo = wid * K, dhi = min(dlo + K, N);
    for (int dst = dlo; dst < dhi; dst += 2) {
        bool two = (dst + 1) < dhi;
        int rsA = rowptr[dst], reA = rowptr[dst + 1];
        int reB = two ? rowptr[dst + 2] : reA;
        int degA = reA - rsA, rsB = reA, degB = reB - reA;
        float2 sdA = sd1[dst];
        float2 sdB = two ? sd1[dst + 1] : make_float2(0.f, 0.f);
        float qA0 = 0, qA1 = 0, qA2 = 0, qA3 = 0, qA4 = 0, qA5 = 0, qA6 = 0, qA7 = 0;
        float qB0 = 0, qB1 = 0, qB2 = 0, qB3 = 0, qB4 = 0, qB5 = 0, qB6 = 0, qB7 = 0;
        int degM = max(degA, degB);
        for (int base = 0; base < degM; base += 64) {
            int idx = base + lane;
            bool vA = idx < degA, vB = idx < degB;
            int sA = vA ? csr[rsA + idx] : 0;
            int sB = vB ? csr[rsB + idx] : 0;
            float4 rA = nrec4[sA];
            float4 rB = nrec4[sB];
            float sA0, sA1, sB0, sB1;
            unpack_scores(rA.w, sA0, sA1);
            unpack_scores(rB.w, sB0, sB1);
            float w0A = vA ? __expf(lrelu(sA0 + sdA.x)) : 0.f;
            float w1A = vA ? __expf(lrelu(sA1 + sdA.y)) : 0.f;
            float w0B = vB ? __expf(lrelu(sB0 + sdB.x)) : 0.f;
            float w1B = vB ? __expf(lrelu(sB1 + sdB.y)) : 0.f;
            qA0 += w0A; qA1 += w0A * rA.x; qA2 += w0A * rA.y; qA3 += w0A * rA.z;
            qA4 += w1A; qA5 += w1A * rA.x; qA6 += w1A * rA.y; qA7 += w1A * rA.z;
            qB0 += w0B; qB1 += w0B * rB.x; qB2 += w0B * rB.y; qB3 += w0B * rB.z;
            qB4 += w1B; qB5 += w1B * rB.x; qB6 += w1B * rB.y; qB7 += w1B * rB.z;
        }
        for (int m = 32; m >= 1; m >>= 1) {
            qA0 += __shfl_xor(qA0, m, 64); qA1 += __shfl_xor(qA1, m, 64);
            qA2 += __shfl_xor(qA2, m, 64); qA3 += __shfl_xor(qA3, m, 64);
            qA4 += __shfl_xor(qA4, m, 64); qA5 += __shfl_xor(qA5, m, 64);
            qA6 += __shfl_xor(qA6, m, 64); qA7 += __shfl_xor(qA7, m, 64);
            qB0 += __shfl_xor(qB0, m, 64); qB1 += __shfl_xor(qB1, m, 64);
            qB2 += __shfl_xor(qB2, m, 64); qB3 += __shfl_xor(qB3, m, 64);
            qB4 += __shfl_xor(qB4, m, 64); qB5 += __shfl_xor(qB5, m, 64);
            qB6 += __shfl_xor(qB6, m, 64); qB7 += __shfl_xor(qB7, m, 64);
        }
        {   // row A epilogue
            float den = head ? qA4 : qA0;
            float AX0 = head ? qA5 : qA1;
            float AX1 = head ? qA6 : qA2;
            float AX2 = head ? qA7 : qA3;
            float v = (w10 * AX0 + w11 * AX1 + w12 * AX2) / (den + 1e-16f);
            float other = __shfl(v, lane ^ 32, 64);
            float g = fmaxf(0.5f * (v + other) + b1v, 0.f);
            float e0 = __shfl(g, (lane & 15) * 2, 64);
            float e1 = __shfl(g, (lane & 15) * 2 + 1, 64);
            if (lane < 16) g1h[(size_t)dst * 16 + lane] = __floats2half2_rn(e0, e1);
            float ps = g * usv, pd = g * udv;
            for (int m = 16; m >= 1; m >>= 1) {
                ps += __shfl_xor(ps, m, 64);
                pd += __shfl_xor(pd, m, 64);
            }
            float ps1 = __shfl(ps, 32, 64);
            float pd1 = __shfl(pd, 32, 64);
            if (lane == 0) {
                ssd2[dst] = make_float2(ps, ps1);
                sd2[dst] = make_float2(pd, pd1);
            }
        }
        if (two) {  // row B epilogue
            float den = head ? qB4 : qB0;
            float AX0 = head ? qB5 : qB1;
            float AX1 = head ? qB6 : qB2;
            float AX2 = head ? qB7 : qB3;
            float v = (w10 * AX0 + w11 * AX1 + w12 * AX2) / (den + 1e-16f);
            float other = __shfl(v, lane ^ 32, 64);
            float g = fmaxf(0.5f * (v + other) + b1v, 0.f);
            float e0 = __shfl(g, (lane & 15) * 2, 64);
            float e1 = __shfl(g, (lane & 15) * 2 + 1, 64);
            if (lane < 16) g1h[(size_t)(dst + 1) * 16 + lane] = __floats2half2_rn(e0, e1);
            float ps = g * usv, pd = g * udv;
            for (int m = 16; m >= 1; m >>= 1) {
                ps += __shfl_xor(ps, m, 64);
                pd += __shfl_xor(pd, m, 64);
            }
            float ps1 = __shfl(ps, 32, 64);
            float pd1 = __shfl(pd, 32, 64);
            if (lane == 0) {
                ssd2[dst + 1] = make_float2(ps, ps1);
                sd2[dst + 1] = make_float2(pd, pd1);
            }
        }
    }
}

// ---------------- GAT2 aggregate: 2-row interleave, lean (no LDS) ----------------
__global__ __launch_bounds__(256, 6) void aggB_gather(
        const int* __restrict__ rowptr, const int* __restrict__ csr,
        const __half2* __restrict__ g1h,
        const float2* __restrict__ ssd2, const float2* __restrict__ sd2,
        float* __restrict__ agg, int N) {
    int lane = threadIdx.x & 63;
    int c = lane & 31;
    bool hi = lane >= 32;
    int grp = lane >> 4;   // 0..3: which edge of each 4-pack
    int t = lane & 15;     // channel-pair index
    int wid = blockIdx.x * 4 + (threadIdx.x >> 6);
    int nwv = gridDim.x * 4;
    int K = (N + nwv - 1) / nwv;
    int dlo = wid * K, dhi = min(dlo + K, N);
    for (int dst = dlo; dst < dhi; dst += 2) {
        bool two = (dst + 1) < dhi;
        int rsA = rowptr[dst], reA = rowptr[dst + 1];
        int reB = two ? rowptr[dst + 2] : reA;
        int degA = reA - rsA, rsB = reA, degB = reB - reA;
        float2 sdA = sd2[dst];
        float2 sdB = two ? sd2[dst + 1] : make_float2(0.f, 0.f);
        float denA0 = 0, denA1 = 0, denB0 = 0, denB1 = 0;
        float aA00 = 0, aA01 = 0, aA10 = 0, aA11 = 0;
        float aB00 = 0, aB01 = 0, aB10 = 0, aB11 = 0;
        int degM = max(degA, degB);
        for (int base = 0; base < degM; base += 64) {
            int idx = base + lane;
            bool vA = idx < degA, vB = idx < degB;
            int sAl = vA ? csr[rsA + idx] : 0;
            int sBl = vB ? csr[rsB + idx] : 0;
            float2 scA = ssd2[sAl];
            float2 scB = ssd2[sBl];
            float w0A = vA ? __expf(lrelu(scA.x + sdA.x)) : 0.f;
            float w1A = vA ? __expf(lrelu(scA.y + sdA.y)) : 0.f;
            float w0B = vB ? __expf(lrelu(scB.x + sdB.x)) : 0.f;
            float w1B = vB ? __expf(lrelu(scB.y + sdB.y)) : 0.f;
            denA0 += w0A; denA1 += w1A; denB0 += w0B; denB1 += w1B;
            int cntM = min(degM - base, 64);
            int iters = (cntM + 3) >> 2;
#pragma unroll 4
            for (int i = 0; i < iters; i++) {
                int e = (i << 2) + grp;  // <= 63; out-of-row edges carry w=0, s=0
                int sA = __shfl(sAl, e, 64);
                float w0Ae = __shfl(w0A, e, 64);
                float w1Ae = __shfl(w1A, e, 64);
                float2 gvA = __half22float2(g1h[(size_t)sA * 16 + t]);
                aA00 += w0Ae * gvA.x; aA01 += w0Ae * gvA.y;
                aA10 += w1Ae * gvA.x; aA11 += w1Ae * gvA.y;
                int sB = __shfl(sBl, e, 64);
                float w0Be = __shfl(w0B, e, 64);
                float w1Be = __shfl(w1B, e, 64);
                float2 gvB = __half22float2(g1h[(size_t)sB * 16 + t]);
                aB00 += w0Be * gvB.x; aB01 += w0Be * gvB.y;
                aB10 += w1Be * gvB.x; aB11 += w1Be * gvB.y;
            }
        }
        for (int m = 32; m >= 1; m >>= 1) {
            denA0 += __shfl_xor(denA0, m, 64); denA1 += __shfl_xor(denA1, m, 64);
            denB0 += __shfl_xor(denB0, m, 64); denB1 += __shfl_xor(denB1, m, 64);
        }
        for (int m = 32; m >= 16; m >>= 1) {
            aA00 += __shfl_xor(aA00, m, 64); aA01 += __shfl_xor(aA01, m, 64);
            aA10 += __shfl_xor(aA10, m, 64); aA11 += __shfl_xor(aA11, m, 64);
            aB00 += __shfl_xor(aB00, m, 64); aB01 += __shfl_xor(aB01, m, 64);
            aB10 += __shfl_xor(aB10, m, 64); aB11 += __shfl_xor(aB11, m, 64);
        }
        int srcl = c >> 1;
        {
            float r00 = __shfl(aA00, srcl, 64), r01 = __shfl(aA01, srcl, 64);
            float r10 = __shfl(aA10, srcl, 64), r11 = __shfl(aA11, srcl, 64);
            float num = hi ? ((c & 1) ? r11 : r10) : ((c & 1) ? r01 : r00);
            float den = hi ? denA1 : denA0;
            agg[(size_t)dst * 64 + lane] = num / (den + 1e-16f);
        }
        if (two) {
            float r00 = __shfl(aB00, srcl, 64), r01 = __shfl(aB01, srcl, 64);
            float r10 = __shfl(aB10, srcl, 64), r11 = __shfl(aB11, srcl, 64);
            float num = hi ? ((c & 1) ? r11 : r10) : ((c & 1) ? r01 : r00);
            float den = hi ? denB1 : denB0;
            agg[(size_t)(dst + 1) * 64 + lane] = num / (den + 1e-16f);
        }
    }
}

// ---------------- dense epilogue, thread-per-node: W2 + mean + relu + GRU ----------------
// lane = node. All weight accesses are loop-uniform -> scalar loads (constant cache),
// zero DS/shfl ops. hstate kept TRANSPOSED hstT[c*N+node] for coalesced access.
__global__ __launch_bounds__(256, 1) void dense_kernel(
        const float* __restrict__ agg,
        const float* __restrict__ W2, const float* __restrict__ b2,
        const float* __restrict__ w_ih, const float* __restrict__ w_hh,
        const float* __restrict__ b_ih, const float* __restrict__ b_hh,
        float* __restrict__ hstT, int N, int first) {
    int node = blockIdx.x * 256 + threadIdx.x;
    if (node >= N) return;
    // this node's 64 aggregated values (16 sequential float4: L1-friendly, full lines used)
    float a[64];
    const float4* ap = (const float4*)(agg + (size_t)node * 64);
#pragma unroll
    for (int i = 0; i < 16; i++) {
        float4 v = ap[i];
        a[i * 4 + 0] = v.x; a[i * 4 + 1] = v.y; a[i * 4 + 2] = v.z; a[i * 4 + 3] = v.w;
    }
    // g[c] = relu(0.5*(W2[c,:]·a_h0 + W2[32+c,:]·a_h1) + b2[c])
    float g[32];
    for (int c = 0; c < 32; c++) {
        float acc0 = 0.f, acc1 = 0.f;
#pragma unroll
        for (int k = 0; k < 32; k++) {
            acc0 += W2[c * 32 + k] * a[k];
            acc1 += W2[(32 + c) * 32 + k] * a[32 + k];
        }
        g[c] = fmaxf(0.5f * (acc0 + acc1) + b2[c], 0.f);
    }
    float hold[32];
    if (first) {
#pragma unroll
        for (int k = 0; k < 32; k++) hold[k] = 0.f;
    } else {
#pragma unroll
        for (int k = 0; k < 32; k++) hold[k] = hstT[(size_t)k * N + node];
    }
    for (int c = 0; c < 32; c++) {
        float ir = b_ih[c], iz = b_ih[32 + c], in_ = b_ih[64 + c];
        float hr = b_hh[c], hz = b_hh[32 + c], hn = b_hh[64 + c];
#pragma unroll
        for (int k = 0; k < 32; k++) {
            float gk = g[k], hk = hold[k];
            ir  += w_ih[c * 32 + k]        * gk;
            iz  += w_ih[(32 + c) * 32 + k] * gk;
            in_ += w_ih[(64 + c) * 32 + k] * gk;
            hr  += w_hh[c * 32 + k]        * hk;
            hz  += w_hh[(32 + c) * 32 + k] * hk;
            hn  += w_hh[(64 + c) * 32 + k] * hk;
        }
        float rr = sigmoidf(ir + hr);
        float zz = sigmoidf(iz + hz);
        float cand = tanhf(in_ + rr * hn);
        hstT[(size_t)c * N + node] = (1.f - zz) * cand + zz * hold[c];
    }
}

// ---------------- final Linear(hid,1): thread-per-node, coalesced over hstT ----------------
__global__ __launch_bounds__(256) void final_kernel(
        const float* __restrict__ hstT, const float* __restrict__ fc_w,
        const float* __restrict__ fc_b, float* __restrict__ out, int N) {
    int node = blockIdx.x * 256 + threadIdx.x;
    if (node >= N) return;
    float v = fc_b[0];
#pragma unroll
    for (int c = 0; c < 32; c++) v += hstT[(size_t)c * N + node] * fc_w[c];
    out[node] = v;
}

extern "C" void kernel_launch(void* const* d_in, const int* in_sizes, int n_in,
                              void* d_out, int out_size, void* d_ws, size_t ws_size,
                              hipStream_t stream) {
    const float* x_seq = (const float*)d_in[0];
    const float* W1  = (const float*)d_in[1];
    const float* a1s = (const float*)d_in[2];
    const float* a1d = (const float*)d_in[3];
    const float* b1  = (const float*)d_in[4];
    const float* W2  = (const float*)d_in[5];
    const float* a2s = (const float*)d_in[6];
    const float* a2d = (const float*)d_in[7];
    const float* b2  = (const float*)d_in[8];
    const float* w_ih = (const float*)d_in[9];
    const float* w_hh = (const float*)d_in[10];
    const float* b_ih = (const float*)d_in[11];
    const float* b_hh = (const float*)d_in[12];
    const float* fc_w = (const float*)d_in[13];
    const float* fc_b = (const float*)d_in[14];
    const void*  ei   = d_in[15];

    const int N = in_sizes[0] / (T_STEPS * FIN);  // 50000
    const int E = in_sizes[15] / 2;               // 800000
    const int NE = E + N;
    const int NB = (N + 255) / 256;               // per-256 blocks (196)

    char* ws = (char*)d_ws;
    size_t off = 0;
    auto alloc = [&](size_t bytes) -> void* {
        void* p = ws + off;
        off += (bytes + 255) & ~(size_t)255;
        return p;
    };
    int*     flag   = (int*)alloc(4);
    int*     rowptr = (int*)alloc((size_t)(N + 1) * 4);
    int*     cnt    = (int*)alloc((size_t)N * 4);        // reused as fill cursor
    int*     bsum   = (int*)alloc(256 * 4);
    int*     csr    = (int*)alloc((size_t)NE * 4);
    float4*  nrec4  = (float4*)alloc((size_t)N * 16);    // {x0,x1,x2,half2(ss0,ss1)}
    float2*  sd1    = (float2*)alloc((size_t)N * 8);
    float2*  ssd2   = (float2*)alloc((size_t)N * 8);
    float2*  sd2    = (float2*)alloc((size_t)N * 8);
    __half2* g1h    = (__half2*)alloc((size_t)N * 16 * 4);  // fp16 g1: 64B/node, L2-resident
    float*   agg    = (float*)alloc((size_t)N * 64 * 4);
    float*   hstT   = (float*)alloc((size_t)N * 32 * 4);    // transposed hstate [c][node]
    float*   u_s    = (float*)alloc(64 * 4);
    float*   u_d    = (float*)alloc(64 * 4);
    if (off > ws_size) return;  // workspace too small — cannot proceed safely

    const int AGG_BLOCKS = 2048;

    // ---- preprocessing: CSR by destination (reused for all 16 aggregations) ----
    detect_kernel<<<1, 128, 0, stream>>>((const int*)ei, in_sizes[15], flag);
    init_kernel<<<NB, 256, 0, stream>>>(cnt, N);
    count_kernel<<<(E + 255) / 256, 256, 0, stream>>>(ei, flag, E, N, cnt);
    scan1_kernel<<<NB, 256, 0, stream>>>(cnt, rowptr, bsum, N);
    scan2_kernel<<<1, 256, 0, stream>>>(bsum, NB);
    scan3_kernel<<<NB, 256, 0, stream>>>(rowptr, bsum, N);
    selffill_kernel<<<NB, 256, 0, stream>>>(rowptr, csr, cnt, N);
    scatter_kernel<<<(E + 255) / 256, 256, 0, stream>>>(ei, flag, E, N, cnt, csr);
    prep_u_kernel<<<1, 64, 0, stream>>>(W2, a2s, a2d, u_s, u_d);

    // ---- T timesteps ----
    for (int t = 0; t < T_STEPS; t++) {
        const float* xt = x_seq + (size_t)t * N * FIN;
        score1_kernel<<<(N * 64 + 255) / 256, 256, 0, stream>>>(xt, W1, a1s, a1d, nrec4, sd1, N);
        aggA_kernel<<<AGG_BLOCKS, 256, 0, stream>>>(rowptr, csr, nrec4, sd1, W1, b1,
                                                    u_s, u_d, g1h, ssd2, sd2, N);
        aggB_gather<<<AGG_BLOCKS, 256, 0, stream>>>(rowptr, csr, g1h, ssd2, sd2, agg, N);
        dense_kernel<<<NB, 256, 0, stream>>>(agg, W2, b2, w_ih, w_hh, b_ih, b_hh,
                                             hstT, N, t == 0 ? 1 : 0);
    }
    final_kernel<<<NB, 256, 0, stream>>>(hstT, fc_w, fc_b, (float*)d_out, N);
}

// Round 7
// 981.679 us; speedup vs baseline: 3.9266x; 1.3659x over previous
//
#include <hip/hip_runtime.h>
#include <hip/hip_fp16.h>
#include <stdint.h>

#define T_STEPS 8
#define FIN 3
#define HID 32
#define NEG_SLOPE 0.2f

__device__ __forceinline__ float lrelu(float x) { return x > 0.f ? x : NEG_SLOPE * x; }
__device__ __forceinline__ float sigmoidf(float x) { return 1.f / (1.f + __expf(-x)); }

// ---------------- edge dtype detection (int64 vs int32) ----------------
__global__ void detect_kernel(const int* ei32, int nElems, int* flag) {
    __shared__ int any_nonzero;
    if (threadIdx.x == 0) any_nonzero = 0;
    __syncthreads();
    int idx = 1 + 2 * (int)threadIdx.x;  // odd int32 slots
    if (idx < nElems && ei32[idx] != 0) any_nonzero = 1;  // benign race
    __syncthreads();
    if (threadIdx.x == 0) *flag = (any_nonzero ? 0 : 1);  // 1 => int64
}

__device__ __forceinline__ int get_edge(const void* ei, int is64, long long idx) {
    if (is64) return (int)((const long long*)ei)[idx];
    return ((const int*)ei)[idx];
}

// ---------------- CSR build ----------------
__global__ void init_kernel(int* cnt, int N) {
    int i = blockIdx.x * 256 + threadIdx.x;
    if (i < N) cnt[i] = 1;  // self-loop pre-counted
}

__global__ void count_kernel(const void* ei, const int* flag, int E, int N, int* cnt) {
    int e = blockIdx.x * 256 + threadIdx.x;
    if (e >= E) return;
    int is64 = *flag;
    int d = get_edge(ei, is64, (long long)E + e);
    if ((unsigned)d < (unsigned)N) atomicAdd(&cnt[d], 1);
}

// hierarchical scan
__global__ __launch_bounds__(256) void scan1_kernel(const int* cnt, int* rowptr, int* bsum, int n) {
    __shared__ int sm[256];
    int i = blockIdx.x * 256 + threadIdx.x;
    int v = (i < n) ? cnt[i] : 0;
    sm[threadIdx.x] = v;
    __syncthreads();
    for (int off = 1; off < 256; off <<= 1) {
        int t = (threadIdx.x >= off) ? sm[threadIdx.x - off] : 0;
        __syncthreads();
        sm[threadIdx.x] += t;
        __syncthreads();
    }
    if (i < n) rowptr[i + 1] = sm[threadIdx.x];
    if (threadIdx.x == 255) bsum[blockIdx.x] = sm[255];
}

__global__ __launch_bounds__(256) void scan2_kernel(int* bsum, int nb) {
    __shared__ int sm[256];
    int v = (threadIdx.x < nb) ? bsum[threadIdx.x] : 0;
    sm[threadIdx.x] = v;
    __syncthreads();
    for (int off = 1; off < 256; off <<= 1) {
        int t = (threadIdx.x >= off) ? sm[threadIdx.x - off] : 0;
        __syncthreads();
        sm[threadIdx.x] += t;
        __syncthreads();
    }
    if (threadIdx.x < nb) bsum[threadIdx.x] = sm[threadIdx.x];
}

__global__ __launch_bounds__(256) void scan3_kernel(int* rowptr, const int* bsum, int n) {
    int i = blockIdx.x * 256 + threadIdx.x;
    if (i < n && blockIdx.x > 0) rowptr[i + 1] += bsum[blockIdx.x - 1];
    if (i == 0) rowptr[0] = 0;
}

__global__ void selffill_kernel(const int* rowptr, int* csr, int* fill, int N) {
    int n = blockIdx.x * 256 + threadIdx.x;
    if (n >= N) return;
    int rp = rowptr[n];
    csr[rp] = n;        // self-loop occupies slot 0 of each row
    fill[n] = rp + 1;
}

__global__ void scatter_kernel(const void* ei, const int* flag, int E, int N, int* fill, int* csr) {
    int e = blockIdx.x * 256 + threadIdx.x;
    if (e >= E) return;
    int is64 = *flag;
    int s = get_edge(ei, is64, e);
    int d = get_edge(ei, is64, (long long)E + e);
    if ((unsigned)d >= (unsigned)N) return;
    if ((unsigned)s >= (unsigned)N) s = 0;  // safety clamp
    int p = atomicAdd(&fill[d], 1);
    csr[p] = s;
}

// ---------------- precompute u = W2^T a2 per head (for layer-2 scores) ----------------
__global__ __launch_bounds__(64) void prep_u_kernel(
        const float* __restrict__ W2, const float* __restrict__ a2s,
        const float* __restrict__ a2d, float* __restrict__ u_s, float* __restrict__ u_d) {
    int l = threadIdx.x;  // 0..63
    int h = l >> 5, k = l & 31;
    float us = 0.f, ud = 0.f;
    for (int c = 0; c < 32; c++) {
        float w = W2[(h * 32 + c) * 32 + k];
        us += a2s[h * 32 + c] * w;
        ud += a2d[h * 32 + c] * w;
    }
    u_s[l] = us;
    u_d[l] = ud;
}

// ---------------- pack weights k-major for the dense phase ----------------
// w2pk[k*64 + c] = W2[c*32 + k]  (c in 0..63 covers both heads' rows)
// wgru[k*192 + r]: r<96 -> w_ih[r*32+k], else w_hh[(r-96)*32+k]
__global__ __launch_bounds__(256) void pack_kernel(
        const float* __restrict__ W2, const float* __restrict__ w_ih,
        const float* __restrict__ w_hh, float* __restrict__ w2pk, float* __restrict__ wgru) {
    int idx = blockIdx.x * 256 + threadIdx.x;
    if (idx < 2048) {
        int k = idx >> 6, c = idx & 63;
        w2pk[idx] = W2[c * 32 + k];
    }
    if (idx < 6144) {
        int k = idx / 192, r = idx % 192;
        wgru[idx] = (r < 96) ? w_ih[r * 32 + k] : w_hh[(r - 96) * 32 + k];
    }
}

// ---------------- layer-1 scores + packed 16B node record {x0,x1,x2,half2(ss0,ss1)} ----------------
__global__ __launch_bounds__(256) void score1_kernel(
        const float* __restrict__ x, const float* __restrict__ W1,
        const float* __restrict__ a1s, const float* __restrict__ a1d,
        float4* __restrict__ nrec4, float2* __restrict__ sd1, int N) {
    int tid = blockIdx.x * 256 + threadIdx.x;
    int node = tid >> 6;
    int lane = threadIdx.x & 63;
    if (node >= N) return;
    const float* xp = x + (size_t)node * FIN;
    float x0 = xp[0], x1 = xp[1], x2 = xp[2];
    float h = W1[lane * 3] * x0 + W1[lane * 3 + 1] * x1 + W1[lane * 3 + 2] * x2;
    float ps = h * a1s[lane], pd = h * a1d[lane];
    for (int m = 16; m >= 1; m >>= 1) {
        ps += __shfl_xor(ps, m, 64);
        pd += __shfl_xor(pd, m, 64);
    }
    float ps1 = __shfl(ps, 32, 64);
    float pd1 = __shfl(pd, 32, 64);
    if (lane == 0) {
        unsigned u = (unsigned)__half_as_ushort(__float2half_rn(ps)) |
                     ((unsigned)__half_as_ushort(__float2half_rn(ps1)) << 16);
        float4 r;
        r.x = x0; r.y = x1; r.z = x2; r.w = __uint_as_float(u);
        nrec4[node] = r;
        sd1[node] = make_float2(pd, pd1);
    }
}

__device__ __forceinline__ void unpack_scores(float wslot, float& s0, float& s1) {
    unsigned u = __float_as_uint(wslot);
    s0 = __half2float(__ushort_as_half((unsigned short)(u & 0xffffu)));
    s1 = __half2float(__ushort_as_half((unsigned short)(u >> 16)));
}

// ---------------- GAT1 aggregate: 2-row interleave, one 16B gather/edge ----------------
__global__ __launch_bounds__(256, 6) void aggA_kernel(
        const int* __restrict__ rowptr, const int* __restrict__ csr,
        const float4* __restrict__ nrec4, const float2* __restrict__ sd1,
        const float* __restrict__ W1, const float* __restrict__ b1,
        const float* __restrict__ u_s, const float* __restrict__ u_d,
        __half2* __restrict__ g1h, float2* __restrict__ ssd2, float2* __restrict__ sd2, int N) {
    int lane = threadIdx.x & 63;
    int head = lane >> 5;
    int c = lane & 31;
    float w10 = W1[lane * 3], w11 = W1[lane * 3 + 1], w12 = W1[lane * 3 + 2];
    float b1v = b1[c];
    float usv = u_s[lane], udv = u_d[lane];
    int wid = blockIdx.x * 4 + (threadIdx.x >> 6);
    int nwv = gridDim.x * 4;
    int K = (N + nwv - 1) / nwv;
    int dlo = wid * K, dhi = min(dlo + K, N);
    for (int dst = dlo; dst < dhi; dst += 2) {
        bool two = (dst + 1) < dhi;
        int rsA = rowptr[dst], reA = rowptr[dst + 1];
        int reB = two ? rowptr[dst + 2] : reA;
        int degA = reA - rsA, rsB = reA, degB = reB - reA;
        float2 sdA = sd1[dst];
        float2 sdB = two ? sd1[dst + 1] : make_float2(0.f, 0.f);
        float qA0 = 0, qA1 = 0, qA2 = 0, qA3 = 0, qA4 = 0, qA5 = 0, qA6 = 0, qA7 = 0;
        float qB0 = 0, qB1 = 0, qB2 = 0, qB3 = 0, qB4 = 0, qB5 = 0, qB6 = 0, qB7 = 0;
        int degM = max(degA, degB);
        for (int base = 0; base < degM; base += 64) {
            int idx = base + lane;
            bool vA = idx < degA, vB = idx < degB;
            int sA = vA ? csr[rsA + idx] : 0;
            int sB = vB ? csr[rsB + idx] : 0;
            float4 rA = nrec4[sA];
            float4 rB = nrec4[sB];
            float sA0, sA1, sB0, sB1;
            unpack_scores(rA.w, sA0, sA1);
            unpack_scores(rB.w, sB0, sB1);
            float w0A = vA ? __expf(lrelu(sA0 + sdA.x)) : 0.f;
            float w1A = vA ? __expf(lrelu(sA1 + sdA.y)) : 0.f;
            float w0B = vB ? __expf(lrelu(sB0 + sdB.x)) : 0.f;
            float w1B = vB ? __expf(lrelu(sB1 + sdB.y)) : 0.f;
            qA0 += w0A; qA1 += w0A * rA.x; qA2 += w0A * rA.y; qA3 += w0A * rA.z;
            qA4 += w1A; qA5 += w1A * rA.x; qA6 += w1A * rA.y; qA7 += w1A * rA.z;
            qB0 += w0B; qB1 += w0B * rB.x; qB2 += w0B * rB.y; qB3 += w0B * rB.z;
            qB4 += w1B; qB5 += w1B * rB.x; qB6 += w1B * rB.y; qB7 += w1B * rB.z;
        }
        for (int m = 32; m >= 1; m >>= 1) {
            qA0 += __shfl_xor(qA0, m, 64); qA1 += __shfl_xor(qA1, m, 64);
            qA2 += __shfl_xor(qA2, m, 64); qA3 += __shfl_xor(qA3, m, 64);
            qA4 += __shfl_xor(qA4, m, 64); qA5 += __shfl_xor(qA5, m, 64);
            qA6 += __shfl_xor(qA6, m, 64); qA7 += __shfl_xor(qA7, m, 64);
            qB0 += __shfl_xor(qB0, m, 64); qB1 += __shfl_xor(qB1, m, 64);
            qB2 += __shfl_xor(qB2, m, 64); qB3 += __shfl_xor(qB3, m, 64);
            qB4 += __shfl_xor(qB4, m, 64); qB5 += __shfl_xor(qB5, m, 64);
            qB6 += __shfl_xor(qB6, m, 64); qB7 += __shfl_xor(qB7, m, 64);
        }
        {   // row A epilogue
            float den = head ? qA4 : qA0;
            float AX0 = head ? qA5 : qA1;
            float AX1 = head ? qA6 : qA2;
            float AX2 = head ? qA7 : qA3;
            float v = (w10 * AX0 + w11 * AX1 + w12 * AX2) / (den + 1e-16f);
            float other = __shfl(v, lane ^ 32, 64);
            float g = fmaxf(0.5f * (v + other) + b1v, 0.f);
            float e0 = __shfl(g, (lane & 15) * 2, 64);
            float e1 = __shfl(g, (lane & 15) * 2 + 1, 64);
            if (lane < 16) g1h[(size_t)dst * 16 + lane] = __floats2half2_rn(e0, e1);
            float ps = g * usv, pd = g * udv;
            for (int m = 16; m >= 1; m >>= 1) {
                ps += __shfl_xor(ps, m, 64);
                pd += __shfl_xor(pd, m, 64);
            }
            float ps1 = __shfl(ps, 32, 64);
            float pd1 = __shfl(pd, 32, 64);
            if (lane == 0) {
                ssd2[dst] = make_float2(ps, ps1);
                sd2[dst] = make_float2(pd, pd1);
            }
        }
        if (two) {  // row B epilogue
            float den = head ? qB4 : qB0;
            float AX0 = head ? qB5 : qB1;
            float AX1 = head ? qB6 : qB2;
            float AX2 = head ? qB7 : qB3;
            float v = (w10 * AX0 + w11 * AX1 + w12 * AX2) / (den + 1e-16f);
            float other = __shfl(v, lane ^ 32, 64);
            float g = fmaxf(0.5f * (v + other) + b1v, 0.f);
            float e0 = __shfl(g, (lane & 15) * 2, 64);
            float e1 = __shfl(g, (lane & 15) * 2 + 1, 64);
            if (lane < 16) g1h[(size_t)(dst + 1) * 16 + lane] = __floats2half2_rn(e0, e1);
            float ps = g * usv, pd = g * udv;
            for (int m = 16; m >= 1; m >>= 1) {
                ps += __shfl_xor(ps, m, 64);
                pd += __shfl_xor(pd, m, 64);
            }
            float ps1 = __shfl(ps, 32, 64);
            float pd1 = __shfl(pd, 32, 64);
            if (lane == 0) {
                ssd2[dst + 1] = make_float2(ps, ps1);
                sd2[dst + 1] = make_float2(pd, pd1);
            }
        }
    }
}

// ---------------- GAT2 aggregate: 2-row interleave, lean (no LDS) ----------------
__global__ __launch_bounds__(256, 6) void aggB_gather(
        const int* __restrict__ rowptr, const int* __restrict__ csr,
        const __half2* __restrict__ g1h,
        const float2* __restrict__ ssd2, const float2* __restrict__ sd2,
        float* __restrict__ agg, int N) {
    int lane = threadIdx.x & 63;
    int c = lane & 31;
    bool hi = lane >= 32;
    int grp = lane >> 4;   // 0..3: which edge of each 4-pack
    int t = lane & 15;     // channel-pair index
    int wid = blockIdx.x * 4 + (threadIdx.x >> 6);
    int nwv = gridDim.x * 4;
    int K = (N + nwv - 1) / nwv;
    int dlo = wid * K, dhi = min(dlo + K, N);
    for (int dst = dlo; dst < dhi; dst += 2) {
        bool two = (dst + 1) < dhi;
        int rsA = rowptr[dst], reA = rowptr[dst + 1];
        int reB = two ? rowptr[dst + 2] : reA;
        int degA = reA - rsA, rsB = reA, degB = reB - reA;
        float2 sdA = sd2[dst];
        float2 sdB = two ? sd2[dst + 1] : make_float2(0.f, 0.f);
        float denA0 = 0, denA1 = 0, denB0 = 0, denB1 = 0;
        float aA00 = 0, aA01 = 0, aA10 = 0, aA11 = 0;
        float aB00 = 0, aB01 = 0, aB10 = 0, aB11 = 0;
        int degM = max(degA, degB);
        for (int base = 0; base < degM; base += 64) {
            int idx = base + lane;
            bool vA = idx < degA, vB = idx < degB;
            int sAl = vA ? csr[rsA + idx] : 0;
            int sBl = vB ? csr[rsB + idx] : 0;
            float2 scA = ssd2[sAl];
            float2 scB = ssd2[sBl];
            float w0A = vA ? __expf(lrelu(scA.x + sdA.x)) : 0.f;
            float w1A = vA ? __expf(lrelu(scA.y + sdA.y)) : 0.f;
            float w0B = vB ? __expf(lrelu(scB.x + sdB.x)) : 0.f;
            float w1B = vB ? __expf(lrelu(scB.y + sdB.y)) : 0.f;
            denA0 += w0A; denA1 += w1A; denB0 += w0B; denB1 += w1B;
            int cntM = min(degM - base, 64);
            int iters = (cntM + 3) >> 2;
#pragma unroll 4
            for (int i = 0; i < iters; i++) {
                int e = (i << 2) + grp;  // <= 63; out-of-row edges carry w=0, s=0
                int sA = __shfl(sAl, e, 64);
                float w0Ae = __shfl(w0A, e, 64);
                float w1Ae = __shfl(w1A, e, 64);
                float2 gvA = __half22float2(g1h[(size_t)sA * 16 + t]);
                aA00 += w0Ae * gvA.x; aA01 += w0Ae * gvA.y;
                aA10 += w1Ae * gvA.x; aA11 += w1Ae * gvA.y;
                int sB = __shfl(sBl, e, 64);
                float w0Be = __shfl(w0B, e, 64);
                float w1Be = __shfl(w1B, e, 64);
                float2 gvB = __half22float2(g1h[(size_t)sB * 16 + t]);
                aB00 += w0Be * gvB.x; aB01 += w0Be * gvB.y;
                aB10 += w1Be * gvB.x; aB11 += w1Be * gvB.y;
            }
        }
        for (int m = 32; m >= 1; m >>= 1) {
            denA0 += __shfl_xor(denA0, m, 64); denA1 += __shfl_xor(denA1, m, 64);
            denB0 += __shfl_xor(denB0, m, 64); denB1 += __shfl_xor(denB1, m, 64);
        }
        for (int m = 32; m >= 16; m >>= 1) {
            aA00 += __shfl_xor(aA00, m, 64); aA01 += __shfl_xor(aA01, m, 64);
            aA10 += __shfl_xor(aA10, m, 64); aA11 += __shfl_xor(aA11, m, 64);
            aB00 += __shfl_xor(aB00, m, 64); aB01 += __shfl_xor(aB01, m, 64);
            aB10 += __shfl_xor(aB10, m, 64); aB11 += __shfl_xor(aB11, m, 64);
        }
        int srcl = c >> 1;
        {
            float r00 = __shfl(aA00, srcl, 64), r01 = __shfl(aA01, srcl, 64);
            float r10 = __shfl(aA10, srcl, 64), r11 = __shfl(aA11, srcl, 64);
            float num = hi ? ((c & 1) ? r11 : r10) : ((c & 1) ? r01 : r00);
            float den = hi ? denA1 : denA0;
            agg[(size_t)dst * 64 + lane] = num / (den + 1e-16f);
        }
        if (two) {
            float r00 = __shfl(aB00, srcl, 64), r01 = __shfl(aB01, srcl, 64);
            float r10 = __shfl(aB10, srcl, 64), r11 = __shfl(aB11, srcl, 64);
            float num = hi ? ((c & 1) ? r11 : r10) : ((c & 1) ? r01 : r00);
            float den = hi ? denB1 : denB0;
            agg[(size_t)(dst + 1) * 64 + lane] = num / (den + 1e-16f);
        }
    }
}

// ---------------- block-cooperative dense: 64 nodes/block, 4 waves ----------------
// thread = (nl = node lane 0..63, cg = wave id 0..3 handling 8 channels).
// cg is wave-uniform (readfirstlane) -> all weight accesses are s_load streams of
// the k-major packed tables. agg + hstate staged in LDS with (nl+k)%32 banking (free).
__global__ __launch_bounds__(256) void dense_kernel(
        const float* __restrict__ agg,
        const float* __restrict__ w2pk, const float* __restrict__ b2,
        const float* __restrict__ wgru,
        const float* __restrict__ b_ih, const float* __restrict__ b_hh,
        float* __restrict__ hstT, int N, int first) {
    __shared__ float a_lds[64 * 65];     // [nl][k] stride 65
    __shared__ float g_lds[64 * 33];     // [nl][c] stride 33
    __shared__ float h_lds[64 * 33];     // [nl][k] stride 33
    int tid = threadIdx.x;
    int node0 = blockIdx.x * 64;
    int nvalid = min(64, N - node0);
    // stage agg rows (coalesced: flat idx = nl*64+k)
    for (int idx = tid; idx < nvalid * 64; idx += 256) {
        int nl = idx >> 6, k = idx & 63;
        a_lds[nl * 65 + k] = agg[(size_t)node0 * 64 + idx];
    }
    // stage h state (coalesced: node fastest)
    for (int idx = tid; idx < 32 * 64; idx += 256) {
        int k = idx >> 6, nl = idx & 63;
        float hv = 0.f;
        if (!first && nl < nvalid) hv = hstT[(size_t)k * N + node0 + nl];
        h_lds[nl * 33 + k] = hv;
    }
    __syncthreads();
    int nl = tid & 63;
    int cg8 = __builtin_amdgcn_readfirstlane((tid >> 6) * 8);  // wave-uniform channel base
    bool active = nl < nvalid;
    int node = node0 + nl;
    // ---- g = relu(0.5*(W2·a) + b2) for channels cg8..cg8+7 ----
    float acc[8] = {0, 0, 0, 0, 0, 0, 0, 0};
    for (int k = 0; k < 32; k++) {
        float ak0 = a_lds[nl * 65 + k];
        float ak1 = a_lds[nl * 65 + 32 + k];
        const float* wp = w2pk + k * 64 + cg8;
#pragma unroll
        for (int j = 0; j < 8; j++) acc[j] += wp[j] * ak0 + wp[32 + j] * ak1;
    }
#pragma unroll
    for (int j = 0; j < 8; j++) {
        float g = fmaxf(0.5f * acc[j] + b2[cg8 + j], 0.f);
        g_lds[nl * 33 + cg8 + j] = g;
    }
    __syncthreads();
    // ---- GRU for channels cg8..cg8+7 ----
    float ir[8], iz[8], in_[8], hr[8], hz[8], hn[8];
#pragma unroll
    for (int j = 0; j < 8; j++) {
        ir[j] = b_ih[cg8 + j]; iz[j] = b_ih[32 + cg8 + j]; in_[j] = b_ih[64 + cg8 + j];
        hr[j] = b_hh[cg8 + j]; hz[j] = b_hh[32 + cg8 + j]; hn[j] = b_hh[64 + cg8 + j];
    }
    for (int k = 0; k < 32; k++) {
        float gk = g_lds[nl * 33 + k];
        float hk = h_lds[nl * 33 + k];
        const float* wp = wgru + k * 192 + cg8;
#pragma unroll
        for (int j = 0; j < 8; j++) {
            ir[j]  += wp[j]       * gk;
            iz[j]  += wp[32 + j]  * gk;
            in_[j] += wp[64 + j]  * gk;
            hr[j]  += wp[96 + j]  * hk;
            hz[j]  += wp[128 + j] * hk;
            hn[j]  += wp[160 + j] * hk;
        }
    }
    if (active) {
#pragma unroll
        for (int j = 0; j < 8; j++) {
            int c = cg8 + j;
            float rr = sigmoidf(ir[j] + hr[j]);
            float zz = sigmoidf(iz[j] + hz[j]);
            float cand = tanhf(in_[j] + rr * hn[j]);
            float hold = h_lds[nl * 33 + c];
            hstT[(size_t)c * N + node] = (1.f - zz) * cand + zz * hold;
        }
    }
}

// ---------------- final Linear(hid,1): thread-per-node, coalesced over hstT ----------------
__global__ __launch_bounds__(256) void final_kernel(
        const float* __restrict__ hstT, const float* __restrict__ fc_w,
        const float* __restrict__ fc_b, float* __restrict__ out, int N) {
    int node = blockIdx.x * 256 + threadIdx.x;
    if (node >= N) return;
    float v = fc_b[0];
#pragma unroll
    for (int c = 0; c < 32; c++) v += hstT[(size_t)c * N + node] * fc_w[c];
    out[node] = v;
}

extern "C" void kernel_launch(void* const* d_in, const int* in_sizes, int n_in,
                              void* d_out, int out_size, void* d_ws, size_t ws_size,
                              hipStream_t stream) {
    const float* x_seq = (const float*)d_in[0];
    const float* W1  = (const float*)d_in[1];
    const float* a1s = (const float*)d_in[2];
    const float* a1d = (const float*)d_in[3];
    const float* b1  = (const float*)d_in[4];
    const float* W2  = (const float*)d_in[5];
    const float* a2s = (const float*)d_in[6];
    const float* a2d = (const float*)d_in[7];
    const float* b2  = (const float*)d_in[8];
    const float* w_ih = (const float*)d_in[9];
    const float* w_hh = (const float*)d_in[10];
    const float* b_ih = (const float*)d_in[11];
    const float* b_hh = (const float*)d_in[12];
    const float* fc_w = (const float*)d_in[13];
    const float* fc_b = (const float*)d_in[14];
    const void*  ei   = d_in[15];

    const int N = in_sizes[0] / (T_STEPS * FIN);  // 50000
    const int E = in_sizes[15] / 2;               // 800000
    const int NE = E + N;
    const int NB = (N + 255) / 256;               // per-256 blocks (196)
    const int NB64 = (N + 63) / 64;               // dense blocks (782)

    char* ws = (char*)d_ws;
    size_t off = 0;
    auto alloc = [&](size_t bytes) -> void* {
        void* p = ws + off;
        off += (bytes + 255) & ~(size_t)255;
        return p;
    };
    int*     flag   = (int*)alloc(4);
    int*     rowptr = (int*)alloc((size_t)(N + 1) * 4);
    int*     cnt    = (int*)alloc((size_t)N * 4);        // reused as fill cursor
    int*     bsum   = (int*)alloc(256 * 4);
    int*     csr    = (int*)alloc((size_t)NE * 4);
    float4*  nrec4  = (float4*)alloc((size_t)N * 16);    // {x0,x1,x2,half2(ss0,ss1)}
    float2*  sd1    = (float2*)alloc((size_t)N * 8);
    float2*  ssd2   = (float2*)alloc((size_t)N * 8);
    float2*  sd2    = (float2*)alloc((size_t)N * 8);
    __half2* g1h    = (__half2*)alloc((size_t)N * 16 * 4);  // fp16 g1: 64B/node, L2-resident
    float*   agg    = (float*)alloc((size_t)N * 64 * 4);
    float*   hstT   = (float*)alloc((size_t)N * 32 * 4);    // transposed hstate [c][node]
    float*   u_s    = (float*)alloc(64 * 4);
    float*   u_d    = (float*)alloc(64 * 4);
    float*   w2pk   = (float*)alloc(2048 * 4);              // k-major W2
    float*   wgru   = (float*)alloc(6144 * 4);              // k-major GRU weights
    if (off > ws_size) return;  // workspace too small — cannot proceed safely

    const int AGG_BLOCKS = 2048;

    // ---- preprocessing: CSR by destination (reused for all 16 aggregations) ----
    detect_kernel<<<1, 128, 0, stream>>>((const int*)ei, in_sizes[15], flag);
    init_kernel<<<NB, 256, 0, stream>>>(cnt, N);
    count_kernel<<<(E + 255) / 256, 256, 0, stream>>>(ei, flag, E, N, cnt);
    scan1_kernel<<<NB, 256, 0, stream>>>(cnt, rowptr, bsum, N);
    scan2_kernel<<<1, 256, 0, stream>>>(bsum, NB);
    scan3_kernel<<<NB, 256, 0, stream>>>(rowptr, bsum, N);
    selffill_kernel<<<NB, 256, 0, stream>>>(rowptr, csr, cnt, N);
    scatter_kernel<<<(E + 255) / 256, 256, 0, stream>>>(ei, flag, E, N, cnt, csr);
    prep_u_kernel<<<1, 64, 0, stream>>>(W2, a2s, a2d, u_s, u_d);
    pack_kernel<<<24, 256, 0, stream>>>(W2, w_ih, w_hh, w2pk, wgru);

    // ---- T timesteps ----
    for (int t = 0; t < T_STEPS; t++) {
        const float* xt = x_seq + (size_t)t * N * FIN;
        score1_kernel<<<(N * 64 + 255) / 256, 256, 0, stream>>>(xt, W1, a1s, a1d, nrec4, sd1, N);
        aggA_kernel<<<AGG_BLOCKS, 256, 0, stream>>>(rowptr, csr, nrec4, sd1, W1, b1,
                                                    u_s, u_d, g1h, ssd2, sd2, N);
        aggB_gather<<<AGG_BLOCKS, 256, 0, stream>>>(rowptr, csr, g1h, ssd2, sd2, agg, N);
        dense_kernel<<<NB64, 256, 0, stream>>>(agg, w2pk, b2, wgru, b_ih, b_hh,
                                               hstT, N, t == 0 ? 1 : 0);
    }
    final_kernel<<<NB, 256, 0, stream>>>(hstT, fc_w, fc_b, (float*)d_out, N);
}

// Round 8
// 650.404 us; speedup vs baseline: 5.9265x; 1.5093x over previous
//
#include <hip/hip_runtime.h>
#include <hip/hip_fp16.h>
#include <stdint.h>

#define T_STEPS 8
#define FIN 3
#define HID 32
#define NEG_SLOPE 0.2f

__device__ __forceinline__ float lrelu(float x) { return x > 0.f ? x : NEG_SLOPE * x; }
__device__ __forceinline__ float sigmoidf(float x) { return 1.f / (1.f + __expf(-x)); }

// ---------------- edge dtype detection (int64 vs int32) ----------------
__global__ void detect_kernel(const int* ei32, int nElems, int* flag) {
    __shared__ int any_nonzero;
    if (threadIdx.x == 0) any_nonzero = 0;
    __syncthreads();
    int idx = 1 + 2 * (int)threadIdx.x;  // odd int32 slots
    if (idx < nElems && ei32[idx] != 0) any_nonzero = 1;  // benign race
    __syncthreads();
    if (threadIdx.x == 0) *flag = (any_nonzero ? 0 : 1);  // 1 => int64
}

__device__ __forceinline__ int get_edge(const void* ei, int is64, long long idx) {
    if (is64) return (int)((const long long*)ei)[idx];
    return ((const int*)ei)[idx];
}

// ---------------- edge conversion to int32 (also validity clamp) ----------------
__global__ void conv_kernel(const void* ei, const int* flag, int E, int N,
                            int* src32, int* dst32) {
    int e = blockIdx.x * 256 + threadIdx.x;
    if (e >= E) return;
    int is64 = *flag;
    int s = get_edge(ei, is64, e);
    int d = get_edge(ei, is64, (long long)E + e);
    if ((unsigned)s >= (unsigned)N) s = 0;  // safety clamp
    src32[e] = s;
    dst32[e] = ((unsigned)d < (unsigned)N) ? d : 0x7fffffff;  // sentinel: excluded everywhere
}

// ---------------- CSR build ----------------
__global__ void init_kernel(int* cnt, int N) {
    int i = blockIdx.x * 256 + threadIdx.x;
    if (i < N) cnt[i] = 1;  // self-loop pre-counted
}

__global__ void count_kernel(const int* __restrict__ dst32, int E, int N, int* cnt) {
    int e = blockIdx.x * 256 + threadIdx.x;
    if (e >= E) return;
    int d = dst32[e];
    if (d < N) atomicAdd(&cnt[d], 1);
}

// hierarchical scan
__global__ __launch_bounds__(256) void scan1_kernel(const int* cnt, int* rowptr, int* bsum, int n) {
    __shared__ int sm[256];
    int i = blockIdx.x * 256 + threadIdx.x;
    int v = (i < n) ? cnt[i] : 0;
    sm[threadIdx.x] = v;
    __syncthreads();
    for (int off = 1; off < 256; off <<= 1) {
        int t = (threadIdx.x >= off) ? sm[threadIdx.x - off] : 0;
        __syncthreads();
        sm[threadIdx.x] += t;
        __syncthreads();
    }
    if (i < n) rowptr[i + 1] = sm[threadIdx.x];
    if (threadIdx.x == 255) bsum[blockIdx.x] = sm[255];
}

__global__ __launch_bounds__(256) void scan2_kernel(int* bsum, int nb) {
    __shared__ int sm[256];
    int v = (threadIdx.x < nb) ? bsum[threadIdx.x] : 0;
    sm[threadIdx.x] = v;
    __syncthreads();
    for (int off = 1; off < 256; off <<= 1) {
        int t = (threadIdx.x >= off) ? sm[threadIdx.x - off] : 0;
        __syncthreads();
        sm[threadIdx.x] += t;
        __syncthreads();
    }
    if (threadIdx.x < nb) bsum[threadIdx.x] = sm[threadIdx.x];
}

__global__ __launch_bounds__(256) void scan3_kernel(int* rowptr, const int* bsum, int n) {
    int i = blockIdx.x * 256 + threadIdx.x;
    if (i < n && blockIdx.x > 0) rowptr[i + 1] += bsum[blockIdx.x - 1];
    if (i == 0) rowptr[0] = 0;
}

__global__ void selffill_kernel(const int* rowptr, int* csr, int* fill, int N) {
    int n = blockIdx.x * 256 + threadIdx.x;
    if (n >= N) return;
    int rp = rowptr[n];
    csr[rp] = n;        // self-loop occupies slot 0 of each row
    fill[n] = rp + 1;
}

// dst-sliced scatter: only edges with dst in [lo,hi) -> csr writes stay in a small
// L2-resident window, lines fill up before eviction (kills the 64B/edge writeback)
__global__ void scatter_kernel(const int* __restrict__ src32, const int* __restrict__ dst32,
                               int E, int lo, int hi, int* fill, int* csr) {
    int e = blockIdx.x * 256 + threadIdx.x;
    if (e >= E) return;
    int d = dst32[e];
    if (d < lo || d >= hi) return;
    int p = atomicAdd(&fill[d], 1);
    csr[p] = src32[e];
}

// ---------------- precompute u = W2^T a2 per head (for layer-2 scores) ----------------
__global__ __launch_bounds__(64) void prep_u_kernel(
        const float* __restrict__ W2, const float* __restrict__ a2s,
        const float* __restrict__ a2d, float* __restrict__ u_s, float* __restrict__ u_d) {
    int l = threadIdx.x;  // 0..63
    int h = l >> 5, k = l & 31;
    float us = 0.f, ud = 0.f;
    for (int c = 0; c < 32; c++) {
        float w = W2[(h * 32 + c) * 32 + k];
        us += a2s[h * 32 + c] * w;
        ud += a2d[h * 32 + c] * w;
    }
    u_s[l] = us;
    u_d[l] = ud;
}

// ---------------- pack weights k-major for the dense phase ----------------
__global__ __launch_bounds__(256) void pack_kernel(
        const float* __restrict__ W2, const float* __restrict__ w_ih,
        const float* __restrict__ w_hh, float* __restrict__ w2pk, float* __restrict__ wgru) {
    int idx = blockIdx.x * 256 + threadIdx.x;
    if (idx < 2048) {
        int k = idx >> 6, c = idx & 63;
        w2pk[idx] = W2[c * 32 + k];
    }
    if (idx < 6144) {
        int k = idx / 192, r = idx % 192;
        wgru[idx] = (r < 96) ? w_ih[r * 32 + k] : w_hh[(r - 96) * 32 + k];
    }
}

// ---------------- layer-1 scores + packed 16B node record {x0,x1,x2,half2(ss0,ss1)} ----------------
__global__ __launch_bounds__(256) void score1_kernel(
        const float* __restrict__ x, const float* __restrict__ W1,
        const float* __restrict__ a1s, const float* __restrict__ a1d,
        float4* __restrict__ nrec4, float2* __restrict__ sd1, int N) {
    int tid = blockIdx.x * 256 + threadIdx.x;
    int node = tid >> 6;
    int lane = threadIdx.x & 63;
    if (node >= N) return;
    const float* xp = x + (size_t)node * FIN;
    float x0 = xp[0], x1 = xp[1], x2 = xp[2];
    float h = W1[lane * 3] * x0 + W1[lane * 3 + 1] * x1 + W1[lane * 3 + 2] * x2;
    float ps = h * a1s[lane], pd = h * a1d[lane];
    for (int m = 16; m >= 1; m >>= 1) {
        ps += __shfl_xor(ps, m, 64);
        pd += __shfl_xor(pd, m, 64);
    }
    float ps1 = __shfl(ps, 32, 64);
    float pd1 = __shfl(pd, 32, 64);
    if (lane == 0) {
        unsigned u = (unsigned)__half_as_ushort(__float2half_rn(ps)) |
                     ((unsigned)__half_as_ushort(__float2half_rn(ps1)) << 16);
        float4 r;
        r.x = x0; r.y = x1; r.z = x2; r.w = __uint_as_float(u);
        nrec4[node] = r;
        sd1[node] = make_float2(pd, pd1);
    }
}

__device__ __forceinline__ void unpack_scores(float wslot, float& s0, float& s1) {
    unsigned u = __float_as_uint(wslot);
    s0 = __half2float(__ushort_as_half((unsigned short)(u & 0xffffu)));
    s1 = __half2float(__ushort_as_half((unsigned short)(u >> 16)));
}

// ---------------- GAT1 aggregate: THREAD-per-dst (zero shfl), 4-way unrolled gathers ----------------
// Per dst: 8 scalar accumulators over its row; epilogue computes all 32 channels with
// wave-uniform weight loads, packs g1 row (64B, 4xfloat4 coalesced), layer-2 scores.
__global__ __launch_bounds__(64) void aggA_kernel(
        const int* __restrict__ rowptr, const int* __restrict__ csr,
        const float4* __restrict__ nrec4, const float2* __restrict__ sd1,
        const float* __restrict__ W1, const float* __restrict__ b1,
        const float* __restrict__ u_s, const float* __restrict__ u_d,
        __half2* __restrict__ g1h, float2* __restrict__ ssd2, float2* __restrict__ sd2, int N) {
    int dst = blockIdx.x * 64 + threadIdx.x;
    if (dst >= N) return;
    int rs = rowptr[dst], re = rowptr[dst + 1];
    float2 sdv = sd1[dst];
    float q0 = 0, qx0 = 0, qx1 = 0, qx2 = 0;
    float q1 = 0, qy0 = 0, qy1 = 0, qy2 = 0;
#define AGGA_EDGE(rr) { \
        float s0h, s1h; unpack_scores(rr.w, s0h, s1h); \
        float w0 = __expf(lrelu(s0h + sdv.x)); \
        float w1 = __expf(lrelu(s1h + sdv.y)); \
        q0 += w0; qx0 += w0 * rr.x; qx1 += w0 * rr.y; qx2 += w0 * rr.z; \
        q1 += w1; qy0 += w1 * rr.x; qy1 += w1 * rr.y; qy2 += w1 * rr.z; }
    int e = rs;
    for (; e + 4 <= re; e += 4) {
        int s0 = csr[e], s1 = csr[e + 1], s2 = csr[e + 2], s3 = csr[e + 3];
        float4 r0 = nrec4[s0], r1 = nrec4[s1], r2 = nrec4[s2], r3 = nrec4[s3];
        AGGA_EDGE(r0); AGGA_EDGE(r1); AGGA_EDGE(r2); AGGA_EDGE(r3);
    }
    for (; e < re; e++) {
        int s = csr[e];
        float4 r = nrec4[s];
        AGGA_EDGE(r);
    }
#undef AGGA_EDGE
    float inv0 = 1.f / (q0 + 1e-16f), inv1 = 1.f / (q1 + 1e-16f);
    float ax0 = qx0 * inv0, ax1 = qx1 * inv0, ax2 = qx2 * inv0;
    float ay0 = qy0 * inv1, ay1 = qy1 * inv1, ay2 = qy2 * inv1;
    float ps0 = 0, ps1 = 0, pd0 = 0, pd1 = 0;
    float4 out[4];
    __half2* ghp = (__half2*)out;
    float gprev = 0.f;
#pragma unroll
    for (int c = 0; c < 32; c++) {
        float v0 = W1[c * 3] * ax0 + W1[c * 3 + 1] * ax1 + W1[c * 3 + 2] * ax2;
        float v1 = W1[96 + c * 3] * ay0 + W1[97 + c * 3] * ay1 + W1[98 + c * 3] * ay2;
        float g = fmaxf(0.5f * (v0 + v1) + b1[c], 0.f);  // mean heads + bias + relu
        ps0 += g * u_s[c];      ps1 += g * u_s[32 + c];
        pd0 += g * u_d[c];      pd1 += g * u_d[32 + c];
        if (c & 1) ghp[c >> 1] = __floats2half2_rn(gprev, g);
        else gprev = g;
    }
    float4* gdst = (float4*)(g1h + (size_t)dst * 16);
    gdst[0] = out[0]; gdst[1] = out[1]; gdst[2] = out[2]; gdst[3] = out[3];
    ssd2[dst] = make_float2(ps0, ps1);
    sd2[dst]  = make_float2(pd0, pd1);
}

// ---------------- GAT2 aggregate: QUARTER-thread-per-dst (4 threads split 32 channels) ----------------
// Adjacent threads q=0..3 of a dst each own 8 channels (16B of the 64B g1h row ->
// the quad's loads coalesce into one line). Zero shfl; fused 1/den; coalesced agg writes.
__global__ __launch_bounds__(256) void aggB_kernel(
        const int* __restrict__ rowptr, const int* __restrict__ csr,
        const __half2* __restrict__ g1h,
        const float2* __restrict__ ssd2, const float2* __restrict__ sd2,
        float* __restrict__ agg, int N) {
    int tid = blockIdx.x * 256 + threadIdx.x;
    int dst = tid >> 2;
    if (dst >= N) return;
    int q = tid & 3;
    int rs = rowptr[dst], re = rowptr[dst + 1];
    float2 sdv = sd2[dst];
    float a0[8] = {0, 0, 0, 0, 0, 0, 0, 0};
    float a1[8] = {0, 0, 0, 0, 0, 0, 0, 0};
    float den0 = 0.f, den1 = 0.f;
    const __half2* gbase = g1h + q * 4;  // this thread's 4 half2 slots of each row
#define AGGB_EDGE(sc, gv) { \
        float w0 = __expf(lrelu(sc.x + sdv.x)); \
        float w1 = __expf(lrelu(sc.y + sdv.y)); \
        den0 += w0; den1 += w1; \
        float2 p0 = __half22float2(*(const __half2*)&gv.x); \
        float2 p1 = __half22float2(*(const __half2*)&gv.y); \
        float2 p2 = __half22float2(*(const __half2*)&gv.z); \
        float2 p3 = __half22float2(*(const __half2*)&gv.w); \
        a0[0] += w0 * p0.x; a0[1] += w0 * p0.y; a0[2] += w0 * p1.x; a0[3] += w0 * p1.y; \
        a0[4] += w0 * p2.x; a0[5] += w0 * p2.y; a0[6] += w0 * p3.x; a0[7] += w0 * p3.y; \
        a1[0] += w1 * p0.x; a1[1] += w1 * p0.y; a1[2] += w1 * p1.x; a1[3] += w1 * p1.y; \
        a1[4] += w1 * p2.x; a1[5] += w1 * p2.y; a1[6] += w1 * p3.x; a1[7] += w1 * p3.y; }
    int e = rs;
    for (; e + 4 <= re; e += 4) {
        int s0 = csr[e], s1 = csr[e + 1], s2 = csr[e + 2], s3 = csr[e + 3];
        float2 c0 = ssd2[s0], c1 = ssd2[s1], c2 = ssd2[s2], c3 = ssd2[s3];
        float4 g0 = *(const float4*)(gbase + (size_t)s0 * 16);
        float4 g1 = *(const float4*)(gbase + (size_t)s1 * 16);
        float4 g2 = *(const float4*)(gbase + (size_t)s2 * 16);
        float4 g3 = *(const float4*)(gbase + (size_t)s3 * 16);
        AGGB_EDGE(c0, g0); AGGB_EDGE(c1, g1); AGGB_EDGE(c2, g2); AGGB_EDGE(c3, g3);
    }
    for (; e < re; e++) {
        int s = csr[e];
        float2 c = ssd2[s];
        float4 g = *(const float4*)(gbase + (size_t)s * 16);
        AGGB_EDGE(c, g);
    }
#undef AGGB_EDGE
    float i0 = 1.f / (den0 + 1e-16f), i1 = 1.f / (den1 + 1e-16f);
    float* ap = agg + (size_t)dst * 64 + q * 8;
    float4 o;
    o.x = a0[0] * i0; o.y = a0[1] * i0; o.z = a0[2] * i0; o.w = a0[3] * i0;
    *(float4*)ap = o;
    o.x = a0[4] * i0; o.y = a0[5] * i0; o.z = a0[6] * i0; o.w = a0[7] * i0;
    *(float4*)(ap + 4) = o;
    o.x = a1[0] * i1; o.y = a1[1] * i1; o.z = a1[2] * i1; o.w = a1[3] * i1;
    *(float4*)(ap + 32) = o;
    o.x = a1[4] * i1; o.y = a1[5] * i1; o.z = a1[6] * i1; o.w = a1[7] * i1;
    *(float4*)(ap + 36) = o;
}

// ---------------- block-cooperative dense: 64 nodes/block, 4 waves ----------------
__global__ __launch_bounds__(256) void dense_kernel(
        const float* __restrict__ agg,
        const float* __restrict__ w2pk, const float* __restrict__ b2,
        const float* __restrict__ wgru,
        const float* __restrict__ b_ih, const float* __restrict__ b_hh,
        float* __restrict__ hstT, int N, int first) {
    __shared__ float a_lds[64 * 65];     // [nl][k] stride 65
    __shared__ float g_lds[64 * 33];     // [nl][c] stride 33
    __shared__ float h_lds[64 * 33];     // [nl][k] stride 33
    int tid = threadIdx.x;
    int node0 = blockIdx.x * 64;
    int nvalid = min(64, N - node0);
    for (int idx = tid; idx < nvalid * 64; idx += 256) {
        int nl = idx >> 6, k = idx & 63;
        a_lds[nl * 65 + k] = agg[(size_t)node0 * 64 + idx];
    }
    for (int idx = tid; idx < 32 * 64; idx += 256) {
        int k = idx >> 6, nl = idx & 63;
        float hv = 0.f;
        if (!first && nl < nvalid) hv = hstT[(size_t)k * N + node0 + nl];
        h_lds[nl * 33 + k] = hv;
    }
    __syncthreads();
    int nl = tid & 63;
    int cg8 = __builtin_amdgcn_readfirstlane((tid >> 6) * 8);  // wave-uniform channel base
    bool active = nl < nvalid;
    int node = node0 + nl;
    float acc[8] = {0, 0, 0, 0, 0, 0, 0, 0};
    for (int k = 0; k < 32; k++) {
        float ak0 = a_lds[nl * 65 + k];
        float ak1 = a_lds[nl * 65 + 32 + k];
        const float* wp = w2pk + k * 64 + cg8;
#pragma unroll
        for (int j = 0; j < 8; j++) acc[j] += wp[j] * ak0 + wp[32 + j] * ak1;
    }
#pragma unroll
    for (int j = 0; j < 8; j++) {
        float g = fmaxf(0.5f * acc[j] + b2[cg8 + j], 0.f);
        g_lds[nl * 33 + cg8 + j] = g;
    }
    __syncthreads();
    float ir[8], iz[8], in_[8], hr[8], hz[8], hn[8];
#pragma unroll
    for (int j = 0; j < 8; j++) {
        ir[j] = b_ih[cg8 + j]; iz[j] = b_ih[32 + cg8 + j]; in_[j] = b_ih[64 + cg8 + j];
        hr[j] = b_hh[cg8 + j]; hz[j] = b_hh[32 + cg8 + j]; hn[j] = b_hh[64 + cg8 + j];
    }
    for (int k = 0; k < 32; k++) {
        float gk = g_lds[nl * 33 + k];
        float hk = h_lds[nl * 33 + k];
        const float* wp = wgru + k * 192 + cg8;
#pragma unroll
        for (int j = 0; j < 8; j++) {
            ir[j]  += wp[j]       * gk;
            iz[j]  += wp[32 + j]  * gk;
            in_[j] += wp[64 + j]  * gk;
            hr[j]  += wp[96 + j]  * hk;
            hz[j]  += wp[128 + j] * hk;
            hn[j]  += wp[160 + j] * hk;
        }
    }
    if (active) {
#pragma unroll
        for (int j = 0; j < 8; j++) {
            int c = cg8 + j;
            float rr = sigmoidf(ir[j] + hr[j]);
            float zz = sigmoidf(iz[j] + hz[j]);
            float cand = tanhf(in_[j] + rr * hn[j]);
            float hold = h_lds[nl * 33 + c];
            hstT[(size_t)c * N + node] = (1.f - zz) * cand + zz * hold;
        }
    }
}

// ---------------- final Linear(hid,1) ----------------
__global__ __launch_bounds__(256) void final_kernel(
        const float* __restrict__ hstT, const float* __restrict__ fc_w,
        const float* __restrict__ fc_b, float* __restrict__ out, int N) {
    int node = blockIdx.x * 256 + threadIdx.x;
    if (node >= N) return;
    float v = fc_b[0];
#pragma unroll
    for (int c = 0; c < 32; c++) v += hstT[(size_t)c * N + node] * fc_w[c];
    out[node] = v;
}

extern "C" void kernel_launch(void* const* d_in, const int* in_sizes, int n_in,
                              void* d_out, int out_size, void* d_ws, size_t ws_size,
                              hipStream_t stream) {
    const float* x_seq = (const float*)d_in[0];
    const float* W1  = (const float*)d_in[1];
    const float* a1s = (const float*)d_in[2];
    const float* a1d = (const float*)d_in[3];
    const float* b1  = (const float*)d_in[4];
    const float* W2  = (const float*)d_in[5];
    const float* a2s = (const float*)d_in[6];
    const float* a2d = (const float*)d_in[7];
    const float* b2  = (const float*)d_in[8];
    const float* w_ih = (const float*)d_in[9];
    const float* w_hh = (const float*)d_in[10];
    const float* b_ih = (const float*)d_in[11];
    const float* b_hh = (const float*)d_in[12];
    const float* fc_w = (const float*)d_in[13];
    const float* fc_b = (const float*)d_in[14];
    const void*  ei   = d_in[15];

    const int N = in_sizes[0] / (T_STEPS * FIN);  // 50000
    const int E = in_sizes[15] / 2;               // 800000
    const int NE = E + N;
    const int NB = (N + 255) / 256;               // per-256 blocks (196)
    const int NB64 = (N + 63) / 64;               // 64-node blocks (782)
    const int EB = (E + 255) / 256;

    char* ws = (char*)d_ws;
    size_t off = 0;
    auto alloc = [&](size_t bytes) -> void* {
        void* p = ws + off;
        off += (bytes + 255) & ~(size_t)255;
        return p;
    };
    int*     flag   = (int*)alloc(4);
    int*     rowptr = (int*)alloc((size_t)(N + 1) * 4);
    int*     cnt    = (int*)alloc((size_t)N * 4);        // reused as fill cursor
    int*     bsum   = (int*)alloc(256 * 4);
    int*     csr    = (int*)alloc((size_t)NE * 4);
    float4*  nrec4  = (float4*)alloc((size_t)N * 16);    // {x0,x1,x2,half2(ss0,ss1)}
    float2*  sd1    = (float2*)alloc((size_t)N * 8);
    float2*  ssd2   = (float2*)alloc((size_t)N * 8);
    float2*  sd2    = (float2*)alloc((size_t)N * 8);
    __half2* g1h    = (__half2*)alloc((size_t)N * 16 * 4);  // fp16 g1: 64B/node, L2-resident
    float*   agg    = (float*)alloc((size_t)N * 64 * 4);
    float*   hstT   = (float*)alloc((size_t)N * 32 * 4);    // transposed hstate [c][node]
    float*   u_s    = (float*)alloc(64 * 4);
    float*   u_d    = (float*)alloc(64 * 4);
    float*   w2pk   = (float*)alloc(2048 * 4);              // k-major W2
    float*   wgru   = (float*)alloc(6144 * 4);              // k-major GRU weights
    if (off > ws_size) return;  // workspace too small — cannot proceed safely

    // int32 edge copies ALIAS the agg buffer (agg is first written by aggB, long
    // after preprocessing completes; deterministic every launch)
    int* src32 = (int*)agg;
    int* dst32 = src32 + E;

    // ---- preprocessing: CSR by destination (reused for all 16 aggregations) ----
    detect_kernel<<<1, 128, 0, stream>>>((const int*)ei, in_sizes[15], flag);
    conv_kernel<<<EB, 256, 0, stream>>>(ei, flag, E, N, src32, dst32);
    init_kernel<<<NB, 256, 0, stream>>>(cnt, N);
    count_kernel<<<EB, 256, 0, stream>>>(dst32, E, N, cnt);
    scan1_kernel<<<NB, 256, 0, stream>>>(cnt, rowptr, bsum, N);
    scan2_kernel<<<1, 256, 0, stream>>>(bsum, NB);
    scan3_kernel<<<NB, 256, 0, stream>>>(rowptr, bsum, N);
    selffill_kernel<<<NB, 256, 0, stream>>>(rowptr, csr, cnt, N);
    {
        const int NPASS = 8;
        int per = (N + NPASS - 1) / NPASS;
        for (int p = 0; p < NPASS; p++) {
            int lo = p * per;
            int hi = min(lo + per, N);
            scatter_kernel<<<EB, 256, 0, stream>>>(src32, dst32, E, lo, hi, cnt, csr);
        }
    }
    prep_u_kernel<<<1, 64, 0, stream>>>(W2, a2s, a2d, u_s, u_d);
    pack_kernel<<<24, 256, 0, stream>>>(W2, w_ih, w_hh, w2pk, wgru);

    // ---- T timesteps ----
    for (int t = 0; t < T_STEPS; t++) {
        const float* xt = x_seq + (size_t)t * N * FIN;
        score1_kernel<<<(N * 64 + 255) / 256, 256, 0, stream>>>(xt, W1, a1s, a1d, nrec4, sd1, N);
        aggA_kernel<<<NB64, 64, 0, stream>>>(rowptr, csr, nrec4, sd1, W1, b1,
                                             u_s, u_d, g1h, ssd2, sd2, N);
        aggB_kernel<<<(N * 4 + 255) / 256, 256, 0, stream>>>(rowptr, csr, g1h, ssd2, sd2, agg, N);
        dense_kernel<<<NB64, 256, 0, stream>>>(agg, w2pk, b2, wgru, b_ih, b_hh,
                                               hstT, N, t == 0 ? 1 : 0);
    }
    final_kernel<<<NB, 256, 0, stream>>>(hstT, fc_w, fc_b, (float*)d_out, N);
}

// Round 9
// 553.174 us; speedup vs baseline: 6.9682x; 1.1758x over previous
//
#include <hip/hip_runtime.h>
#include <hip/hip_fp16.h>
#include <stdint.h>

#define T_STEPS 8
#define FIN 3
#define HID 32
#define NEG_SLOPE 0.2f

__device__ __forceinline__ float lrelu(float x) { return x > 0.f ? x : NEG_SLOPE * x; }
__device__ __forceinline__ float sigmoidf(float x) { return 1.f / (1.f + __expf(-x)); }

// ---------------- edge dtype detection (int64 vs int32) ----------------
__global__ void detect_kernel(const int* ei32, int nElems, int* flag) {
    __shared__ int any_nonzero;
    if (threadIdx.x == 0) any_nonzero = 0;
    __syncthreads();
    int idx = 1 + 2 * (int)threadIdx.x;  // odd int32 slots
    if (idx < nElems && ei32[idx] != 0) any_nonzero = 1;  // benign race
    __syncthreads();
    if (threadIdx.x == 0) *flag = (any_nonzero ? 0 : 1);  // 1 => int64
}

__device__ __forceinline__ int get_edge(const void* ei, int is64, long long idx) {
    if (is64) return (int)((const long long*)ei)[idx];
    return ((const int*)ei)[idx];
}

__global__ void init_kernel(int* cnt, int N) {
    int i = blockIdx.x * 256 + threadIdx.x;
    if (i < N) cnt[i] = 1;  // self-loop pre-counted
}

// fused: int32 conversion + validity clamp + per-dst count
__global__ void conv_count_kernel(const void* ei, const int* flag, int E, int N,
                                  int* src32, int* dst32, int* cnt) {
    int e = blockIdx.x * 256 + threadIdx.x;
    if (e >= E) return;
    int is64 = *flag;
    int s = get_edge(ei, is64, e);
    int d = get_edge(ei, is64, (long long)E + e);
    if ((unsigned)s >= (unsigned)N) s = 0;  // safety clamp
    src32[e] = s;
    int dd = ((unsigned)d < (unsigned)N) ? d : 0x7fffffff;  // sentinel: excluded everywhere
    dst32[e] = dd;
    if (dd < N) atomicAdd(&cnt[dd], 1);
}

// hierarchical scan
__global__ __launch_bounds__(256) void scan1_kernel(const int* cnt, int* rowptr, int* bsum, int n) {
    __shared__ int sm[256];
    int i = blockIdx.x * 256 + threadIdx.x;
    int v = (i < n) ? cnt[i] : 0;
    sm[threadIdx.x] = v;
    __syncthreads();
    for (int off = 1; off < 256; off <<= 1) {
        int t = (threadIdx.x >= off) ? sm[threadIdx.x - off] : 0;
        __syncthreads();
        sm[threadIdx.x] += t;
        __syncthreads();
    }
    if (i < n) rowptr[i + 1] = sm[threadIdx.x];
    if (threadIdx.x == 255) bsum[blockIdx.x] = sm[255];
}

__global__ __launch_bounds__(256) void scan2_kernel(int* bsum, int nb) {
    __shared__ int sm[256];
    int v = (threadIdx.x < nb) ? bsum[threadIdx.x] : 0;
    sm[threadIdx.x] = v;
    __syncthreads();
    for (int off = 1; off < 256; off <<= 1) {
        int t = (threadIdx.x >= off) ? sm[threadIdx.x - off] : 0;
        __syncthreads();
        sm[threadIdx.x] += t;
        __syncthreads();
    }
    if (threadIdx.x < nb) bsum[threadIdx.x] = sm[threadIdx.x];
}

__global__ __launch_bounds__(256) void scan3_kernel(int* rowptr, const int* bsum, int n) {
    int i = blockIdx.x * 256 + threadIdx.x;
    if (i < n && blockIdx.x > 0) rowptr[i + 1] += bsum[blockIdx.x - 1];
    if (i == 0) rowptr[0] = 0;
}

__global__ void selffill_kernel(const int* rowptr, int* csr, int* fill, int N) {
    int n = blockIdx.x * 256 + threadIdx.x;
    if (n >= N) return;
    int rp = rowptr[n];
    csr[rp] = n;        // self-loop occupies slot 0 of each row
    fill[n] = rp + 1;
}

// dst-sliced scatter: csr writes confined to an L2-resident window per pass
__global__ void scatter_kernel(const int* __restrict__ src32, const int* __restrict__ dst32,
                               int E, int lo, int hi, int* fill, int* csr) {
    int e = blockIdx.x * 256 + threadIdx.x;
    if (e >= E) return;
    int d = dst32[e];
    if (d < lo || d >= hi) return;
    int p = atomicAdd(&fill[d], 1);
    csr[p] = src32[e];
}

// ---------------- precompute u = W2^T a2 per head (for layer-2 scores) ----------------
__global__ __launch_bounds__(64) void prep_u_kernel(
        const float* __restrict__ W2, const float* __restrict__ a2s,
        const float* __restrict__ a2d, float* __restrict__ u_s, float* __restrict__ u_d) {
    int l = threadIdx.x;  // 0..63
    int h = l >> 5, k = l & 31;
    float us = 0.f, ud = 0.f;
    for (int c = 0; c < 32; c++) {
        float w = W2[(h * 32 + c) * 32 + k];
        us += a2s[h * 32 + c] * w;
        ud += a2d[h * 32 + c] * w;
    }
    u_s[l] = us;
    u_d[l] = ud;
}

// ---------------- pack weights k-major for the dense phase ----------------
__global__ __launch_bounds__(256) void pack_kernel(
        const float* __restrict__ W2, const float* __restrict__ w_ih,
        const float* __restrict__ w_hh, float* __restrict__ w2pk, float* __restrict__ wgru) {
    int idx = blockIdx.x * 256 + threadIdx.x;
    if (idx < 2048) {
        int k = idx >> 6, c = idx & 63;
        w2pk[idx] = W2[c * 32 + k];
    }
    if (idx < 6144) {
        int k = idx / 192, r = idx % 192;
        wgru[idx] = (r < 96) ? w_ih[r * 32 + k] : w_hh[(r - 96) * 32 + k];
    }
}

// ---------------- layer-1 scores: THREAD-per-node (zero shfl, s_load weights) ----------------
__global__ __launch_bounds__(256) void score1_kernel(
        const float* __restrict__ x, const float* __restrict__ W1,
        const float* __restrict__ a1s, const float* __restrict__ a1d,
        float4* __restrict__ nrec4, float2* __restrict__ sd1, int N) {
    int node = blockIdx.x * 256 + threadIdx.x;
    if (node >= N) return;
    const float* xp = x + (size_t)node * FIN;
    float x0 = xp[0], x1 = xp[1], x2 = xp[2];
    float ps0 = 0.f, ps1 = 0.f, pd0 = 0.f, pd1 = 0.f;
    for (int c = 0; c < 32; c++) {
        float h0 = W1[c * 3] * x0 + W1[c * 3 + 1] * x1 + W1[c * 3 + 2] * x2;
        float h1 = W1[96 + c * 3] * x0 + W1[97 + c * 3] * x1 + W1[98 + c * 3] * x2;
        ps0 += h0 * a1s[c]; pd0 += h0 * a1d[c];
        ps1 += h1 * a1s[32 + c]; pd1 += h1 * a1d[32 + c];
    }
    unsigned u = (unsigned)__half_as_ushort(__float2half_rn(ps0)) |
                 ((unsigned)__half_as_ushort(__float2half_rn(ps1)) << 16);
    float4 r;
    r.x = x0; r.y = x1; r.z = x2; r.w = __uint_as_float(u);
    nrec4[node] = r;
    sd1[node] = make_float2(pd0, pd1);
}

__device__ __forceinline__ void unpack_scores(float wslot, float& s0, float& s1) {
    unsigned u = __float_as_uint(wslot);
    s0 = __half2float(__ushort_as_half((unsigned short)(u & 0xffffu)));
    s1 = __half2float(__ushort_as_half((unsigned short)(u >> 16)));
}

// ---------------- GAT1 aggregate: THREAD-per-dst, 4-way unrolled 16B gathers ----------------
__global__ __launch_bounds__(64) void aggA_kernel(
        const int* __restrict__ rowptr, const int* __restrict__ csr,
        const float4* __restrict__ nrec4, const float2* __restrict__ sd1,
        const float* __restrict__ W1, const float* __restrict__ b1,
        const float* __restrict__ u_s, const float* __restrict__ u_d,
        __half2* __restrict__ g1h, float2* __restrict__ ssd2, float2* __restrict__ sd2, int N) {
    int dst = blockIdx.x * 64 + threadIdx.x;
    if (dst >= N) return;
    int rs = rowptr[dst], re = rowptr[dst + 1];
    float2 sdv = sd1[dst];
    float q0 = 0, qx0 = 0, qx1 = 0, qx2 = 0;
    float q1 = 0, qy0 = 0, qy1 = 0, qy2 = 0;
#define AGGA_EDGE(rr) { \
        float s0h, s1h; unpack_scores(rr.w, s0h, s1h); \
        float w0 = __expf(lrelu(s0h + sdv.x)); \
        float w1 = __expf(lrelu(s1h + sdv.y)); \
        q0 += w0; qx0 += w0 * rr.x; qx1 += w0 * rr.y; qx2 += w0 * rr.z; \
        q1 += w1; qy0 += w1 * rr.x; qy1 += w1 * rr.y; qy2 += w1 * rr.z; }
    int e = rs;
    for (; e + 4 <= re; e += 4) {
        int s0 = csr[e], s1 = csr[e + 1], s2 = csr[e + 2], s3 = csr[e + 3];
        float4 r0 = nrec4[s0], r1 = nrec4[s1], r2 = nrec4[s2], r3 = nrec4[s3];
        AGGA_EDGE(r0); AGGA_EDGE(r1); AGGA_EDGE(r2); AGGA_EDGE(r3);
    }
    for (; e < re; e++) {
        int s = csr[e];
        float4 r = nrec4[s];
        AGGA_EDGE(r);
    }
#undef AGGA_EDGE
    float inv0 = 1.f / (q0 + 1e-16f), inv1 = 1.f / (q1 + 1e-16f);
    float ax0 = qx0 * inv0, ax1 = qx1 * inv0, ax2 = qx2 * inv0;
    float ay0 = qy0 * inv1, ay1 = qy1 * inv1, ay2 = qy2 * inv1;
    float ps0 = 0, ps1 = 0, pd0 = 0, pd1 = 0;
    float4 out[4];
    __half2* ghp = (__half2*)out;
    float gprev = 0.f;
#pragma unroll
    for (int c = 0; c < 32; c++) {
        float v0 = W1[c * 3] * ax0 + W1[c * 3 + 1] * ax1 + W1[c * 3 + 2] * ax2;
        float v1 = W1[96 + c * 3] * ay0 + W1[97 + c * 3] * ay1 + W1[98 + c * 3] * ay2;
        float g = fmaxf(0.5f * (v0 + v1) + b1[c], 0.f);  // mean heads + bias + relu
        ps0 += g * u_s[c];      ps1 += g * u_s[32 + c];
        pd0 += g * u_d[c];      pd1 += g * u_d[32 + c];
        if (c & 1) ghp[c >> 1] = __floats2half2_rn(gprev, g);
        else gprev = g;
    }
    float4* gdst = (float4*)(g1h + (size_t)dst * 16);
    gdst[0] = out[0]; gdst[1] = out[1]; gdst[2] = out[2]; gdst[3] = out[3];
    ssd2[dst] = make_float2(ps0, ps1);
    sd2[dst]  = make_float2(pd0, pd1);
}

// ---------------- FUSED: GAT2 aggregate (quad-per-dst -> LDS) + W2 + GRU (+final fc) ----------------
// Block = 256 threads = 64 dsts. Phase 1: 4 threads/dst gather+aggregate into a_lds.
// Phase 2: block-cooperative dense (wave-uniform s_load weight streams).
// On last step: skip hstT store, reduce fc dot into out directly.
__global__ __launch_bounds__(256) void aggBdense_kernel(
        const int* __restrict__ rowptr, const int* __restrict__ csr,
        const __half2* __restrict__ g1h,
        const float2* __restrict__ ssd2, const float2* __restrict__ sd2,
        const float* __restrict__ w2pk, const float* __restrict__ b2,
        const float* __restrict__ wgru,
        const float* __restrict__ b_ih, const float* __restrict__ b_hh,
        float* __restrict__ hstT, const float* __restrict__ fc_w,
        const float* __restrict__ fc_b, float* __restrict__ out,
        int N, int first, int last) {
    __shared__ float a_lds[64 * 65];     // [nl][k] stride 65 (also reused for fc partials)
    __shared__ float g_lds[64 * 33];     // [nl][c] stride 33
    __shared__ float h_lds[64 * 33];     // [nl][k] stride 33
    int tid = threadIdx.x;
    int node0 = blockIdx.x * 64;
    // stage previous h state (coalesced: node fastest)
    for (int idx = tid; idx < 32 * 64; idx += 256) {
        int k = idx >> 6, nl = idx & 63;
        float hv = 0.f;
        if (!first && node0 + nl < N) hv = hstT[(size_t)k * N + node0 + nl];
        h_lds[nl * 33 + k] = hv;
    }
    // ---- phase 1: quad-per-dst GAT2 aggregation ----
    int dl = tid >> 2;           // local dst 0..63
    int q = tid & 3;             // quarter: channels q*8..q*8+7 per head
    int dst = node0 + dl;
    if (dst < N) {
        int rs = rowptr[dst], re = rowptr[dst + 1];
        float2 sdv = sd2[dst];
        float a0[8] = {0, 0, 0, 0, 0, 0, 0, 0};
        float a1[8] = {0, 0, 0, 0, 0, 0, 0, 0};
        float den0 = 0.f, den1 = 0.f;
        const __half2* gbase = g1h + q * 4;
#define AGGB_EDGE(sc, gv) { \
        float w0 = __expf(lrelu(sc.x + sdv.x)); \
        float w1 = __expf(lrelu(sc.y + sdv.y)); \
        den0 += w0; den1 += w1; \
        float2 p0 = __half22float2(*(const __half2*)&gv.x); \
        float2 p1 = __half22float2(*(const __half2*)&gv.y); \
        float2 p2 = __half22float2(*(const __half2*)&gv.z); \
        float2 p3 = __half22float2(*(const __half2*)&gv.w); \
        a0[0] += w0 * p0.x; a0[1] += w0 * p0.y; a0[2] += w0 * p1.x; a0[3] += w0 * p1.y; \
        a0[4] += w0 * p2.x; a0[5] += w0 * p2.y; a0[6] += w0 * p3.x; a0[7] += w0 * p3.y; \
        a1[0] += w1 * p0.x; a1[1] += w1 * p0.y; a1[2] += w1 * p1.x; a1[3] += w1 * p1.y; \
        a1[4] += w1 * p2.x; a1[5] += w1 * p2.y; a1[6] += w1 * p3.x; a1[7] += w1 * p3.y; }
        int e = rs;
        for (; e + 4 <= re; e += 4) {
            int s0 = csr[e], s1 = csr[e + 1], s2 = csr[e + 2], s3 = csr[e + 3];
            float2 c0 = ssd2[s0], c1 = ssd2[s1], c2 = ssd2[s2], c3 = ssd2[s3];
            float4 g0 = *(const float4*)(gbase + (size_t)s0 * 16);
            float4 g1 = *(const float4*)(gbase + (size_t)s1 * 16);
            float4 g2 = *(const float4*)(gbase + (size_t)s2 * 16);
            float4 g3 = *(const float4*)(gbase + (size_t)s3 * 16);
            AGGB_EDGE(c0, g0); AGGB_EDGE(c1, g1); AGGB_EDGE(c2, g2); AGGB_EDGE(c3, g3);
        }
        for (; e < re; e++) {
            int s = csr[e];
            float2 c = ssd2[s];
            float4 g = *(const float4*)(gbase + (size_t)s * 16);
            AGGB_EDGE(c, g);
        }
#undef AGGB_EDGE
        float i0 = 1.f / (den0 + 1e-16f), i1 = 1.f / (den1 + 1e-16f);
#pragma unroll
        for (int j = 0; j < 8; j++) {
            a_lds[dl * 65 + q * 8 + j] = a0[j] * i0;
            a_lds[dl * 65 + 32 + q * 8 + j] = a1[j] * i1;
        }
    }
    __syncthreads();
    // ---- phase 2: W2 + mean-heads + relu ----
    int nl = tid & 63;
    int cg8 = __builtin_amdgcn_readfirstlane((tid >> 6) * 8);  // wave-uniform channel base
    int node = node0 + nl;
    bool active = node < N;
    float acc[8] = {0, 0, 0, 0, 0, 0, 0, 0};
    for (int k = 0; k < 32; k++) {
        float ak0 = a_lds[nl * 65 + k];
        float ak1 = a_lds[nl * 65 + 32 + k];
        const float* wp = w2pk + k * 64 + cg8;
#pragma unroll
        for (int j = 0; j < 8; j++) acc[j] += wp[j] * ak0 + wp[32 + j] * ak1;
    }
#pragma unroll
    for (int j = 0; j < 8; j++) {
        float g = fmaxf(0.5f * acc[j] + b2[cg8 + j], 0.f);
        g_lds[nl * 33 + cg8 + j] = g;
    }
    __syncthreads();
    // ---- GRU for channels cg8..cg8+7 ----
    float ir[8], iz[8], in_[8], hr[8], hz[8], hn[8];
#pragma unroll
    for (int j = 0; j < 8; j++) {
        ir[j] = b_ih[cg8 + j]; iz[j] = b_ih[32 + cg8 + j]; in_[j] = b_ih[64 + cg8 + j];
        hr[j] = b_hh[cg8 + j]; hz[j] = b_hh[32 + cg8 + j]; hn[j] = b_hh[64 + cg8 + j];
    }
    for (int k = 0; k < 32; k++) {
        float gk = g_lds[nl * 33 + k];
        float hk = h_lds[nl * 33 + k];
        const float* wp = wgru + k * 192 + cg8;
#pragma unroll
        for (int j = 0; j < 8; j++) {
            ir[j]  += wp[j]       * gk;
            iz[j]  += wp[32 + j]  * gk;
            in_[j] += wp[64 + j]  * gk;
            hr[j]  += wp[96 + j]  * hk;
            hz[j]  += wp[128 + j] * hk;
            hn[j]  += wp[160 + j] * hk;
        }
    }
    float part = 0.f;
    if (active) {
#pragma unroll
        for (int j = 0; j < 8; j++) {
            int c = cg8 + j;
            float rr = sigmoidf(ir[j] + hr[j]);
            float zz = sigmoidf(iz[j] + hz[j]);
            float cand = tanhf(in_[j] + rr * hn[j]);
            float hold = h_lds[nl * 33 + c];
            float hnew = (1.f - zz) * cand + zz * hold;
            if (!last) hstT[(size_t)c * N + node] = hnew;
            else part += fc_w[c] * hnew;
        }
    }
    if (last) {
        __syncthreads();  // a_lds no longer needed; reuse for fc partials
        a_lds[nl * 5 + (tid >> 6)] = part;
        __syncthreads();
        if (tid < 64 && node0 + tid < N) {
            float v = a_lds[tid * 5] + a_lds[tid * 5 + 1] + a_lds[tid * 5 + 2] +
                      a_lds[tid * 5 + 3] + fc_b[0];
            out[node0 + tid] = v;
        }
    }
}

extern "C" void kernel_launch(void* const* d_in, const int* in_sizes, int n_in,
                              void* d_out, int out_size, void* d_ws, size_t ws_size,
                              hipStream_t stream) {
    const float* x_seq = (const float*)d_in[0];
    const float* W1  = (const float*)d_in[1];
    const float* a1s = (const float*)d_in[2];
    const float* a1d = (const float*)d_in[3];
    const float* b1  = (const float*)d_in[4];
    const float* W2  = (const float*)d_in[5];
    const float* a2s = (const float*)d_in[6];
    const float* a2d = (const float*)d_in[7];
    const float* b2  = (const float*)d_in[8];
    const float* w_ih = (const float*)d_in[9];
    const float* w_hh = (const float*)d_in[10];
    const float* b_ih = (const float*)d_in[11];
    const float* b_hh = (const float*)d_in[12];
    const float* fc_w = (const float*)d_in[13];
    const float* fc_b = (const float*)d_in[14];
    const void*  ei   = d_in[15];

    const int N = in_sizes[0] / (T_STEPS * FIN);  // 50000
    const int E = in_sizes[15] / 2;               // 800000
    const int NE = E + N;
    const int NB = (N + 255) / 256;               // per-256 blocks (196)
    const int NB64 = (N + 63) / 64;               // 64-node blocks (782)
    const int EB = (E + 255) / 256;

    char* ws = (char*)d_ws;
    size_t off = 0;
    auto alloc = [&](size_t bytes) -> void* {
        void* p = ws + off;
        off += (bytes + 255) & ~(size_t)255;
        return p;
    };
    int*     flag   = (int*)alloc(4);
    int*     rowptr = (int*)alloc((size_t)(N + 1) * 4);
    int*     cnt    = (int*)alloc((size_t)N * 4);        // reused as fill cursor
    int*     bsum   = (int*)alloc(256 * 4);
    int*     csr    = (int*)alloc((size_t)NE * 4);
    int*     src32  = (int*)alloc((size_t)E * 4);
    int*     dst32  = (int*)alloc((size_t)E * 4);
    float4*  nrec4  = (float4*)alloc((size_t)N * 16);    // {x0,x1,x2,half2(ss0,ss1)}
    float2*  sd1    = (float2*)alloc((size_t)N * 8);
    float2*  ssd2   = (float2*)alloc((size_t)N * 8);
    float2*  sd2    = (float2*)alloc((size_t)N * 8);
    __half2* g1h    = (__half2*)alloc((size_t)N * 16 * 4);  // fp16 g1: 64B/node, L2-resident
    float*   hstT   = (float*)alloc((size_t)N * 32 * 4);    // transposed hstate [c][node]
    float*   u_s    = (float*)alloc(64 * 4);
    float*   u_d    = (float*)alloc(64 * 4);
    float*   w2pk   = (float*)alloc(2048 * 4);              // k-major W2
    float*   wgru   = (float*)alloc(6144 * 4);              // k-major GRU weights
    if (off > ws_size) return;  // workspace too small — cannot proceed safely

    // ---- preprocessing: CSR by destination (reused for all 16 aggregations) ----
    detect_kernel<<<1, 128, 0, stream>>>((const int*)ei, in_sizes[15], flag);
    init_kernel<<<NB, 256, 0, stream>>>(cnt, N);
    conv_count_kernel<<<EB, 256, 0, stream>>>(ei, flag, E, N, src32, dst32, cnt);
    scan1_kernel<<<NB, 256, 0, stream>>>(cnt, rowptr, bsum, N);
    scan2_kernel<<<1, 256, 0, stream>>>(bsum, NB);
    scan3_kernel<<<NB, 256, 0, stream>>>(rowptr, bsum, N);
    selffill_kernel<<<NB, 256, 0, stream>>>(rowptr, csr, cnt, N);
    {
        const int NPASS = 4;
        int per = (N + NPASS - 1) / NPASS;
        for (int p = 0; p < NPASS; p++) {
            int lo = p * per;
            int hi = min(lo + per, N);
            scatter_kernel<<<EB, 256, 0, stream>>>(src32, dst32, E, lo, hi, cnt, csr);
        }
    }
    prep_u_kernel<<<1, 64, 0, stream>>>(W2, a2s, a2d, u_s, u_d);
    pack_kernel<<<24, 256, 0, stream>>>(W2, w_ih, w_hh, w2pk, wgru);

    // ---- T timesteps ----
    for (int t = 0; t < T_STEPS; t++) {
        const float* xt = x_seq + (size_t)t * N * FIN;
        score1_kernel<<<NB, 256, 0, stream>>>(xt, W1, a1s, a1d, nrec4, sd1, N);
        aggA_kernel<<<NB64, 64, 0, stream>>>(rowptr, csr, nrec4, sd1, W1, b1,
                                             u_s, u_d, g1h, ssd2, sd2, N);
        aggBdense_kernel<<<NB64, 256, 0, stream>>>(rowptr, csr, g1h, ssd2, sd2,
                                                   w2pk, b2, wgru, b_ih, b_hh,
                                                   hstT, fc_w, fc_b, (float*)d_out,
                                                   N, t == 0 ? 1 : 0, t == T_STEPS - 1 ? 1 : 0);
    }
}